// Round 1
// baseline (1428.025 us; speedup 1.0000x reference)
//
#include <hip/hip_runtime.h>
#include <hip/hip_bf16.h>

#define N_NODES 100000
#define E_EDGES 1600000
#define FDIM 64
#define G_GRAPHS 128
#define OUTD 32

// ---------------- CSR build ----------------

__global__ __launch_bounds__(256) void hist_kernel(const int* __restrict__ dst,
                                                   int* __restrict__ deg) {
    int e = blockIdx.x * 256 + threadIdx.x;
    if (e < E_EDGES) atomicAdd(&deg[dst[e]], 1);
}

// single-block exclusive scan over N_NODES elements, 1024 threads
__global__ __launch_bounds__(1024) void scan_kernel(const int* __restrict__ deg,
                                                    int* __restrict__ offsets) {
    __shared__ int s[1024];
    const int tid = threadIdx.x;
    const int per = (N_NODES + 1023) / 1024;  // 98
    int lo = tid * per;
    int hi = lo + per; if (hi > N_NODES) hi = N_NODES;
    if (lo > N_NODES) lo = N_NODES;
    int sum = 0;
    for (int i = lo; i < hi; ++i) sum += deg[i];
    s[tid] = sum;
    __syncthreads();
    for (int off = 1; off < 1024; off <<= 1) {
        int v = 0;
        if (tid >= off) v = s[tid - off];
        __syncthreads();
        if (tid >= off) s[tid] += v;
        __syncthreads();
    }
    int pre = s[tid] - sum;  // exclusive prefix for this thread's chunk
    int run = pre;
    for (int i = lo; i < hi; ++i) { offsets[i] = run; run += deg[i]; }
    if (tid == 1023) offsets[N_NODES] = s[1023];
}

__global__ __launch_bounds__(256) void scatter_kernel(const int* __restrict__ src,
                                                      const int* __restrict__ dst,
                                                      const int* __restrict__ offsets,
                                                      int* __restrict__ cursor,
                                                      int* __restrict__ srcSorted) {
    int e = blockIdx.x * 256 + threadIdx.x;
    if (e < E_EDGES) {
        int d = dst[e];
        int pos = offsets[d] + atomicAdd(&cursor[d], 1);
        srcSorted[pos] = src[e];
    }
}

__global__ __launch_bounds__(256) void bound_kernel(const int* __restrict__ batch,
                                                    int* __restrict__ gstart) {
    int i = blockIdx.x * 256 + threadIdx.x;
    if (i < N_NODES) atomicMin(&gstart[batch[i]], i);
}

// ---------------- dual linear: outM = in@Wm.T + bm ; outC = in@Wc.T + bc ----------------
// block = 256 threads (4 waves), handles 64 nodes. In-place safe when outC == in
// (rows staged through LDS before any write, blocks own disjoint rows).

template <bool DUAL>
__global__ __launch_bounds__(256) void lin_kernel(const float* __restrict__ in,
                                                  const float* __restrict__ Wm,
                                                  const float* __restrict__ bm,
                                                  const float* __restrict__ Wc,
                                                  const float* __restrict__ bc,
                                                  float* __restrict__ outM,
                                                  float* __restrict__ outC) {
    __shared__ float WmT[64][65];
    __shared__ float WcT[64][65];
    __shared__ float rows[4][64];
    const int tid = threadIdx.x;
    for (int i = tid; i < 4096; i += 256) {
        int f = i >> 6, k = i & 63;
        WmT[k][f] = Wm[i];
        if (DUAL) WcT[k][f] = Wc[i];
    }
    __syncthreads();
    const int f = tid & 63, r = tid >> 6;
    const float bmv = bm[f];
    const float bcv = DUAL ? bc[f] : 0.f;
    const int base = blockIdx.x * 64;
    for (int c = 0; c < 64; c += 4) {
        int node = base + c + r;
        bool ok = node < N_NODES;
        if (ok) rows[r][f] = in[node * 64 + f];
        __syncthreads();
        if (ok) {
            float am = bmv, ac = bcv;
#pragma unroll
            for (int k = 0; k < 64; ++k) {
                float hv = rows[r][k];
                am = fmaf(hv, WmT[k][f], am);
                if (DUAL) ac = fmaf(hv, WcT[k][f], ac);
            }
            outM[node * 64 + f] = am;
            if (DUAL) outC[node * 64 + f] = ac;
        }
        __syncthreads();
    }
}

// ---------------- per-node adaptive-relu aggregation (wave per node) ----------------
// hbuf[node] = hbuf[node] (combine-linear result) + projection(stats)

__global__ __launch_bounds__(256) void agg_kernel(const float* __restrict__ msg,
                                                  const int* __restrict__ offsets,
                                                  const int* __restrict__ srcSorted,
                                                  const float* __restrict__ tptr,
                                                  const float* __restrict__ Wp,
                                                  const float* __restrict__ bp,
                                                  float* __restrict__ hbuf) {
    const int wave = threadIdx.x >> 6;
    const int f = threadIdx.x & 63;
    const int node = blockIdx.x * 4 + wave;
    if (node >= N_NODES) return;
    const int start = offsets[node], end = offsets[node + 1];
    float mn = __builtin_inff(), mx = -__builtin_inff(), sm = 0.f;
    for (int e = start; e < end; ++e) {
        int s = srcSorted[e];
        float v = msg[s * 64 + f];
        mn = fminf(mn, v);
        mx = fmaxf(mx, v);
        sm += v;
    }
    float tv = fminf(fmaxf(tptr[f], 0.f), 1.f);
    float bias = tv * mx + (1.f - tv) * mn;
    float rs = 0.f;
    for (int e = start; e < end; ++e) {
        int s = srcSorted[e];
        float v = msg[s * 64 + f];
        rs += fmaxf(v - bias, 0.f);
    }
    float cnt = (float)(end - start);
    float agg = Wp[0] * cnt + Wp[1] * mn + Wp[2] * mx + Wp[3] * rs + Wp[4] * sm + bp[0];
    hbuf[node * 64 + f] += agg;
}

// ---------------- global pooling: block per graph ----------------

__global__ __launch_bounds__(256) void gagg_kernel(const float* __restrict__ msg,
                                                   const int* __restrict__ gstart,
                                                   const float* __restrict__ gt,
                                                   const float* __restrict__ gWp,
                                                   const float* __restrict__ gbp,
                                                   float* __restrict__ emb) {
    const int g = blockIdx.x;
    const int f = threadIdx.x & 63, r = threadIdx.x >> 6;
    const int start = gstart[g];
    const int end = (g == G_GRAPHS - 1) ? N_NODES : gstart[g + 1];
    float mn = __builtin_inff(), mx = -__builtin_inff(), sm = 0.f;
    for (int i = start + r; i < end; i += 4) {
        float v = msg[i * 64 + f];
        mn = fminf(mn, v);
        mx = fmaxf(mx, v);
        sm += v;
    }
    __shared__ float smn[4][64], smx[4][64], ssm[4][64];
    smn[r][f] = mn; smx[r][f] = mx; ssm[r][f] = sm;
    __syncthreads();
    float Mn = fminf(fminf(smn[0][f], smn[1][f]), fminf(smn[2][f], smn[3][f]));
    float Mx = fmaxf(fmaxf(smx[0][f], smx[1][f]), fmaxf(smx[2][f], smx[3][f]));
    float Sm = ssm[0][f] + ssm[1][f] + ssm[2][f] + ssm[3][f];
    float tv = fminf(fmaxf(gt[f], 0.f), 1.f);
    float bias = tv * Mx + (1.f - tv) * Mn;
    float rs = 0.f;
    for (int i = start + r; i < end; i += 4) {
        float v = msg[i * 64 + f];
        rs += fmaxf(v - bias, 0.f);
    }
    __syncthreads();
    smn[r][f] = rs;
    __syncthreads();
    if (r == 0) {
        float Rs = smn[0][f] + smn[1][f] + smn[2][f] + smn[3][f];
        float cnt = (float)(end - start);
        emb[g * 64 + f] = gWp[0] * cnt + gWp[1] * Mn + gWp[2] * Mx + gWp[3] * Rs +
                          gWp[4] * Sm + gbp[0];
    }
}

// ---------------- output GEMV ----------------

__global__ __launch_bounds__(256) void out_kernel(const float* __restrict__ emb,
                                                  const float* __restrict__ Wout,
                                                  const float* __restrict__ bout,
                                                  float* __restrict__ out) {
    int i = blockIdx.x * 256 + threadIdx.x;
    if (i >= G_GRAPHS * OUTD) return;
    int g = i >> 5, o = i & 31;
    float a = bout[o];
#pragma unroll
    for (int k = 0; k < 64; ++k) a = fmaf(emb[g * 64 + k], Wout[o * 64 + k], a);
    out[i] = a;
}

// ---------------- launch ----------------

extern "C" void kernel_launch(void* const* d_in, const int* in_sizes, int n_in,
                              void* d_out, int out_size, void* d_ws, size_t ws_size,
                              hipStream_t stream) {
    const float* x     = (const float*)d_in[0];
    const int*   ei    = (const int*)d_in[1];
    const int*   batch = (const int*)d_in[2];
    const float* Wlin  = (const float*)d_in[3];
    const float* blin  = (const float*)d_in[4];
    const float* t     = (const float*)d_in[5];
    const float* Wproj = (const float*)d_in[6];
    const float* bproj = (const float*)d_in[7];
    const float* Wc    = (const float*)d_in[8];
    const float* bc    = (const float*)d_in[9];
    const float* gWlin = (const float*)d_in[10];
    const float* gblin = (const float*)d_in[11];
    const float* gt    = (const float*)d_in[12];
    const float* gWproj= (const float*)d_in[13];
    const float* gbproj= (const float*)d_in[14];
    const float* Wout  = (const float*)d_in[15];
    const float* bout  = (const float*)d_in[16];
    float* out = (float*)d_out;

    const int* src = ei;
    const int* dst = ei + E_EDGES;

    // workspace layout
    char* p = (char*)d_ws;
    float* bufMsg = (float*)p; p += (size_t)N_NODES * FDIM * sizeof(float);
    float* bufH   = (float*)p; p += (size_t)N_NODES * FDIM * sizeof(float);
    float* emb    = (float*)p; p += (size_t)G_GRAPHS * FDIM * sizeof(float);
    int* deg      = (int*)p;   p += (size_t)N_NODES * sizeof(int);
    int* offsets  = (int*)p;   p += (size_t)(N_NODES + 1) * sizeof(int);
    int* cursor   = (int*)p;   p += (size_t)N_NODES * sizeof(int);
    int* gstart   = (int*)p;   p += (size_t)G_GRAPHS * sizeof(int);
    int* srcSorted= (int*)p;   p += (size_t)E_EDGES * sizeof(int);

    hipMemsetAsync(deg, 0, N_NODES * sizeof(int), stream);
    hipMemsetAsync(cursor, 0, N_NODES * sizeof(int), stream);
    hipMemsetAsync(gstart, 0x7f, G_GRAPHS * sizeof(int), stream);

    const int EB = (E_EDGES + 255) / 256;
    const int NB = (N_NODES + 255) / 256;
    hist_kernel<<<EB, 256, 0, stream>>>(dst, deg);
    scan_kernel<<<1, 1024, 0, stream>>>(deg, offsets);
    scatter_kernel<<<EB, 256, 0, stream>>>(src, dst, offsets, cursor, srcSorted);
    bound_kernel<<<NB, 256, 0, stream>>>(batch, gstart);

    const int LB = (N_NODES + 63) / 64;       // lin_kernel grid
    const int AB = (N_NODES + 3) / 4;         // agg_kernel grid

    // layer 0: h = x
    lin_kernel<true><<<LB, 256, 0, stream>>>(x, Wlin, blin, Wc, bc, bufMsg, bufH);
    agg_kernel<<<AB, 256, 0, stream>>>(bufMsg, offsets, srcSorted, t, Wproj, bproj, bufH);
    // layer 1: h = bufH (combine written in place)
    lin_kernel<true><<<LB, 256, 0, stream>>>(bufH, Wlin + 4096, blin + 64, Wc + 4096,
                                             bc + 64, bufMsg, bufH);
    agg_kernel<<<AB, 256, 0, stream>>>(bufMsg, offsets, srcSorted, t + 64, Wproj + 5,
                                       bproj + 1, bufH);
    // global conv message
    lin_kernel<false><<<LB, 256, 0, stream>>>(bufH, gWlin, gblin, nullptr, nullptr,
                                              bufMsg, nullptr);
    gagg_kernel<<<G_GRAPHS, 256, 0, stream>>>(bufMsg, gstart, gt, gWproj, gbproj, emb);
    out_kernel<<<(G_GRAPHS * OUTD + 255) / 256, 256, 0, stream>>>(emb, Wout, bout, out);
}

// Round 2
// 1181.914 us; speedup vs baseline: 1.2082x; 1.2082x over previous
//
#include <hip/hip_runtime.h>
#include <hip/hip_bf16.h>

#define N_NODES 100000
#define E_EDGES 1600000
#define FDIM 64
#define G_GRAPHS 128
#define OUTD 32
#define CAP 32  // edges cached in LDS per node (multiple of 4)

__device__ __forceinline__ float4 f4min(float4 a, float4 b) {
    return make_float4(fminf(a.x,b.x), fminf(a.y,b.y), fminf(a.z,b.z), fminf(a.w,b.w));
}
__device__ __forceinline__ float4 f4max(float4 a, float4 b) {
    return make_float4(fmaxf(a.x,b.x), fmaxf(a.y,b.y), fmaxf(a.z,b.z), fmaxf(a.w,b.w));
}
__device__ __forceinline__ float4 f4add(float4 a, float4 b) {
    return make_float4(a.x+b.x, a.y+b.y, a.z+b.z, a.w+b.w);
}

// ---------------- CSR build ----------------

__global__ __launch_bounds__(256) void hist_kernel(const int* __restrict__ dst,
                                                   int* __restrict__ deg) {
    int e = blockIdx.x * 256 + threadIdx.x;
    if (e < E_EDGES) atomicAdd(&deg[dst[e]], 1);
}

// single-block exclusive scan over N_NODES elements, 1024 threads
__global__ __launch_bounds__(1024) void scan_kernel(const int* __restrict__ deg,
                                                    int* __restrict__ offsets) {
    __shared__ int s[1024];
    const int tid = threadIdx.x;
    const int per = (N_NODES + 1023) / 1024;  // 98
    int lo = tid * per;
    int hi = lo + per; if (hi > N_NODES) hi = N_NODES;
    if (lo > N_NODES) lo = N_NODES;
    int sum = 0;
    for (int i = lo; i < hi; ++i) sum += deg[i];
    s[tid] = sum;
    __syncthreads();
    for (int off = 1; off < 1024; off <<= 1) {
        int v = 0;
        if (tid >= off) v = s[tid - off];
        __syncthreads();
        if (tid >= off) s[tid] += v;
        __syncthreads();
    }
    int pre = s[tid] - sum;
    int run = pre;
    for (int i = lo; i < hi; ++i) { offsets[i] = run; run += deg[i]; }
    if (tid == 1023) offsets[N_NODES] = s[1023];
}

__global__ __launch_bounds__(256) void scatter_kernel(const int* __restrict__ src,
                                                      const int* __restrict__ dst,
                                                      int* __restrict__ cursor,
                                                      int* __restrict__ srcSorted) {
    int e = blockIdx.x * 256 + threadIdx.x;
    if (e < E_EDGES) {
        int pos = atomicAdd(&cursor[dst[e]], 1);
        srcSorted[pos] = src[e];
    }
}

__global__ __launch_bounds__(256) void bound_kernel(const int* __restrict__ batch,
                                                    int* __restrict__ gstart) {
    int i = blockIdx.x * 256 + threadIdx.x;
    if (i < N_NODES) atomicMin(&gstart[batch[i]], i);
}

// ---------------- dual linear: outM = in@Wm.T + bm ; outC = in@Wc.T + bc ----------------
// W rows held in registers (128 VGPR for dual); h rows broadcast from LDS via b128.
// In-place safe when outC == in (rows staged through LDS before writes, blocks
// own disjoint rows).

template <bool DUAL>
__global__ __launch_bounds__(256) void lin_kernel(const float* __restrict__ in,
                                                  const float* __restrict__ Wm,
                                                  const float* __restrict__ bm,
                                                  const float* __restrict__ Wc,
                                                  const float* __restrict__ bc,
                                                  float* __restrict__ outM,
                                                  float* __restrict__ outC) {
    __shared__ __align__(16) float rows[4][64];
    const int tid = threadIdx.x;
    const int f = tid & 63, r = tid >> 6;
    // per-thread W row f in registers
    float4 wm[16], wc[16];
    const float4* Wm4 = (const float4*)(Wm + f * 64);
#pragma unroll
    for (int i = 0; i < 16; ++i) wm[i] = Wm4[i];
    if (DUAL) {
        const float4* Wc4 = (const float4*)(Wc + f * 64);
#pragma unroll
        for (int i = 0; i < 16; ++i) wc[i] = Wc4[i];
    }
    const float bmv = bm[f];
    const float bcv = DUAL ? bc[f] : 0.f;
    const int base = blockIdx.x * 64;
    for (int c = 0; c < 64; c += 4) {
        int node = base + c + r;
        bool ok = node < N_NODES;
        if (ok) rows[r][f] = in[node * 64 + f];
        __syncthreads();
        if (ok) {
            float am = bmv, ac = bcv;
            const float4* rp = (const float4*)rows[r];
#pragma unroll
            for (int k = 0; k < 16; ++k) {
                float4 hv = rp[k];
                am = fmaf(hv.x, wm[k].x, am);
                am = fmaf(hv.y, wm[k].y, am);
                am = fmaf(hv.z, wm[k].z, am);
                am = fmaf(hv.w, wm[k].w, am);
                if (DUAL) {
                    ac = fmaf(hv.x, wc[k].x, ac);
                    ac = fmaf(hv.y, wc[k].y, ac);
                    ac = fmaf(hv.z, wc[k].z, ac);
                    ac = fmaf(hv.w, wc[k].w, ac);
                }
            }
            outM[node * 64 + f] = am;
            if (DUAL) outC[node * 64 + f] = ac;
        }
        __syncthreads();
    }
}

// ---------------- per-node adaptive-relu aggregation ----------------
// wave per node; lane = (edge slot g = lane>>4, feature quad fq = lane&15).
// 4 edges x float4 per iteration; first CAP edges cached in LDS for pass 2.

__global__ __launch_bounds__(256) void agg_kernel(const float* __restrict__ msg,
                                                  const int* __restrict__ offsets,
                                                  const int* __restrict__ srcSorted,
                                                  const float* __restrict__ tptr,
                                                  const float* __restrict__ Wp,
                                                  const float* __restrict__ bp,
                                                  float* __restrict__ hbuf) {
    __shared__ float4 cache[4][CAP][16];  // 32 KB
    const int w = threadIdx.x >> 6;
    const int lane = threadIdx.x & 63;
    const int g = lane >> 4;
    const int fq = lane & 15;
    const int node = blockIdx.x * 4 + w;
    if (node >= N_NODES) return;
    const int start = offsets[node], end = offsets[node + 1];
    const float INF = __builtin_inff();
    float4 mn = make_float4(INF, INF, INF, INF);
    float4 mx = make_float4(-INF, -INF, -INF, -INF);
    float4 sm = make_float4(0.f, 0.f, 0.f, 0.f);
    for (int e = start; e < end; e += 4) {
        int idx = e + g;
        if (idx < end) {
            int sid = srcSorted[idx];
            float4 v = *(const float4*)(msg + (size_t)sid * 64 + 4 * fq);
            int slot = idx - start;
            if (slot < CAP) cache[w][slot][fq] = v;
            mn = f4min(mn, v);
            mx = f4max(mx, v);
            sm = f4add(sm, v);
        }
    }
    // reduce across the 4 edge groups (lanes xor 16, 32)
#pragma unroll
    for (int off = 16; off <= 32; off <<= 1) {
        mn.x = fminf(mn.x, __shfl_xor(mn.x, off)); mn.y = fminf(mn.y, __shfl_xor(mn.y, off));
        mn.z = fminf(mn.z, __shfl_xor(mn.z, off)); mn.w = fminf(mn.w, __shfl_xor(mn.w, off));
        mx.x = fmaxf(mx.x, __shfl_xor(mx.x, off)); mx.y = fmaxf(mx.y, __shfl_xor(mx.y, off));
        mx.z = fmaxf(mx.z, __shfl_xor(mx.z, off)); mx.w = fmaxf(mx.w, __shfl_xor(mx.w, off));
        sm.x += __shfl_xor(sm.x, off); sm.y += __shfl_xor(sm.y, off);
        sm.z += __shfl_xor(sm.z, off); sm.w += __shfl_xor(sm.w, off);
    }
    float4 tv = *(const float4*)(tptr + 4 * fq);
    tv.x = fminf(fmaxf(tv.x, 0.f), 1.f); tv.y = fminf(fmaxf(tv.y, 0.f), 1.f);
    tv.z = fminf(fmaxf(tv.z, 0.f), 1.f); tv.w = fminf(fmaxf(tv.w, 0.f), 1.f);
    float4 bias;
    bias.x = tv.x * mx.x + (1.f - tv.x) * mn.x;
    bias.y = tv.y * mx.y + (1.f - tv.y) * mn.y;
    bias.z = tv.z * mx.z + (1.f - tv.z) * mn.z;
    bias.w = tv.w * mx.w + (1.f - tv.w) * mn.w;
    float4 rs = make_float4(0.f, 0.f, 0.f, 0.f);
    for (int e = start; e < end; e += 4) {
        int idx = e + g;
        if (idx < end) {
            int slot = idx - start;
            float4 v;
            if (slot < CAP) {
                v = cache[w][slot][fq];
            } else {
                int sid = srcSorted[idx];
                v = *(const float4*)(msg + (size_t)sid * 64 + 4 * fq);
            }
            rs.x += fmaxf(v.x - bias.x, 0.f);
            rs.y += fmaxf(v.y - bias.y, 0.f);
            rs.z += fmaxf(v.z - bias.z, 0.f);
            rs.w += fmaxf(v.w - bias.w, 0.f);
        }
    }
#pragma unroll
    for (int off = 16; off <= 32; off <<= 1) {
        rs.x += __shfl_xor(rs.x, off); rs.y += __shfl_xor(rs.y, off);
        rs.z += __shfl_xor(rs.z, off); rs.w += __shfl_xor(rs.w, off);
    }
    if (g == 0) {
        float cnt = (float)(end - start);
        float w0 = Wp[0], w1 = Wp[1], w2 = Wp[2], w3 = Wp[3], w4 = Wp[4], b0 = bp[0];
        float4* hp = (float4*)(hbuf + (size_t)node * 64 + 4 * fq);
        float4 h = *hp;
        h.x += w0 * cnt + w1 * mn.x + w2 * mx.x + w3 * rs.x + w4 * sm.x + b0;
        h.y += w0 * cnt + w1 * mn.y + w2 * mx.y + w3 * rs.y + w4 * sm.y + b0;
        h.z += w0 * cnt + w1 * mn.z + w2 * mx.z + w3 * rs.z + w4 * sm.z + b0;
        h.w += w0 * cnt + w1 * mn.w + w2 * mx.w + w3 * rs.w + w4 * sm.w + b0;
        *hp = h;
    }
}

// ---------------- global pooling: block per graph ----------------

__global__ __launch_bounds__(256) void gagg_kernel(const float* __restrict__ msg,
                                                   const int* __restrict__ gstart,
                                                   const float* __restrict__ gt,
                                                   const float* __restrict__ gWp,
                                                   const float* __restrict__ gbp,
                                                   float* __restrict__ emb) {
    const int g = blockIdx.x;
    const int f = threadIdx.x & 63, r = threadIdx.x >> 6;
    const int start = gstart[g];
    const int end = (g == G_GRAPHS - 1) ? N_NODES : gstart[g + 1];
    float mn = __builtin_inff(), mx = -__builtin_inff(), sm = 0.f;
    for (int i = start + r; i < end; i += 4) {
        float v = msg[(size_t)i * 64 + f];
        mn = fminf(mn, v);
        mx = fmaxf(mx, v);
        sm += v;
    }
    __shared__ float smn[4][64], smx[4][64], ssm[4][64];
    smn[r][f] = mn; smx[r][f] = mx; ssm[r][f] = sm;
    __syncthreads();
    float Mn = fminf(fminf(smn[0][f], smn[1][f]), fminf(smn[2][f], smn[3][f]));
    float Mx = fmaxf(fmaxf(smx[0][f], smx[1][f]), fmaxf(smx[2][f], smx[3][f]));
    float Sm = ssm[0][f] + ssm[1][f] + ssm[2][f] + ssm[3][f];
    float tv = fminf(fmaxf(gt[f], 0.f), 1.f);
    float bias = tv * Mx + (1.f - tv) * Mn;
    float rs = 0.f;
    for (int i = start + r; i < end; i += 4) {
        float v = msg[(size_t)i * 64 + f];
        rs += fmaxf(v - bias, 0.f);
    }
    __syncthreads();
    smn[r][f] = rs;
    __syncthreads();
    if (r == 0) {
        float Rs = smn[0][f] + smn[1][f] + smn[2][f] + smn[3][f];
        float cnt = (float)(end - start);
        emb[g * 64 + f] = gWp[0] * cnt + gWp[1] * Mn + gWp[2] * Mx + gWp[3] * Rs +
                          gWp[4] * Sm + gbp[0];
    }
}

// ---------------- output GEMV ----------------

__global__ __launch_bounds__(256) void out_kernel(const float* __restrict__ emb,
                                                  const float* __restrict__ Wout,
                                                  const float* __restrict__ bout,
                                                  float* __restrict__ out) {
    int i = blockIdx.x * 256 + threadIdx.x;
    if (i >= G_GRAPHS * OUTD) return;
    int g = i >> 5, o = i & 31;
    float a = bout[o];
#pragma unroll
    for (int k = 0; k < 64; ++k) a = fmaf(emb[g * 64 + k], Wout[o * 64 + k], a);
    out[i] = a;
}

// ---------------- launch ----------------

extern "C" void kernel_launch(void* const* d_in, const int* in_sizes, int n_in,
                              void* d_out, int out_size, void* d_ws, size_t ws_size,
                              hipStream_t stream) {
    const float* x     = (const float*)d_in[0];
    const int*   ei    = (const int*)d_in[1];
    const int*   batch = (const int*)d_in[2];
    const float* Wlin  = (const float*)d_in[3];
    const float* blin  = (const float*)d_in[4];
    const float* t     = (const float*)d_in[5];
    const float* Wproj = (const float*)d_in[6];
    const float* bproj = (const float*)d_in[7];
    const float* Wc    = (const float*)d_in[8];
    const float* bc    = (const float*)d_in[9];
    const float* gWlin = (const float*)d_in[10];
    const float* gblin = (const float*)d_in[11];
    const float* gt    = (const float*)d_in[12];
    const float* gWproj= (const float*)d_in[13];
    const float* gbproj= (const float*)d_in[14];
    const float* Wout  = (const float*)d_in[15];
    const float* bout  = (const float*)d_in[16];
    float* out = (float*)d_out;

    const int* src = ei;
    const int* dst = ei + E_EDGES;

    // workspace layout
    char* p = (char*)d_ws;
    float* bufMsg = (float*)p; p += (size_t)N_NODES * FDIM * sizeof(float);
    float* bufH   = (float*)p; p += (size_t)N_NODES * FDIM * sizeof(float);
    float* emb    = (float*)p; p += (size_t)G_GRAPHS * FDIM * sizeof(float);
    int* deg      = (int*)p;   p += (size_t)N_NODES * sizeof(int);
    int* offsets  = (int*)p;   p += (size_t)(N_NODES + 1) * sizeof(int);
    int* cursor   = (int*)p;   p += (size_t)N_NODES * sizeof(int);
    int* gstart   = (int*)p;   p += (size_t)G_GRAPHS * sizeof(int);
    int* srcSorted= (int*)p;   p += (size_t)E_EDGES * sizeof(int);

    hipMemsetAsync(deg, 0, N_NODES * sizeof(int), stream);
    hipMemsetAsync(gstart, 0x7f, G_GRAPHS * sizeof(int), stream);

    const int EB = (E_EDGES + 255) / 256;
    const int NB = (N_NODES + 255) / 256;
    hist_kernel<<<EB, 256, 0, stream>>>(dst, deg);
    scan_kernel<<<1, 1024, 0, stream>>>(deg, offsets);
    hipMemcpyAsync(cursor, offsets, N_NODES * sizeof(int), hipMemcpyDeviceToDevice, stream);
    scatter_kernel<<<EB, 256, 0, stream>>>(src, dst, cursor, srcSorted);
    bound_kernel<<<NB, 256, 0, stream>>>(batch, gstart);

    const int LB = (N_NODES + 63) / 64;
    const int AB = (N_NODES + 3) / 4;

    // layer 0: h = x
    lin_kernel<true><<<LB, 256, 0, stream>>>(x, Wlin, blin, Wc, bc, bufMsg, bufH);
    agg_kernel<<<AB, 256, 0, stream>>>(bufMsg, offsets, srcSorted, t, Wproj, bproj, bufH);
    // layer 1: h = bufH (combine written in place)
    lin_kernel<true><<<LB, 256, 0, stream>>>(bufH, Wlin + 4096, blin + 64, Wc + 4096,
                                             bc + 64, bufMsg, bufH);
    agg_kernel<<<AB, 256, 0, stream>>>(bufMsg, offsets, srcSorted, t + 64, Wproj + 5,
                                       bproj + 1, bufH);
    // global conv message
    lin_kernel<false><<<LB, 256, 0, stream>>>(bufH, gWlin, gblin, nullptr, nullptr,
                                              bufMsg, nullptr);
    gagg_kernel<<<G_GRAPHS, 256, 0, stream>>>(bufMsg, gstart, gt, gWproj, gbproj, emb);
    out_kernel<<<(G_GRAPHS * OUTD + 255) / 256, 256, 0, stream>>>(emb, Wout, bout, out);
}

// Round 3
// 914.665 us; speedup vs baseline: 1.5613x; 1.2922x over previous
//
#include <hip/hip_runtime.h>
#include <hip/hip_bf16.h>

#define N_NODES 100000
#define E_EDGES 1600000
#define FDIM 64
#define G_GRAPHS 128
#define OUTD 32
#define CAP 32  // edges cached in LDS per node (multiple of 8)

__device__ __forceinline__ float4 f4min(float4 a, float4 b) {
    return make_float4(fminf(a.x,b.x), fminf(a.y,b.y), fminf(a.z,b.z), fminf(a.w,b.w));
}
__device__ __forceinline__ float4 f4max(float4 a, float4 b) {
    return make_float4(fmaxf(a.x,b.x), fmaxf(a.y,b.y), fmaxf(a.z,b.z), fmaxf(a.w,b.w));
}
__device__ __forceinline__ float4 f4add(float4 a, float4 b) {
    return make_float4(a.x+b.x, a.y+b.y, a.z+b.z, a.w+b.w);
}

// ---------------- CSR build ----------------

__global__ __launch_bounds__(256) void hist_kernel(const int* __restrict__ dst,
                                                   int* __restrict__ deg) {
    int e = blockIdx.x * 256 + threadIdx.x;
    if (e < E_EDGES) atomicAdd(&deg[dst[e]], 1);
}

// single-block exclusive scan over N_NODES elements, 1024 threads
__global__ __launch_bounds__(1024) void scan_kernel(const int* __restrict__ deg,
                                                    int* __restrict__ offsets) {
    __shared__ int s[1024];
    const int tid = threadIdx.x;
    const int per = (N_NODES + 1023) / 1024;  // 98
    int lo = tid * per;
    int hi = lo + per; if (hi > N_NODES) hi = N_NODES;
    if (lo > N_NODES) lo = N_NODES;
    int sum = 0;
    for (int i = lo; i < hi; ++i) sum += deg[i];
    s[tid] = sum;
    __syncthreads();
    for (int off = 1; off < 1024; off <<= 1) {
        int v = 0;
        if (tid >= off) v = s[tid - off];
        __syncthreads();
        if (tid >= off) s[tid] += v;
        __syncthreads();
    }
    int pre = s[tid] - sum;
    int run = pre;
    for (int i = lo; i < hi; ++i) { offsets[i] = run; run += deg[i]; }
    if (tid == 1023) offsets[N_NODES] = s[1023];
}

__global__ __launch_bounds__(256) void scatter_kernel(const int* __restrict__ src,
                                                      const int* __restrict__ dst,
                                                      int* __restrict__ cursor,
                                                      int* __restrict__ srcSorted) {
    int e = blockIdx.x * 256 + threadIdx.x;
    if (e < E_EDGES) {
        int pos = atomicAdd(&cursor[dst[e]], 1);
        srcSorted[pos] = src[e];
    }
}

// batch is sorted -> graph g starts where batch changes value. No atomics.
__global__ __launch_bounds__(256) void bound_kernel(const int* __restrict__ batch,
                                                    int* __restrict__ gstart) {
    int i = blockIdx.x * 256 + threadIdx.x;
    if (i >= N_NODES) return;
    if (i == 0) {
        gstart[batch[0]] = 0;  // batch sorted, batch[0] == 0
    } else {
        int b = batch[i], pb = batch[i - 1];
        if (b != pb) gstart[b] = i;
    }
}

// ---------------- dual linear: outM = in@Wm.T + bm ; outC = in@Wc.T + bc ----------------
// W rows held in registers; h rows broadcast from LDS via b128.
// In-place safe when outC == in (rows staged through LDS before writes).

template <bool DUAL>
__global__ __launch_bounds__(256) void lin_kernel(const float* __restrict__ in,
                                                  const float* __restrict__ Wm,
                                                  const float* __restrict__ bm,
                                                  const float* __restrict__ Wc,
                                                  const float* __restrict__ bc,
                                                  float* __restrict__ outM,
                                                  float* __restrict__ outC) {
    __shared__ __align__(16) float rows[4][64];
    const int tid = threadIdx.x;
    const int f = tid & 63, r = tid >> 6;
    float4 wm[16], wc[16];
    const float4* Wm4 = (const float4*)(Wm + f * 64);
#pragma unroll
    for (int i = 0; i < 16; ++i) wm[i] = Wm4[i];
    if (DUAL) {
        const float4* Wc4 = (const float4*)(Wc + f * 64);
#pragma unroll
        for (int i = 0; i < 16; ++i) wc[i] = Wc4[i];
    }
    const float bmv = bm[f];
    const float bcv = DUAL ? bc[f] : 0.f;
    const int base = blockIdx.x * 64;
    for (int c = 0; c < 64; c += 4) {
        int node = base + c + r;
        bool ok = node < N_NODES;
        if (ok) rows[r][f] = in[node * 64 + f];
        __syncthreads();
        if (ok) {
            float am = bmv, ac = bcv;
            const float4* rp = (const float4*)rows[r];
#pragma unroll
            for (int k = 0; k < 16; ++k) {
                float4 hv = rp[k];
                am = fmaf(hv.x, wm[k].x, am);
                am = fmaf(hv.y, wm[k].y, am);
                am = fmaf(hv.z, wm[k].z, am);
                am = fmaf(hv.w, wm[k].w, am);
                if (DUAL) {
                    ac = fmaf(hv.x, wc[k].x, ac);
                    ac = fmaf(hv.y, wc[k].y, ac);
                    ac = fmaf(hv.z, wc[k].z, ac);
                    ac = fmaf(hv.w, wc[k].w, ac);
                }
            }
            outM[node * 64 + f] = am;
            if (DUAL) outC[node * 64 + f] = ac;
        }
        __syncthreads();
    }
}

// ---------------- per-node adaptive-relu aggregation ----------------
// wave per node; lane = (edge group g = lane>>4, feature quad fq = lane&15).
// 8 edges x float4 in flight per iteration; first CAP edges cached in LDS.

__global__ __launch_bounds__(256) void agg_kernel(const float* __restrict__ msg,
                                                  const int* __restrict__ offsets,
                                                  const int* __restrict__ srcSorted,
                                                  const float* __restrict__ tptr,
                                                  const float* __restrict__ Wp,
                                                  const float* __restrict__ bp,
                                                  float* __restrict__ hbuf) {
    __shared__ float4 cache[4][CAP][16];  // 32 KB
    const int w = threadIdx.x >> 6;
    const int lane = threadIdx.x & 63;
    const int g = lane >> 4;
    const int fq = lane & 15;
    const int node = blockIdx.x * 4 + w;
    if (node >= N_NODES) return;
    const int start = offsets[node], end = offsets[node + 1];
    const float INF = __builtin_inff();
    float4 mn = make_float4(INF, INF, INF, INF);
    float4 mx = make_float4(-INF, -INF, -INF, -INF);
    float4 sm = make_float4(0.f, 0.f, 0.f, 0.f);
    for (int e = start; e < end; e += 8) {
        int i0 = e + g, i1 = e + 4 + g;
        bool ok0 = i0 < end, ok1 = i1 < end;
        int s0 = 0, s1 = 0;
        if (ok0) s0 = srcSorted[i0];
        if (ok1) s1 = srcSorted[i1];
        float4 v0, v1;
        if (ok0) v0 = *(const float4*)(msg + (size_t)s0 * 64 + 4 * fq);
        if (ok1) v1 = *(const float4*)(msg + (size_t)s1 * 64 + 4 * fq);
        if (ok0) {
            int slot = i0 - start;
            if (slot < CAP) cache[w][slot][fq] = v0;
            mn = f4min(mn, v0); mx = f4max(mx, v0); sm = f4add(sm, v0);
        }
        if (ok1) {
            int slot = i1 - start;
            if (slot < CAP) cache[w][slot][fq] = v1;
            mn = f4min(mn, v1); mx = f4max(mx, v1); sm = f4add(sm, v1);
        }
    }
#pragma unroll
    for (int off = 16; off <= 32; off <<= 1) {
        mn.x = fminf(mn.x, __shfl_xor(mn.x, off)); mn.y = fminf(mn.y, __shfl_xor(mn.y, off));
        mn.z = fminf(mn.z, __shfl_xor(mn.z, off)); mn.w = fminf(mn.w, __shfl_xor(mn.w, off));
        mx.x = fmaxf(mx.x, __shfl_xor(mx.x, off)); mx.y = fmaxf(mx.y, __shfl_xor(mx.y, off));
        mx.z = fmaxf(mx.z, __shfl_xor(mx.z, off)); mx.w = fmaxf(mx.w, __shfl_xor(mx.w, off));
        sm.x += __shfl_xor(sm.x, off); sm.y += __shfl_xor(sm.y, off);
        sm.z += __shfl_xor(sm.z, off); sm.w += __shfl_xor(sm.w, off);
    }
    float4 tv = *(const float4*)(tptr + 4 * fq);
    tv.x = fminf(fmaxf(tv.x, 0.f), 1.f); tv.y = fminf(fmaxf(tv.y, 0.f), 1.f);
    tv.z = fminf(fmaxf(tv.z, 0.f), 1.f); tv.w = fminf(fmaxf(tv.w, 0.f), 1.f);
    float4 bias;
    bias.x = tv.x * mx.x + (1.f - tv.x) * mn.x;
    bias.y = tv.y * mx.y + (1.f - tv.y) * mn.y;
    bias.z = tv.z * mx.z + (1.f - tv.z) * mn.z;
    bias.w = tv.w * mx.w + (1.f - tv.w) * mn.w;
    float4 rs = make_float4(0.f, 0.f, 0.f, 0.f);
    for (int e = start; e < end; e += 8) {
        int i0 = e + g, i1 = e + 4 + g;
        bool ok0 = i0 < end, ok1 = i1 < end;
        float4 v0, v1;
        if (ok0) {
            int slot = i0 - start;
            if (slot < CAP) v0 = cache[w][slot][fq];
            else v0 = *(const float4*)(msg + (size_t)srcSorted[i0] * 64 + 4 * fq);
        }
        if (ok1) {
            int slot = i1 - start;
            if (slot < CAP) v1 = cache[w][slot][fq];
            else v1 = *(const float4*)(msg + (size_t)srcSorted[i1] * 64 + 4 * fq);
        }
        if (ok0) {
            rs.x += fmaxf(v0.x - bias.x, 0.f); rs.y += fmaxf(v0.y - bias.y, 0.f);
            rs.z += fmaxf(v0.z - bias.z, 0.f); rs.w += fmaxf(v0.w - bias.w, 0.f);
        }
        if (ok1) {
            rs.x += fmaxf(v1.x - bias.x, 0.f); rs.y += fmaxf(v1.y - bias.y, 0.f);
            rs.z += fmaxf(v1.z - bias.z, 0.f); rs.w += fmaxf(v1.w - bias.w, 0.f);
        }
    }
#pragma unroll
    for (int off = 16; off <= 32; off <<= 1) {
        rs.x += __shfl_xor(rs.x, off); rs.y += __shfl_xor(rs.y, off);
        rs.z += __shfl_xor(rs.z, off); rs.w += __shfl_xor(rs.w, off);
    }
    if (g == 0) {
        float cnt = (float)(end - start);
        float w0 = Wp[0], w1 = Wp[1], w2 = Wp[2], w3 = Wp[3], w4 = Wp[4], b0 = bp[0];
        float4* hp = (float4*)(hbuf + (size_t)node * 64 + 4 * fq);
        float4 h = *hp;
        h.x += w0 * cnt + w1 * mn.x + w2 * mx.x + w3 * rs.x + w4 * sm.x + b0;
        h.y += w0 * cnt + w1 * mn.y + w2 * mx.y + w3 * rs.y + w4 * sm.y + b0;
        h.z += w0 * cnt + w1 * mn.z + w2 * mx.z + w3 * rs.z + w4 * sm.z + b0;
        h.w += w0 * cnt + w1 * mn.w + w2 * mx.w + w3 * rs.w + w4 * sm.w + b0;
        *hp = h;
    }
}

// ---------------- global pooling: block per graph ----------------

__global__ __launch_bounds__(256) void gagg_kernel(const float* __restrict__ msg,
                                                   const int* __restrict__ gstart,
                                                   const float* __restrict__ gt,
                                                   const float* __restrict__ gWp,
                                                   const float* __restrict__ gbp,
                                                   float* __restrict__ emb) {
    const int g = blockIdx.x;
    const int f = threadIdx.x & 63, r = threadIdx.x >> 6;
    const int start = gstart[g];
    const int end = (g == G_GRAPHS - 1) ? N_NODES : gstart[g + 1];
    float mn = __builtin_inff(), mx = -__builtin_inff(), sm = 0.f;
    for (int i = start + r; i < end; i += 4) {
        float v = msg[(size_t)i * 64 + f];
        mn = fminf(mn, v);
        mx = fmaxf(mx, v);
        sm += v;
    }
    __shared__ float smn[4][64], smx[4][64], ssm[4][64];
    smn[r][f] = mn; smx[r][f] = mx; ssm[r][f] = sm;
    __syncthreads();
    float Mn = fminf(fminf(smn[0][f], smn[1][f]), fminf(smn[2][f], smn[3][f]));
    float Mx = fmaxf(fmaxf(smx[0][f], smx[1][f]), fmaxf(smx[2][f], smx[3][f]));
    float Sm = ssm[0][f] + ssm[1][f] + ssm[2][f] + ssm[3][f];
    float tv = fminf(fmaxf(gt[f], 0.f), 1.f);
    float bias = tv * Mx + (1.f - tv) * Mn;
    float rs = 0.f;
    for (int i = start + r; i < end; i += 4) {
        float v = msg[(size_t)i * 64 + f];
        rs += fmaxf(v - bias, 0.f);
    }
    __syncthreads();
    smn[r][f] = rs;
    __syncthreads();
    if (r == 0) {
        float Rs = smn[0][f] + smn[1][f] + smn[2][f] + smn[3][f];
        float cnt = (float)(end - start);
        emb[g * 64 + f] = gWp[0] * cnt + gWp[1] * Mn + gWp[2] * Mx + gWp[3] * Rs +
                          gWp[4] * Sm + gbp[0];
    }
}

// ---------------- output GEMV ----------------

__global__ __launch_bounds__(256) void out_kernel(const float* __restrict__ emb,
                                                  const float* __restrict__ Wout,
                                                  const float* __restrict__ bout,
                                                  float* __restrict__ out) {
    int i = blockIdx.x * 256 + threadIdx.x;
    if (i >= G_GRAPHS * OUTD) return;
    int g = i >> 5, o = i & 31;
    float a = bout[o];
#pragma unroll
    for (int k = 0; k < 64; ++k) a = fmaf(emb[g * 64 + k], Wout[o * 64 + k], a);
    out[i] = a;
}

// ---------------- launch ----------------

extern "C" void kernel_launch(void* const* d_in, const int* in_sizes, int n_in,
                              void* d_out, int out_size, void* d_ws, size_t ws_size,
                              hipStream_t stream) {
    const float* x     = (const float*)d_in[0];
    const int*   ei    = (const int*)d_in[1];
    const int*   batch = (const int*)d_in[2];
    const float* Wlin  = (const float*)d_in[3];
    const float* blin  = (const float*)d_in[4];
    const float* t     = (const float*)d_in[5];
    const float* Wproj = (const float*)d_in[6];
    const float* bproj = (const float*)d_in[7];
    const float* Wc    = (const float*)d_in[8];
    const float* bc    = (const float*)d_in[9];
    const float* gWlin = (const float*)d_in[10];
    const float* gblin = (const float*)d_in[11];
    const float* gt    = (const float*)d_in[12];
    const float* gWproj= (const float*)d_in[13];
    const float* gbproj= (const float*)d_in[14];
    const float* Wout  = (const float*)d_in[15];
    const float* bout  = (const float*)d_in[16];
    float* out = (float*)d_out;

    const int* src = ei;
    const int* dst = ei + E_EDGES;

    // workspace layout
    char* p = (char*)d_ws;
    float* bufMsg = (float*)p; p += (size_t)N_NODES * FDIM * sizeof(float);
    float* bufH   = (float*)p; p += (size_t)N_NODES * FDIM * sizeof(float);
    float* emb    = (float*)p; p += (size_t)G_GRAPHS * FDIM * sizeof(float);
    int* deg      = (int*)p;   p += (size_t)N_NODES * sizeof(int);
    int* offsets  = (int*)p;   p += (size_t)(N_NODES + 1) * sizeof(int);
    int* cursor   = (int*)p;   p += (size_t)N_NODES * sizeof(int);
    int* gstart   = (int*)p;   p += (size_t)G_GRAPHS * sizeof(int);
    int* srcSorted= (int*)p;   p += (size_t)E_EDGES * sizeof(int);

    hipMemsetAsync(deg, 0, N_NODES * sizeof(int), stream);

    const int EB = (E_EDGES + 255) / 256;
    const int NB = (N_NODES + 255) / 256;
    hist_kernel<<<EB, 256, 0, stream>>>(dst, deg);
    scan_kernel<<<1, 1024, 0, stream>>>(deg, offsets);
    hipMemcpyAsync(cursor, offsets, N_NODES * sizeof(int), hipMemcpyDeviceToDevice, stream);
    scatter_kernel<<<EB, 256, 0, stream>>>(src, dst, cursor, srcSorted);
    bound_kernel<<<NB, 256, 0, stream>>>(batch, gstart);

    const int LB = (N_NODES + 63) / 64;
    const int AB = (N_NODES + 3) / 4;

    // layer 0: h = x
    lin_kernel<true><<<LB, 256, 0, stream>>>(x, Wlin, blin, Wc, bc, bufMsg, bufH);
    agg_kernel<<<AB, 256, 0, stream>>>(bufMsg, offsets, srcSorted, t, Wproj, bproj, bufH);
    // layer 1: h = bufH (combine written in place)
    lin_kernel<true><<<LB, 256, 0, stream>>>(bufH, Wlin + 4096, blin + 64, Wc + 4096,
                                             bc + 64, bufMsg, bufH);
    agg_kernel<<<AB, 256, 0, stream>>>(bufMsg, offsets, srcSorted, t + 64, Wproj + 5,
                                       bproj + 1, bufH);
    // global conv message
    lin_kernel<false><<<LB, 256, 0, stream>>>(bufH, gWlin, gblin, nullptr, nullptr,
                                              bufMsg, nullptr);
    gagg_kernel<<<G_GRAPHS, 256, 0, stream>>>(bufMsg, gstart, gt, gWproj, gbproj, emb);
    out_kernel<<<(G_GRAPHS * OUTD + 255) / 256, 256, 0, stream>>>(emb, Wout, bout, out);
}

// Round 4
// 764.292 us; speedup vs baseline: 1.8684x; 1.1967x over previous
//
#include <hip/hip_runtime.h>
#include <hip/hip_bf16.h>

#define N_NODES 100000
#define E_EDGES 1600000
#define FDIM 64
#define G_GRAPHS 128
#define OUTD 32
#define CAP 32        // edges cached in LDS per node (multiple of 8)
#define SCHUNK 2048   // scan: elements per block (256 threads x 8)
#define NCHUNK ((N_NODES + SCHUNK - 1) / SCHUNK)  // 49 (<= 64)

__device__ __forceinline__ float4 f4min(float4 a, float4 b) {
    return make_float4(fminf(a.x,b.x), fminf(a.y,b.y), fminf(a.z,b.z), fminf(a.w,b.w));
}
__device__ __forceinline__ float4 f4max(float4 a, float4 b) {
    return make_float4(fmaxf(a.x,b.x), fmaxf(a.y,b.y), fmaxf(a.z,b.z), fmaxf(a.w,b.w));
}
__device__ __forceinline__ float4 f4add(float4 a, float4 b) {
    return make_float4(a.x+b.x, a.y+b.y, a.z+b.z, a.w+b.w);
}

// ---------------- CSR build ----------------

__global__ __launch_bounds__(256) void hist_kernel(const int* __restrict__ dst,
                                                   int* __restrict__ deg) {
    int e = blockIdx.x * 256 + threadIdx.x;
    if (e < E_EDGES) atomicAdd(&deg[dst[e]], 1);
}

// scan phase A: per-block chunk sums
__global__ __launch_bounds__(256) void scanA_kernel(const int* __restrict__ deg,
                                                    int* __restrict__ blockSums) {
    const int tid = threadIdx.x;
    const int base = blockIdx.x * SCHUNK + tid * 8;
    int s = 0;
#pragma unroll
    for (int i = 0; i < 8; ++i) {
        int idx = base + i;
        if (idx < N_NODES) s += deg[idx];
    }
#pragma unroll
    for (int off = 32; off > 0; off >>= 1) s += __shfl_xor(s, off);
    __shared__ int ws[4];
    if ((tid & 63) == 0) ws[tid >> 6] = s;
    __syncthreads();
    if (tid == 0) blockSums[blockIdx.x] = ws[0] + ws[1] + ws[2] + ws[3];
}

// scan phase B: one wave scans the (<=64) block sums
__global__ __launch_bounds__(64) void scanB_kernel(const int* __restrict__ blockSums,
                                                   int* __restrict__ blockPrefix,
                                                   int* __restrict__ offsets) {
    int lane = threadIdx.x;
    int v = (lane < NCHUNK) ? blockSums[lane] : 0;
    int incl = v;
#pragma unroll
    for (int off = 1; off < 64; off <<= 1) {
        int o = __shfl_up(incl, off);
        if (lane >= off) incl += o;
    }
    if (lane < NCHUNK) blockPrefix[lane] = incl - v;
    if (lane == 63) offsets[N_NODES] = incl;  // total edge count
}

// scan phase C: per-thread 8-elem scan + wave scan + block prefix -> offsets
__global__ __launch_bounds__(256) void scanC_kernel(const int* __restrict__ deg,
                                                    const int* __restrict__ blockPrefix,
                                                    int* __restrict__ offsets) {
    const int tid = threadIdx.x;
    const int lane = tid & 63, wv = tid >> 6;
    const int base = blockIdx.x * SCHUNK + tid * 8;
    int v[8];
    int s = 0;
#pragma unroll
    for (int i = 0; i < 8; ++i) {
        int idx = base + i;
        v[i] = (idx < N_NODES) ? deg[idx] : 0;
        s += v[i];
    }
    int incl = s;
#pragma unroll
    for (int off = 1; off < 64; off <<= 1) {
        int o = __shfl_up(incl, off);
        if (lane >= off) incl += o;
    }
    __shared__ int ws[4];
    if (lane == 63) ws[wv] = incl;
    __syncthreads();
    int wPre = 0;
    for (int w = 0; w < 4; ++w) wPre += (w < wv) ? ws[w] : 0;
    int run = blockPrefix[blockIdx.x] + wPre + (incl - s);
#pragma unroll
    for (int i = 0; i < 8; ++i) {
        int idx = base + i;
        if (idx < N_NODES) offsets[idx] = run;
        run += v[i];
    }
}

__global__ __launch_bounds__(256) void scatter_kernel(const int* __restrict__ src,
                                                      const int* __restrict__ dst,
                                                      int* __restrict__ cursor,
                                                      int* __restrict__ srcSorted) {
    int e = blockIdx.x * 256 + threadIdx.x;
    if (e < E_EDGES) {
        int pos = atomicAdd(&cursor[dst[e]], 1);
        srcSorted[pos] = src[e];
    }
}

// batch is sorted -> graph g starts where batch changes value. No atomics.
__global__ __launch_bounds__(256) void bound_kernel(const int* __restrict__ batch,
                                                    int* __restrict__ gstart) {
    int i = blockIdx.x * 256 + threadIdx.x;
    if (i >= N_NODES) return;
    if (i == 0) {
        gstart[batch[0]] = 0;
    } else {
        int b = batch[i], pb = batch[i - 1];
        if (b != pb) gstart[b] = i;
    }
}

// ---------------- dual linear: outM = in@Wm.T + bm ; outC = in@Wc.T + bc ----------------

template <bool DUAL>
__global__ __launch_bounds__(256) void lin_kernel(const float* __restrict__ in,
                                                  const float* __restrict__ Wm,
                                                  const float* __restrict__ bm,
                                                  const float* __restrict__ Wc,
                                                  const float* __restrict__ bc,
                                                  float* __restrict__ outM,
                                                  float* __restrict__ outC) {
    __shared__ __align__(16) float rows[4][64];
    const int tid = threadIdx.x;
    const int f = tid & 63, r = tid >> 6;
    float4 wm[16], wc[16];
    const float4* Wm4 = (const float4*)(Wm + f * 64);
#pragma unroll
    for (int i = 0; i < 16; ++i) wm[i] = Wm4[i];
    if (DUAL) {
        const float4* Wc4 = (const float4*)(Wc + f * 64);
#pragma unroll
        for (int i = 0; i < 16; ++i) wc[i] = Wc4[i];
    }
    const float bmv = bm[f];
    const float bcv = DUAL ? bc[f] : 0.f;
    const int base = blockIdx.x * 64;
    for (int c = 0; c < 64; c += 4) {
        int node = base + c + r;
        bool ok = node < N_NODES;
        if (ok) rows[r][f] = in[node * 64 + f];
        __syncthreads();
        if (ok) {
            float am = bmv, ac = bcv;
            const float4* rp = (const float4*)rows[r];
#pragma unroll
            for (int k = 0; k < 16; ++k) {
                float4 hv = rp[k];
                am = fmaf(hv.x, wm[k].x, am);
                am = fmaf(hv.y, wm[k].y, am);
                am = fmaf(hv.z, wm[k].z, am);
                am = fmaf(hv.w, wm[k].w, am);
                if (DUAL) {
                    ac = fmaf(hv.x, wc[k].x, ac);
                    ac = fmaf(hv.y, wc[k].y, ac);
                    ac = fmaf(hv.z, wc[k].z, ac);
                    ac = fmaf(hv.w, wc[k].w, ac);
                }
            }
            outM[node * 64 + f] = am;
            if (DUAL) outC[node * 64 + f] = ac;
        }
        __syncthreads();
    }
}

// ---------------- per-node adaptive-relu aggregation ----------------

__global__ __launch_bounds__(256) void agg_kernel(const float* __restrict__ msg,
                                                  const int* __restrict__ offsets,
                                                  const int* __restrict__ srcSorted,
                                                  const float* __restrict__ tptr,
                                                  const float* __restrict__ Wp,
                                                  const float* __restrict__ bp,
                                                  float* __restrict__ hbuf) {
    __shared__ float4 cache[4][CAP][16];  // 32 KB
    const int w = threadIdx.x >> 6;
    const int lane = threadIdx.x & 63;
    const int g = lane >> 4;
    const int fq = lane & 15;
    const int node = blockIdx.x * 4 + w;
    if (node >= N_NODES) return;
    const int start = offsets[node], end = offsets[node + 1];
    const float INF = __builtin_inff();
    float4 mn = make_float4(INF, INF, INF, INF);
    float4 mx = make_float4(-INF, -INF, -INF, -INF);
    float4 sm = make_float4(0.f, 0.f, 0.f, 0.f);
    for (int e = start; e < end; e += 8) {
        int i0 = e + g, i1 = e + 4 + g;
        bool ok0 = i0 < end, ok1 = i1 < end;
        int s0 = 0, s1 = 0;
        if (ok0) s0 = srcSorted[i0];
        if (ok1) s1 = srcSorted[i1];
        float4 v0, v1;
        if (ok0) v0 = *(const float4*)(msg + (size_t)s0 * 64 + 4 * fq);
        if (ok1) v1 = *(const float4*)(msg + (size_t)s1 * 64 + 4 * fq);
        if (ok0) {
            int slot = i0 - start;
            if (slot < CAP) cache[w][slot][fq] = v0;
            mn = f4min(mn, v0); mx = f4max(mx, v0); sm = f4add(sm, v0);
        }
        if (ok1) {
            int slot = i1 - start;
            if (slot < CAP) cache[w][slot][fq] = v1;
            mn = f4min(mn, v1); mx = f4max(mx, v1); sm = f4add(sm, v1);
        }
    }
#pragma unroll
    for (int off = 16; off <= 32; off <<= 1) {
        mn.x = fminf(mn.x, __shfl_xor(mn.x, off)); mn.y = fminf(mn.y, __shfl_xor(mn.y, off));
        mn.z = fminf(mn.z, __shfl_xor(mn.z, off)); mn.w = fminf(mn.w, __shfl_xor(mn.w, off));
        mx.x = fmaxf(mx.x, __shfl_xor(mx.x, off)); mx.y = fmaxf(mx.y, __shfl_xor(mx.y, off));
        mx.z = fmaxf(mx.z, __shfl_xor(mx.z, off)); mx.w = fmaxf(mx.w, __shfl_xor(mx.w, off));
        sm.x += __shfl_xor(sm.x, off); sm.y += __shfl_xor(sm.y, off);
        sm.z += __shfl_xor(sm.z, off); sm.w += __shfl_xor(sm.w, off);
    }
    float4 tv = *(const float4*)(tptr + 4 * fq);
    tv.x = fminf(fmaxf(tv.x, 0.f), 1.f); tv.y = fminf(fmaxf(tv.y, 0.f), 1.f);
    tv.z = fminf(fmaxf(tv.z, 0.f), 1.f); tv.w = fminf(fmaxf(tv.w, 0.f), 1.f);
    float4 bias;
    bias.x = tv.x * mx.x + (1.f - tv.x) * mn.x;
    bias.y = tv.y * mx.y + (1.f - tv.y) * mn.y;
    bias.z = tv.z * mx.z + (1.f - tv.z) * mn.z;
    bias.w = tv.w * mx.w + (1.f - tv.w) * mn.w;
    float4 rs = make_float4(0.f, 0.f, 0.f, 0.f);
    for (int e = start; e < end; e += 8) {
        int i0 = e + g, i1 = e + 4 + g;
        bool ok0 = i0 < end, ok1 = i1 < end;
        float4 v0, v1;
        if (ok0) {
            int slot = i0 - start;
            if (slot < CAP) v0 = cache[w][slot][fq];
            else v0 = *(const float4*)(msg + (size_t)srcSorted[i0] * 64 + 4 * fq);
        }
        if (ok1) {
            int slot = i1 - start;
            if (slot < CAP) v1 = cache[w][slot][fq];
            else v1 = *(const float4*)(msg + (size_t)srcSorted[i1] * 64 + 4 * fq);
        }
        if (ok0) {
            rs.x += fmaxf(v0.x - bias.x, 0.f); rs.y += fmaxf(v0.y - bias.y, 0.f);
            rs.z += fmaxf(v0.z - bias.z, 0.f); rs.w += fmaxf(v0.w - bias.w, 0.f);
        }
        if (ok1) {
            rs.x += fmaxf(v1.x - bias.x, 0.f); rs.y += fmaxf(v1.y - bias.y, 0.f);
            rs.z += fmaxf(v1.z - bias.z, 0.f); rs.w += fmaxf(v1.w - bias.w, 0.f);
        }
    }
#pragma unroll
    for (int off = 16; off <= 32; off <<= 1) {
        rs.x += __shfl_xor(rs.x, off); rs.y += __shfl_xor(rs.y, off);
        rs.z += __shfl_xor(rs.z, off); rs.w += __shfl_xor(rs.w, off);
    }
    if (g == 0) {
        float cnt = (float)(end - start);
        float w0 = Wp[0], w1 = Wp[1], w2 = Wp[2], w3 = Wp[3], w4 = Wp[4], b0 = bp[0];
        float4* hp = (float4*)(hbuf + (size_t)node * 64 + 4 * fq);
        float4 h = *hp;
        h.x += w0 * cnt + w1 * mn.x + w2 * mx.x + w3 * rs.x + w4 * sm.x + b0;
        h.y += w0 * cnt + w1 * mn.y + w2 * mx.y + w3 * rs.y + w4 * sm.y + b0;
        h.z += w0 * cnt + w1 * mn.z + w2 * mx.z + w3 * rs.z + w4 * sm.z + b0;
        h.w += w0 * cnt + w1 * mn.w + w2 * mx.w + w3 * rs.w + w4 * sm.w + b0;
        *hp = h;
    }
}

// ---------------- global pooling: block per graph ----------------

__global__ __launch_bounds__(256) void gagg_kernel(const float* __restrict__ msg,
                                                   const int* __restrict__ gstart,
                                                   const float* __restrict__ gt,
                                                   const float* __restrict__ gWp,
                                                   const float* __restrict__ gbp,
                                                   float* __restrict__ emb) {
    const int g = blockIdx.x;
    const int f = threadIdx.x & 63, r = threadIdx.x >> 6;
    const int start = gstart[g];
    const int end = (g == G_GRAPHS - 1) ? N_NODES : gstart[g + 1];
    float mn = __builtin_inff(), mx = -__builtin_inff(), sm = 0.f;
    for (int i = start + r; i < end; i += 4) {
        float v = msg[(size_t)i * 64 + f];
        mn = fminf(mn, v);
        mx = fmaxf(mx, v);
        sm += v;
    }
    __shared__ float smn[4][64], smx[4][64], ssm[4][64];
    smn[r][f] = mn; smx[r][f] = mx; ssm[r][f] = sm;
    __syncthreads();
    float Mn = fminf(fminf(smn[0][f], smn[1][f]), fminf(smn[2][f], smn[3][f]));
    float Mx = fmaxf(fmaxf(smx[0][f], smx[1][f]), fmaxf(smx[2][f], smx[3][f]));
    float Sm = ssm[0][f] + ssm[1][f] + ssm[2][f] + ssm[3][f];
    float tv = fminf(fmaxf(gt[f], 0.f), 1.f);
    float bias = tv * Mx + (1.f - tv) * Mn;
    float rs = 0.f;
    for (int i = start + r; i < end; i += 4) {
        float v = msg[(size_t)i * 64 + f];
        rs += fmaxf(v - bias, 0.f);
    }
    __syncthreads();
    smn[r][f] = rs;
    __syncthreads();
    if (r == 0) {
        float Rs = smn[0][f] + smn[1][f] + smn[2][f] + smn[3][f];
        float cnt = (float)(end - start);
        emb[g * 64 + f] = gWp[0] * cnt + gWp[1] * Mn + gWp[2] * Mx + gWp[3] * Rs +
                          gWp[4] * Sm + gbp[0];
    }
}

// ---------------- output GEMV ----------------

__global__ __launch_bounds__(256) void out_kernel(const float* __restrict__ emb,
                                                  const float* __restrict__ Wout,
                                                  const float* __restrict__ bout,
                                                  float* __restrict__ out) {
    int i = blockIdx.x * 256 + threadIdx.x;
    if (i >= G_GRAPHS * OUTD) return;
    int g = i >> 5, o = i & 31;
    float a = bout[o];
#pragma unroll
    for (int k = 0; k < 64; ++k) a = fmaf(emb[g * 64 + k], Wout[o * 64 + k], a);
    out[i] = a;
}

// ---------------- launch ----------------

extern "C" void kernel_launch(void* const* d_in, const int* in_sizes, int n_in,
                              void* d_out, int out_size, void* d_ws, size_t ws_size,
                              hipStream_t stream) {
    const float* x     = (const float*)d_in[0];
    const int*   ei    = (const int*)d_in[1];
    const int*   batch = (const int*)d_in[2];
    const float* Wlin  = (const float*)d_in[3];
    const float* blin  = (const float*)d_in[4];
    const float* t     = (const float*)d_in[5];
    const float* Wproj = (const float*)d_in[6];
    const float* bproj = (const float*)d_in[7];
    const float* Wc    = (const float*)d_in[8];
    const float* bc    = (const float*)d_in[9];
    const float* gWlin = (const float*)d_in[10];
    const float* gblin = (const float*)d_in[11];
    const float* gt    = (const float*)d_in[12];
    const float* gWproj= (const float*)d_in[13];
    const float* gbproj= (const float*)d_in[14];
    const float* Wout  = (const float*)d_in[15];
    const float* bout  = (const float*)d_in[16];
    float* out = (float*)d_out;

    const int* src = ei;
    const int* dst = ei + E_EDGES;

    // workspace layout
    char* p = (char*)d_ws;
    float* bufMsg = (float*)p; p += (size_t)N_NODES * FDIM * sizeof(float);
    float* bufH   = (float*)p; p += (size_t)N_NODES * FDIM * sizeof(float);
    float* emb    = (float*)p; p += (size_t)G_GRAPHS * FDIM * sizeof(float);
    int* deg      = (int*)p;   p += (size_t)N_NODES * sizeof(int);
    int* offsets  = (int*)p;   p += (size_t)(N_NODES + 1) * sizeof(int);
    int* cursor   = (int*)p;   p += (size_t)N_NODES * sizeof(int);
    int* gstart   = (int*)p;   p += (size_t)G_GRAPHS * sizeof(int);
    int* blockSums= (int*)p;   p += (size_t)NCHUNK * sizeof(int);
    int* blockPre = (int*)p;   p += (size_t)(NCHUNK + 1) * sizeof(int);
    int* srcSorted= (int*)p;   p += (size_t)E_EDGES * sizeof(int);

    hipMemsetAsync(deg, 0, N_NODES * sizeof(int), stream);

    const int EB = (E_EDGES + 255) / 256;
    const int NB = (N_NODES + 255) / 256;
    hist_kernel<<<EB, 256, 0, stream>>>(dst, deg);
    scanA_kernel<<<NCHUNK, 256, 0, stream>>>(deg, blockSums);
    scanB_kernel<<<1, 64, 0, stream>>>(blockSums, blockPre, offsets);
    scanC_kernel<<<NCHUNK, 256, 0, stream>>>(deg, blockPre, offsets);
    hipMemcpyAsync(cursor, offsets, N_NODES * sizeof(int), hipMemcpyDeviceToDevice, stream);
    scatter_kernel<<<EB, 256, 0, stream>>>(src, dst, cursor, srcSorted);
    bound_kernel<<<NB, 256, 0, stream>>>(batch, gstart);

    const int LB = (N_NODES + 63) / 64;
    const int AB = (N_NODES + 3) / 4;

    // layer 0: h = x
    lin_kernel<true><<<LB, 256, 0, stream>>>(x, Wlin, blin, Wc, bc, bufMsg, bufH);
    agg_kernel<<<AB, 256, 0, stream>>>(bufMsg, offsets, srcSorted, t, Wproj, bproj, bufH);
    // layer 1: h = bufH (combine written in place)
    lin_kernel<true><<<LB, 256, 0, stream>>>(bufH, Wlin + 4096, blin + 64, Wc + 4096,
                                             bc + 64, bufMsg, bufH);
    agg_kernel<<<AB, 256, 0, stream>>>(bufMsg, offsets, srcSorted, t + 64, Wproj + 5,
                                       bproj + 1, bufH);
    // global conv message
    lin_kernel<false><<<LB, 256, 0, stream>>>(bufH, gWlin, gblin, nullptr, nullptr,
                                              bufMsg, nullptr);
    gagg_kernel<<<G_GRAPHS, 256, 0, stream>>>(bufMsg, gstart, gt, gWproj, gbproj, emb);
    out_kernel<<<(G_GRAPHS * OUTD + 255) / 256, 256, 0, stream>>>(emb, Wout, bout, out);
}

// Round 5
// 639.147 us; speedup vs baseline: 2.2343x; 1.1958x over previous
//
#include <hip/hip_runtime.h>
#include <hip/hip_bf16.h>

#define N_NODES 100000
#define E_EDGES 1600000
#define FDIM 64
#define G_GRAPHS 128
#define OUTD 32
#define CAP 16        // edges cached in LDS per node (multiple of 8) -> 16KB/block
#define SCHUNK 2048   // scan: elements per block (256 threads x 8)
#define NCHUNK ((N_NODES + SCHUNK - 1) / SCHUNK)  // 49 (<= 64)

__device__ __forceinline__ float4 f4min(float4 a, float4 b) {
    return make_float4(fminf(a.x,b.x), fminf(a.y,b.y), fminf(a.z,b.z), fminf(a.w,b.w));
}
__device__ __forceinline__ float4 f4max(float4 a, float4 b) {
    return make_float4(fmaxf(a.x,b.x), fmaxf(a.y,b.y), fmaxf(a.z,b.z), fmaxf(a.w,b.w));
}
__device__ __forceinline__ float4 f4add(float4 a, float4 b) {
    return make_float4(a.x+b.x, a.y+b.y, a.z+b.z, a.w+b.w);
}

// ---------------- CSR build ----------------

__global__ __launch_bounds__(256) void hist_kernel(const int* __restrict__ dst,
                                                   int* __restrict__ deg) {
    int e = blockIdx.x * 256 + threadIdx.x;
    if (e < E_EDGES) atomicAdd(&deg[dst[e]], 1);
}

// scan phase A: per-block chunk sums
__global__ __launch_bounds__(256) void scanA_kernel(const int* __restrict__ deg,
                                                    int* __restrict__ blockSums) {
    const int tid = threadIdx.x;
    const int base = blockIdx.x * SCHUNK + tid * 8;
    int s = 0;
#pragma unroll
    for (int i = 0; i < 8; ++i) {
        int idx = base + i;
        if (idx < N_NODES) s += deg[idx];
    }
#pragma unroll
    for (int off = 32; off > 0; off >>= 1) s += __shfl_xor(s, off);
    __shared__ int ws[4];
    if ((tid & 63) == 0) ws[tid >> 6] = s;
    __syncthreads();
    if (tid == 0) blockSums[blockIdx.x] = ws[0] + ws[1] + ws[2] + ws[3];
}

// scan phase B: one wave scans the (<=64) block sums
__global__ __launch_bounds__(64) void scanB_kernel(const int* __restrict__ blockSums,
                                                   int* __restrict__ blockPrefix,
                                                   int* __restrict__ offsets) {
    int lane = threadIdx.x;
    int v = (lane < NCHUNK) ? blockSums[lane] : 0;
    int incl = v;
#pragma unroll
    for (int off = 1; off < 64; off <<= 1) {
        int o = __shfl_up(incl, off);
        if (lane >= off) incl += o;
    }
    if (lane < NCHUNK) blockPrefix[lane] = incl - v;
    if (lane == 63) offsets[N_NODES] = incl;  // total edge count
}

// scan phase C: per-thread 8-elem scan + wave scan + block prefix -> offsets & cursor
__global__ __launch_bounds__(256) void scanC_kernel(const int* __restrict__ deg,
                                                    const int* __restrict__ blockPrefix,
                                                    int* __restrict__ offsets,
                                                    int* __restrict__ cursor) {
    const int tid = threadIdx.x;
    const int lane = tid & 63, wv = tid >> 6;
    const int base = blockIdx.x * SCHUNK + tid * 8;
    int v[8];
    int s = 0;
#pragma unroll
    for (int i = 0; i < 8; ++i) {
        int idx = base + i;
        v[i] = (idx < N_NODES) ? deg[idx] : 0;
        s += v[i];
    }
    int incl = s;
#pragma unroll
    for (int off = 1; off < 64; off <<= 1) {
        int o = __shfl_up(incl, off);
        if (lane >= off) incl += o;
    }
    __shared__ int ws[4];
    if (lane == 63) ws[wv] = incl;
    __syncthreads();
    int wPre = 0;
    for (int w = 0; w < 4; ++w) wPre += (w < wv) ? ws[w] : 0;
    int run = blockPrefix[blockIdx.x] + wPre + (incl - s);
#pragma unroll
    for (int i = 0; i < 8; ++i) {
        int idx = base + i;
        if (idx < N_NODES) { offsets[idx] = run; cursor[idx] = run; }
        run += v[i];
    }
}

__global__ __launch_bounds__(256) void scatter_kernel(const int* __restrict__ src,
                                                      const int* __restrict__ dst,
                                                      int* __restrict__ cursor,
                                                      int* __restrict__ srcSorted) {
    int e = blockIdx.x * 256 + threadIdx.x;
    if (e < E_EDGES) {
        int pos = atomicAdd(&cursor[dst[e]], 1);
        srcSorted[pos] = src[e];
    }
}

// batch is sorted -> graph g starts where batch changes value. No atomics.
__global__ __launch_bounds__(256) void bound_kernel(const int* __restrict__ batch,
                                                    int* __restrict__ gstart) {
    int i = blockIdx.x * 256 + threadIdx.x;
    if (i >= N_NODES) return;
    if (i == 0) {
        gstart[batch[0]] = 0;
    } else {
        int b = batch[i], pb = batch[i - 1];
        if (b != pb) gstart[b] = i;
    }
}

// ---------------- dual linear: outM = in@Wm.T + bm ; outC = in@Wc.T + bc ----------------

template <bool DUAL>
__global__ __launch_bounds__(256) void lin_kernel(const float* __restrict__ in,
                                                  const float* __restrict__ Wm,
                                                  const float* __restrict__ bm,
                                                  const float* __restrict__ Wc,
                                                  const float* __restrict__ bc,
                                                  float* __restrict__ outM,
                                                  float* __restrict__ outC) {
    __shared__ __align__(16) float rows[4][64];
    const int tid = threadIdx.x;
    const int f = tid & 63, r = tid >> 6;
    float4 wm[16], wc[16];
    const float4* Wm4 = (const float4*)(Wm + f * 64);
#pragma unroll
    for (int i = 0; i < 16; ++i) wm[i] = Wm4[i];
    if (DUAL) {
        const float4* Wc4 = (const float4*)(Wc + f * 64);
#pragma unroll
        for (int i = 0; i < 16; ++i) wc[i] = Wc4[i];
    }
    const float bmv = bm[f];
    const float bcv = DUAL ? bc[f] : 0.f;
    const int base = blockIdx.x * 64;
    for (int c = 0; c < 64; c += 4) {
        int node = base + c + r;
        bool ok = node < N_NODES;
        if (ok) rows[r][f] = in[node * 64 + f];
        __syncthreads();
        if (ok) {
            float am = bmv, ac = bcv;
            const float4* rp = (const float4*)rows[r];
#pragma unroll
            for (int k = 0; k < 16; ++k) {
                float4 hv = rp[k];
                am = fmaf(hv.x, wm[k].x, am);
                am = fmaf(hv.y, wm[k].y, am);
                am = fmaf(hv.z, wm[k].z, am);
                am = fmaf(hv.w, wm[k].w, am);
                if (DUAL) {
                    ac = fmaf(hv.x, wc[k].x, ac);
                    ac = fmaf(hv.y, wc[k].y, ac);
                    ac = fmaf(hv.z, wc[k].z, ac);
                    ac = fmaf(hv.w, wc[k].w, ac);
                }
            }
            outM[node * 64 + f] = am;
            if (DUAL) outC[node * 64 + f] = ac;
        }
        __syncthreads();
    }
}

// ---------------- per-node adaptive-relu aggregation ----------------
// wave per node; lane = (edge group g = lane>>4, feature quad fq = lane&15).
// 8 edges x float4 in flight per iter; first CAP edges cached in LDS for pass 2.

__global__ __launch_bounds__(256) void agg_kernel(const float* __restrict__ msg,
                                                  const int* __restrict__ offsets,
                                                  const int* __restrict__ srcSorted,
                                                  const float* __restrict__ tptr,
                                                  const float* __restrict__ Wp,
                                                  const float* __restrict__ bp,
                                                  float* __restrict__ hbuf) {
    __shared__ float4 cache[4][CAP][16];  // 16 KB
    const int w = threadIdx.x >> 6;
    const int lane = threadIdx.x & 63;
    const int g = lane >> 4;
    const int fq = lane & 15;
    const int node = blockIdx.x * 4 + w;
    if (node >= N_NODES) return;
    const int start = offsets[node], end = offsets[node + 1];
    const float INF = __builtin_inff();
    float4 mn = make_float4(INF, INF, INF, INF);
    float4 mx = make_float4(-INF, -INF, -INF, -INF);
    float4 sm = make_float4(0.f, 0.f, 0.f, 0.f);
    for (int e = start; e < end; e += 8) {
        int i0 = e + g, i1 = e + 4 + g;
        bool ok0 = i0 < end, ok1 = i1 < end;
        int s0 = 0, s1 = 0;
        if (ok0) s0 = srcSorted[i0];
        if (ok1) s1 = srcSorted[i1];
        float4 v0, v1;
        if (ok0) v0 = *(const float4*)(msg + (size_t)s0 * 64 + 4 * fq);
        if (ok1) v1 = *(const float4*)(msg + (size_t)s1 * 64 + 4 * fq);
        if (ok0) {
            int slot = i0 - start;
            if (slot < CAP) cache[w][slot][fq] = v0;
            mn = f4min(mn, v0); mx = f4max(mx, v0); sm = f4add(sm, v0);
        }
        if (ok1) {
            int slot = i1 - start;
            if (slot < CAP) cache[w][slot][fq] = v1;
            mn = f4min(mn, v1); mx = f4max(mx, v1); sm = f4add(sm, v1);
        }
    }
#pragma unroll
    for (int off = 16; off <= 32; off <<= 1) {
        mn.x = fminf(mn.x, __shfl_xor(mn.x, off)); mn.y = fminf(mn.y, __shfl_xor(mn.y, off));
        mn.z = fminf(mn.z, __shfl_xor(mn.z, off)); mn.w = fminf(mn.w, __shfl_xor(mn.w, off));
        mx.x = fmaxf(mx.x, __shfl_xor(mx.x, off)); mx.y = fmaxf(mx.y, __shfl_xor(mx.y, off));
        mx.z = fmaxf(mx.z, __shfl_xor(mx.z, off)); mx.w = fmaxf(mx.w, __shfl_xor(mx.w, off));
        sm.x += __shfl_xor(sm.x, off); sm.y += __shfl_xor(sm.y, off);
        sm.z += __shfl_xor(sm.z, off); sm.w += __shfl_xor(sm.w, off);
    }
    float4 tv = *(const float4*)(tptr + 4 * fq);
    tv.x = fminf(fmaxf(tv.x, 0.f), 1.f); tv.y = fminf(fmaxf(tv.y, 0.f), 1.f);
    tv.z = fminf(fmaxf(tv.z, 0.f), 1.f); tv.w = fminf(fmaxf(tv.w, 0.f), 1.f);
    float4 bias;
    bias.x = tv.x * mx.x + (1.f - tv.x) * mn.x;
    bias.y = tv.y * mx.y + (1.f - tv.y) * mn.y;
    bias.z = tv.z * mx.z + (1.f - tv.z) * mn.z;
    bias.w = tv.w * mx.w + (1.f - tv.w) * mn.w;
    float4 rs = make_float4(0.f, 0.f, 0.f, 0.f);
    // pass 2a: cached slots (LDS, branch-free)
    const int cachedEnd = (end - start < CAP) ? end : (start + CAP);
    for (int e = start; e < cachedEnd; e += 4) {
        int idx = e + g;
        if (idx < cachedEnd) {
            float4 v = cache[w][idx - start][fq];
            rs.x += fmaxf(v.x - bias.x, 0.f); rs.y += fmaxf(v.y - bias.y, 0.f);
            rs.z += fmaxf(v.z - bias.z, 0.f); rs.w += fmaxf(v.w - bias.w, 0.f);
        }
    }
    // pass 2b: overflow slots (global re-gather)
    for (int e = start + CAP; e < end; e += 8) {
        int i0 = e + g, i1 = e + 4 + g;
        bool ok0 = i0 < end, ok1 = i1 < end;
        float4 v0, v1;
        if (ok0) v0 = *(const float4*)(msg + (size_t)srcSorted[i0] * 64 + 4 * fq);
        if (ok1) v1 = *(const float4*)(msg + (size_t)srcSorted[i1] * 64 + 4 * fq);
        if (ok0) {
            rs.x += fmaxf(v0.x - bias.x, 0.f); rs.y += fmaxf(v0.y - bias.y, 0.f);
            rs.z += fmaxf(v0.z - bias.z, 0.f); rs.w += fmaxf(v0.w - bias.w, 0.f);
        }
        if (ok1) {
            rs.x += fmaxf(v1.x - bias.x, 0.f); rs.y += fmaxf(v1.y - bias.y, 0.f);
            rs.z += fmaxf(v1.z - bias.z, 0.f); rs.w += fmaxf(v1.w - bias.w, 0.f);
        }
    }
#pragma unroll
    for (int off = 16; off <= 32; off <<= 1) {
        rs.x += __shfl_xor(rs.x, off); rs.y += __shfl_xor(rs.y, off);
        rs.z += __shfl_xor(rs.z, off); rs.w += __shfl_xor(rs.w, off);
    }
    if (g == 0) {
        float cnt = (float)(end - start);
        float w0 = Wp[0], w1 = Wp[1], w2 = Wp[2], w3 = Wp[3], w4 = Wp[4], b0 = bp[0];
        float4* hp = (float4*)(hbuf + (size_t)node * 64 + 4 * fq);
        float4 h = *hp;
        h.x += w0 * cnt + w1 * mn.x + w2 * mx.x + w3 * rs.x + w4 * sm.x + b0;
        h.y += w0 * cnt + w1 * mn.y + w2 * mx.y + w3 * rs.y + w4 * sm.y + b0;
        h.z += w0 * cnt + w1 * mn.z + w2 * mx.z + w3 * rs.z + w4 * sm.z + b0;
        h.w += w0 * cnt + w1 * mn.w + w2 * mx.w + w3 * rs.w + w4 * sm.w + b0;
        *hp = h;
    }
}

// ---------------- global pooling: block per graph ----------------

__global__ __launch_bounds__(256) void gagg_kernel(const float* __restrict__ msg,
                                                   const int* __restrict__ gstart,
                                                   const float* __restrict__ gt,
                                                   const float* __restrict__ gWp,
                                                   const float* __restrict__ gbp,
                                                   float* __restrict__ emb) {
    const int g = blockIdx.x;
    const int f = threadIdx.x & 63, r = threadIdx.x >> 6;
    const int start = gstart[g];
    const int end = (g == G_GRAPHS - 1) ? N_NODES : gstart[g + 1];
    float mn = __builtin_inff(), mx = -__builtin_inff(), sm = 0.f;
    for (int i = start + r; i < end; i += 4) {
        float v = msg[(size_t)i * 64 + f];
        mn = fminf(mn, v);
        mx = fmaxf(mx, v);
        sm += v;
    }
    __shared__ float smn[4][64], smx[4][64], ssm[4][64];
    smn[r][f] = mn; smx[r][f] = mx; ssm[r][f] = sm;
    __syncthreads();
    float Mn = fminf(fminf(smn[0][f], smn[1][f]), fminf(smn[2][f], smn[3][f]));
    float Mx = fmaxf(fmaxf(smx[0][f], smx[1][f]), fmaxf(smx[2][f], smx[3][f]));
    float Sm = ssm[0][f] + ssm[1][f] + ssm[2][f] + ssm[3][f];
    float tv = fminf(fmaxf(gt[f], 0.f), 1.f);
    float bias = tv * Mx + (1.f - tv) * Mn;
    float rs = 0.f;
    for (int i = start + r; i < end; i += 4) {
        float v = msg[(size_t)i * 64 + f];
        rs += fmaxf(v - bias, 0.f);
    }
    __syncthreads();
    smn[r][f] = rs;
    __syncthreads();
    if (r == 0) {
        float Rs = smn[0][f] + smn[1][f] + smn[2][f] + smn[3][f];
        float cnt = (float)(end - start);
        emb[g * 64 + f] = gWp[0] * cnt + gWp[1] * Mn + gWp[2] * Mx + gWp[3] * Rs +
                          gWp[4] * Sm + gbp[0];
    }
}

// ---------------- output GEMV ----------------

__global__ __launch_bounds__(256) void out_kernel(const float* __restrict__ emb,
                                                  const float* __restrict__ Wout,
                                                  const float* __restrict__ bout,
                                                  float* __restrict__ out) {
    int i = blockIdx.x * 256 + threadIdx.x;
    if (i >= G_GRAPHS * OUTD) return;
    int g = i >> 5, o = i & 31;
    float a = bout[o];
#pragma unroll
    for (int k = 0; k < 64; ++k) a = fmaf(emb[g * 64 + k], Wout[o * 64 + k], a);
    out[i] = a;
}

// ---------------- launch ----------------

extern "C" void kernel_launch(void* const* d_in, const int* in_sizes, int n_in,
                              void* d_out, int out_size, void* d_ws, size_t ws_size,
                              hipStream_t stream) {
    const float* x     = (const float*)d_in[0];
    const int*   ei    = (const int*)d_in[1];
    const int*   batch = (const int*)d_in[2];
    const float* Wlin  = (const float*)d_in[3];
    const float* blin  = (const float*)d_in[4];
    const float* t     = (const float*)d_in[5];
    const float* Wproj = (const float*)d_in[6];
    const float* bproj = (const float*)d_in[7];
    const float* Wc    = (const float*)d_in[8];
    const float* bc    = (const float*)d_in[9];
    const float* gWlin = (const float*)d_in[10];
    const float* gblin = (const float*)d_in[11];
    const float* gt    = (const float*)d_in[12];
    const float* gWproj= (const float*)d_in[13];
    const float* gbproj= (const float*)d_in[14];
    const float* Wout  = (const float*)d_in[15];
    const float* bout  = (const float*)d_in[16];
    float* out = (float*)d_out;

    const int* src = ei;
    const int* dst = ei + E_EDGES;

    // workspace layout
    char* p = (char*)d_ws;
    float* bufMsg = (float*)p; p += (size_t)N_NODES * FDIM * sizeof(float);
    float* bufH   = (float*)p; p += (size_t)N_NODES * FDIM * sizeof(float);
    float* emb    = (float*)p; p += (size_t)G_GRAPHS * FDIM * sizeof(float);
    int* deg      = (int*)p;   p += (size_t)N_NODES * sizeof(int);
    int* offsets  = (int*)p;   p += (size_t)(N_NODES + 1) * sizeof(int);
    int* cursor   = (int*)p;   p += (size_t)N_NODES * sizeof(int);
    int* gstart   = (int*)p;   p += (size_t)G_GRAPHS * sizeof(int);
    int* blockSums= (int*)p;   p += (size_t)NCHUNK * sizeof(int);
    int* blockPre = (int*)p;   p += (size_t)(NCHUNK + 1) * sizeof(int);
    int* srcSorted= (int*)p;   p += (size_t)E_EDGES * sizeof(int);

    hipMemsetAsync(deg, 0, N_NODES * sizeof(int), stream);

    const int EB = (E_EDGES + 255) / 256;
    const int NB = (N_NODES + 255) / 256;
    hist_kernel<<<EB, 256, 0, stream>>>(dst, deg);
    scanA_kernel<<<NCHUNK, 256, 0, stream>>>(deg, blockSums);
    scanB_kernel<<<1, 64, 0, stream>>>(blockSums, blockPre, offsets);
    scanC_kernel<<<NCHUNK, 256, 0, stream>>>(deg, blockPre, offsets, cursor);
    scatter_kernel<<<EB, 256, 0, stream>>>(src, dst, cursor, srcSorted);
    bound_kernel<<<NB, 256, 0, stream>>>(batch, gstart);

    const int LB = (N_NODES + 63) / 64;
    const int AB = (N_NODES + 3) / 4;

    // layer 0: h = x
    lin_kernel<true><<<LB, 256, 0, stream>>>(x, Wlin, blin, Wc, bc, bufMsg, bufH);
    agg_kernel<<<AB, 256, 0, stream>>>(bufMsg, offsets, srcSorted, t, Wproj, bproj, bufH);
    // layer 1: h = bufH (combine written in place)
    lin_kernel<true><<<LB, 256, 0, stream>>>(bufH, Wlin + 4096, blin + 64, Wc + 4096,
                                             bc + 64, bufMsg, bufH);
    agg_kernel<<<AB, 256, 0, stream>>>(bufMsg, offsets, srcSorted, t + 64, Wproj + 5,
                                       bproj + 1, bufH);
    // global conv message
    lin_kernel<false><<<LB, 256, 0, stream>>>(bufH, gWlin, gblin, nullptr, nullptr,
                                              bufMsg, nullptr);
    gagg_kernel<<<G_GRAPHS, 256, 0, stream>>>(bufMsg, gstart, gt, gWproj, gbproj, emb);
    out_kernel<<<(G_GRAPHS * OUTD + 255) / 256, 256, 0, stream>>>(emb, Wout, bout, out);
}

// Round 6
// 618.372 us; speedup vs baseline: 2.3093x; 1.0336x over previous
//
#include <hip/hip_runtime.h>
#include <hip/hip_bf16.h>

#define N_NODES 100000
#define E_EDGES 1600000
#define FDIM 64
#define G_GRAPHS 128
#define OUTD 32
#define CAP 16        // edges cached in LDS per node in agg (multiple of 8)
#define NPB 512       // nodes per bucket (power of 2)
#define NPB_SH 9
#define KBUK ((N_NODES + NPB - 1) / NPB)   // 196 (<= 256)
#define SEB 4096      // edges per block in bucket hist/scatter
#define SEBLK ((E_EDGES + SEB - 1) / SEB)  // 391

__device__ __forceinline__ float4 f4min(float4 a, float4 b) {
    return make_float4(fminf(a.x,b.x), fminf(a.y,b.y), fminf(a.z,b.z), fminf(a.w,b.w));
}
__device__ __forceinline__ float4 f4max(float4 a, float4 b) {
    return make_float4(fmaxf(a.x,b.x), fmaxf(a.y,b.y), fmaxf(a.z,b.z), fmaxf(a.w,b.w));
}
__device__ __forceinline__ float4 f4add(float4 a, float4 b) {
    return make_float4(a.x+b.x, a.y+b.y, a.z+b.z, a.w+b.w);
}

// ---------------- CSR build (bucketed) ----------------

// S1: bucket histogram. LDS hist per block, one padded global atomic per bucket.
__global__ __launch_bounds__(256) void bhist_kernel(const int* __restrict__ dst,
                                                    int* __restrict__ bucketCount) {
    __shared__ int h[KBUK];
    for (int i = threadIdx.x; i < KBUK; i += 256) h[i] = 0;
    __syncthreads();
    const int base = blockIdx.x * SEB;
#pragma unroll
    for (int i = 0; i < 16; ++i) {
        int e = base + i * 256 + threadIdx.x;
        if (e < E_EDGES) atomicAdd(&h[dst[e] >> NPB_SH], 1);
    }
    __syncthreads();
    for (int i = threadIdx.x; i < KBUK; i += 256)
        if (h[i]) atomicAdd(&bucketCount[i * 16], h[i]);  // line-padded
}

// S2: scan 196 bucket sums -> bucketStart, init bucketCursor; offsets[N]=E.
__global__ __launch_bounds__(256) void bscan_kernel(const int* __restrict__ bucketCount,
                                                    int* __restrict__ bucketStart,
                                                    int* __restrict__ bucketCursor,
                                                    int* __restrict__ offsets) {
    __shared__ int s[256];
    const int tid = threadIdx.x;
    int v = (tid < KBUK) ? bucketCount[tid * 16] : 0;
    s[tid] = v;
    __syncthreads();
    for (int off = 1; off < 256; off <<= 1) {
        int t = 0;
        if (tid >= off) t = s[tid - off];
        __syncthreads();
        if (tid >= off) s[tid] += t;
        __syncthreads();
    }
    int excl = s[tid] - v;
    if (tid < KBUK) { bucketStart[tid] = excl; bucketCursor[tid * 16] = excl; }
    if (tid == 0) { bucketStart[KBUK] = E_EDGES; offsets[N_NODES] = E_EDGES; }
}

// S3: coarse scatter into bucket regions. Block reserves per-bucket ranges with
// one global atomic each, then appends via LDS cursors. Packed (src<<9)|dstLow.
__global__ __launch_bounds__(256) void bscatter_kernel(const int* __restrict__ src,
                                                       const int* __restrict__ dst,
                                                       int* __restrict__ bucketCursor,
                                                       int* __restrict__ ebuf) {
    __shared__ int h[KBUK], resbase[KBUK], lcur[KBUK];
    for (int i = threadIdx.x; i < KBUK; i += 256) { h[i] = 0; lcur[i] = 0; }
    __syncthreads();
    const int base = blockIdx.x * SEB;
#pragma unroll
    for (int i = 0; i < 16; ++i) {
        int e = base + i * 256 + threadIdx.x;
        if (e < E_EDGES) atomicAdd(&h[dst[e] >> NPB_SH], 1);
    }
    __syncthreads();
    for (int i = threadIdx.x; i < KBUK; i += 256)
        resbase[i] = h[i] ? atomicAdd(&bucketCursor[i * 16], h[i]) : 0;
    __syncthreads();
#pragma unroll
    for (int i = 0; i < 16; ++i) {
        int e = base + i * 256 + threadIdx.x;
        if (e < E_EDGES) {
            int d = dst[e];
            int b = d >> NPB_SH;
            int pos = resbase[b] + atomicAdd(&lcur[b], 1);
            ebuf[pos] = (src[e] << NPB_SH) | (d & (NPB - 1));
        }
    }
}

// S4: per-bucket counting sort -> offsets[] + srcSorted[]. One block per bucket;
// output region owned by one block -> writes fully L2-absorbed.
__global__ __launch_bounds__(256) void bsort_kernel(const int* __restrict__ ebuf,
                                                    const int* __restrict__ bucketStart,
                                                    int* __restrict__ offsets,
                                                    int* __restrict__ srcSorted) {
    __shared__ int cnt[NPB];
    __shared__ int cur[NPB];
    __shared__ int wsum[4];
    const int b = blockIdx.x;
    const int tid = threadIdx.x;
    const int ebase = bucketStart[b], eend = bucketStart[b + 1];
    const int nbase = b * NPB;
    cnt[tid] = 0; cnt[tid + 256] = 0;
    __syncthreads();
    for (int e = ebase + tid; e < eend; e += 256)
        atomicAdd(&cnt[ebuf[e] & (NPB - 1)], 1);
    __syncthreads();
    int v0 = cnt[2 * tid], v1 = cnt[2 * tid + 1];
    int s = v0 + v1;
    const int lane = tid & 63, wv = tid >> 6;
    int incl = s;
#pragma unroll
    for (int off = 1; off < 64; off <<= 1) {
        int o = __shfl_up(incl, off);
        if (lane >= off) incl += o;
    }
    if (lane == 63) wsum[wv] = incl;
    __syncthreads();
    int wpre = 0;
#pragma unroll
    for (int w = 0; w < 4; ++w) wpre += (w < wv) ? wsum[w] : 0;
    int excl = wpre + incl - s;
    cur[2 * tid] = excl; cur[2 * tid + 1] = excl + v0;
    int n0 = nbase + 2 * tid;
    if (n0 < N_NODES) offsets[n0] = ebase + excl;
    if (n0 + 1 < N_NODES) offsets[n0 + 1] = ebase + excl + v0;
    __syncthreads();
    for (int e = ebase + tid; e < eend; e += 256) {
        int u = ebuf[e];
        int pos = ebase + atomicAdd(&cur[u & (NPB - 1)], 1);
        srcSorted[pos] = u >> NPB_SH;
    }
}

// batch is sorted -> graph g starts where batch changes value. No atomics.
__global__ __launch_bounds__(256) void bound_kernel(const int* __restrict__ batch,
                                                    int* __restrict__ gstart) {
    int i = blockIdx.x * 256 + threadIdx.x;
    if (i >= N_NODES) return;
    if (i == 0) {
        gstart[batch[0]] = 0;
    } else {
        int b = batch[i], pb = batch[i - 1];
        if (b != pb) gstart[b] = i;
    }
}

// ---------------- dual linear: outM = in@Wm.T + bm ; outC = in@Wc.T + bc ----------------
// W rows in registers; all 64 node rows staged once (single barrier), then
// barrier-free compute. In-place safe (reads only LDS after the barrier).

template <bool DUAL>
__global__ __launch_bounds__(256) void lin_kernel(const float* __restrict__ in,
                                                  const float* __restrict__ Wm,
                                                  const float* __restrict__ bm,
                                                  const float* __restrict__ Wc,
                                                  const float* __restrict__ bc,
                                                  float* __restrict__ outM,
                                                  float* __restrict__ outC) {
    __shared__ __align__(16) float rows[64][64];  // 16 KB
    const int tid = threadIdx.x;
    const int f = tid & 63, r = tid >> 6;
    float4 wm[16], wc[16];
    const float4* Wm4 = (const float4*)(Wm + f * 64);
#pragma unroll
    for (int i = 0; i < 16; ++i) wm[i] = Wm4[i];
    if (DUAL) {
        const float4* Wc4 = (const float4*)(Wc + f * 64);
#pragma unroll
        for (int i = 0; i < 16; ++i) wc[i] = Wc4[i];
    }
    const float bmv = bm[f];
    const float bcv = DUAL ? bc[f] : 0.f;
    const int base = blockIdx.x * 64;
#pragma unroll
    for (int i = 0; i < 4; ++i) {
        int j = tid + i * 256;  // float4 index within the 64x64 tile
        if (base + (j >> 4) < N_NODES)
            ((float4*)rows)[j] = ((const float4*)in)[(size_t)base * 16 + j];
    }
    __syncthreads();
    for (int c = r; c < 64; c += 4) {
        int node = base + c;
        if (node >= N_NODES) break;
        const float4* rp = (const float4*)rows[c];
        float am = bmv, ac = bcv;
#pragma unroll
        for (int k = 0; k < 16; ++k) {
            float4 hv = rp[k];
            am = fmaf(hv.x, wm[k].x, am); am = fmaf(hv.y, wm[k].y, am);
            am = fmaf(hv.z, wm[k].z, am); am = fmaf(hv.w, wm[k].w, am);
            if (DUAL) {
                ac = fmaf(hv.x, wc[k].x, ac); ac = fmaf(hv.y, wc[k].y, ac);
                ac = fmaf(hv.z, wc[k].z, ac); ac = fmaf(hv.w, wc[k].w, ac);
            }
        }
        outM[(size_t)node * 64 + f] = am;
        if (DUAL) outC[(size_t)node * 64 + f] = ac;
    }
}

// ---------------- per-node adaptive-relu aggregation ----------------
// wave per node; lane = (edge group g = lane>>4, feature quad fq = lane&15).
// 8 edges x float4 in flight per iter; first CAP edges cached in LDS for pass 2.

__global__ __launch_bounds__(256) void agg_kernel(const float* __restrict__ msg,
                                                  const int* __restrict__ offsets,
                                                  const int* __restrict__ srcSorted,
                                                  const float* __restrict__ tptr,
                                                  const float* __restrict__ Wp,
                                                  const float* __restrict__ bp,
                                                  float* __restrict__ hbuf) {
    __shared__ float4 cache[4][CAP][16];  // 16 KB
    const int w = threadIdx.x >> 6;
    const int lane = threadIdx.x & 63;
    const int g = lane >> 4;
    const int fq = lane & 15;
    const int node = blockIdx.x * 4 + w;
    if (node >= N_NODES) return;
    const int start = offsets[node], end = offsets[node + 1];
    const float INF = __builtin_inff();
    float4 mn = make_float4(INF, INF, INF, INF);
    float4 mx = make_float4(-INF, -INF, -INF, -INF);
    float4 sm = make_float4(0.f, 0.f, 0.f, 0.f);
    for (int e = start; e < end; e += 8) {
        int i0 = e + g, i1 = e + 4 + g;
        bool ok0 = i0 < end, ok1 = i1 < end;
        int s0 = 0, s1 = 0;
        if (ok0) s0 = srcSorted[i0];
        if (ok1) s1 = srcSorted[i1];
        float4 v0, v1;
        if (ok0) v0 = *(const float4*)(msg + (size_t)s0 * 64 + 4 * fq);
        if (ok1) v1 = *(const float4*)(msg + (size_t)s1 * 64 + 4 * fq);
        if (ok0) {
            int slot = i0 - start;
            if (slot < CAP) cache[w][slot][fq] = v0;
            mn = f4min(mn, v0); mx = f4max(mx, v0); sm = f4add(sm, v0);
        }
        if (ok1) {
            int slot = i1 - start;
            if (slot < CAP) cache[w][slot][fq] = v1;
            mn = f4min(mn, v1); mx = f4max(mx, v1); sm = f4add(sm, v1);
        }
    }
#pragma unroll
    for (int off = 16; off <= 32; off <<= 1) {
        mn.x = fminf(mn.x, __shfl_xor(mn.x, off)); mn.y = fminf(mn.y, __shfl_xor(mn.y, off));
        mn.z = fminf(mn.z, __shfl_xor(mn.z, off)); mn.w = fminf(mn.w, __shfl_xor(mn.w, off));
        mx.x = fmaxf(mx.x, __shfl_xor(mx.x, off)); mx.y = fmaxf(mx.y, __shfl_xor(mx.y, off));
        mx.z = fmaxf(mx.z, __shfl_xor(mx.z, off)); mx.w = fmaxf(mx.w, __shfl_xor(mx.w, off));
        sm.x += __shfl_xor(sm.x, off); sm.y += __shfl_xor(sm.y, off);
        sm.z += __shfl_xor(sm.z, off); sm.w += __shfl_xor(sm.w, off);
    }
    float4 tv = *(const float4*)(tptr + 4 * fq);
    tv.x = fminf(fmaxf(tv.x, 0.f), 1.f); tv.y = fminf(fmaxf(tv.y, 0.f), 1.f);
    tv.z = fminf(fmaxf(tv.z, 0.f), 1.f); tv.w = fminf(fmaxf(tv.w, 0.f), 1.f);
    float4 bias;
    bias.x = tv.x * mx.x + (1.f - tv.x) * mn.x;
    bias.y = tv.y * mx.y + (1.f - tv.y) * mn.y;
    bias.z = tv.z * mx.z + (1.f - tv.z) * mn.z;
    bias.w = tv.w * mx.w + (1.f - tv.w) * mn.w;
    float4 rs = make_float4(0.f, 0.f, 0.f, 0.f);
    const int cachedEnd = (end - start < CAP) ? end : (start + CAP);
    for (int e = start; e < cachedEnd; e += 4) {
        int idx = e + g;
        if (idx < cachedEnd) {
            float4 v = cache[w][idx - start][fq];
            rs.x += fmaxf(v.x - bias.x, 0.f); rs.y += fmaxf(v.y - bias.y, 0.f);
            rs.z += fmaxf(v.z - bias.z, 0.f); rs.w += fmaxf(v.w - bias.w, 0.f);
        }
    }
    for (int e = start + CAP; e < end; e += 8) {
        int i0 = e + g, i1 = e + 4 + g;
        bool ok0 = i0 < end, ok1 = i1 < end;
        float4 v0, v1;
        if (ok0) v0 = *(const float4*)(msg + (size_t)srcSorted[i0] * 64 + 4 * fq);
        if (ok1) v1 = *(const float4*)(msg + (size_t)srcSorted[i1] * 64 + 4 * fq);
        if (ok0) {
            rs.x += fmaxf(v0.x - bias.x, 0.f); rs.y += fmaxf(v0.y - bias.y, 0.f);
            rs.z += fmaxf(v0.z - bias.z, 0.f); rs.w += fmaxf(v0.w - bias.w, 0.f);
        }
        if (ok1) {
            rs.x += fmaxf(v1.x - bias.x, 0.f); rs.y += fmaxf(v1.y - bias.y, 0.f);
            rs.z += fmaxf(v1.z - bias.z, 0.f); rs.w += fmaxf(v1.w - bias.w, 0.f);
        }
    }
#pragma unroll
    for (int off = 16; off <= 32; off <<= 1) {
        rs.x += __shfl_xor(rs.x, off); rs.y += __shfl_xor(rs.y, off);
        rs.z += __shfl_xor(rs.z, off); rs.w += __shfl_xor(rs.w, off);
    }
    if (g == 0) {
        float cnt = (float)(end - start);
        float w0 = Wp[0], w1 = Wp[1], w2 = Wp[2], w3 = Wp[3], w4 = Wp[4], b0 = bp[0];
        float4* hp = (float4*)(hbuf + (size_t)node * 64 + 4 * fq);
        float4 h = *hp;
        h.x += w0 * cnt + w1 * mn.x + w2 * mx.x + w3 * rs.x + w4 * sm.x + b0;
        h.y += w0 * cnt + w1 * mn.y + w2 * mx.y + w3 * rs.y + w4 * sm.y + b0;
        h.z += w0 * cnt + w1 * mn.z + w2 * mx.z + w3 * rs.z + w4 * sm.z + b0;
        h.w += w0 * cnt + w1 * mn.w + w2 * mx.w + w3 * rs.w + w4 * sm.w + b0;
        *hp = h;
    }
}

// ---------------- global pooling: block per graph ----------------

__global__ __launch_bounds__(256) void gagg_kernel(const float* __restrict__ msg,
                                                   const int* __restrict__ gstart,
                                                   const float* __restrict__ gt,
                                                   const float* __restrict__ gWp,
                                                   const float* __restrict__ gbp,
                                                   float* __restrict__ emb) {
    const int g = blockIdx.x;
    const int f = threadIdx.x & 63, r = threadIdx.x >> 6;
    const int start = gstart[g];
    const int end = (g == G_GRAPHS - 1) ? N_NODES : gstart[g + 1];
    float mn = __builtin_inff(), mx = -__builtin_inff(), sm = 0.f;
    for (int i = start + r; i < end; i += 4) {
        float v = msg[(size_t)i * 64 + f];
        mn = fminf(mn, v);
        mx = fmaxf(mx, v);
        sm += v;
    }
    __shared__ float smn[4][64], smx[4][64], ssm[4][64];
    smn[r][f] = mn; smx[r][f] = mx; ssm[r][f] = sm;
    __syncthreads();
    float Mn = fminf(fminf(smn[0][f], smn[1][f]), fminf(smn[2][f], smn[3][f]));
    float Mx = fmaxf(fmaxf(smx[0][f], smx[1][f]), fmaxf(smx[2][f], smx[3][f]));
    float Sm = ssm[0][f] + ssm[1][f] + ssm[2][f] + ssm[3][f];
    float tv = fminf(fmaxf(gt[f], 0.f), 1.f);
    float bias = tv * Mx + (1.f - tv) * Mn;
    float rs = 0.f;
    for (int i = start + r; i < end; i += 4) {
        float v = msg[(size_t)i * 64 + f];
        rs += fmaxf(v - bias, 0.f);
    }
    __syncthreads();
    smn[r][f] = rs;
    __syncthreads();
    if (r == 0) {
        float Rs = smn[0][f] + smn[1][f] + smn[2][f] + smn[3][f];
        float cnt = (float)(end - start);
        emb[g * 64 + f] = gWp[0] * cnt + gWp[1] * Mn + gWp[2] * Mx + gWp[3] * Rs +
                          gWp[4] * Sm + gbp[0];
    }
}

// ---------------- output GEMV ----------------

__global__ __launch_bounds__(256) void out_kernel(const float* __restrict__ emb,
                                                  const float* __restrict__ Wout,
                                                  const float* __restrict__ bout,
                                                  float* __restrict__ out) {
    int i = blockIdx.x * 256 + threadIdx.x;
    if (i >= G_GRAPHS * OUTD) return;
    int g = i >> 5, o = i & 31;
    float a = bout[o];
#pragma unroll
    for (int k = 0; k < 64; ++k) a = fmaf(emb[g * 64 + k], Wout[o * 64 + k], a);
    out[i] = a;
}

// ---------------- launch ----------------

extern "C" void kernel_launch(void* const* d_in, const int* in_sizes, int n_in,
                              void* d_out, int out_size, void* d_ws, size_t ws_size,
                              hipStream_t stream) {
    const float* x     = (const float*)d_in[0];
    const int*   ei    = (const int*)d_in[1];
    const int*   batch = (const int*)d_in[2];
    const float* Wlin  = (const float*)d_in[3];
    const float* blin  = (const float*)d_in[4];
    const float* t     = (const float*)d_in[5];
    const float* Wproj = (const float*)d_in[6];
    const float* bproj = (const float*)d_in[7];
    const float* Wc    = (const float*)d_in[8];
    const float* bc    = (const float*)d_in[9];
    const float* gWlin = (const float*)d_in[10];
    const float* gblin = (const float*)d_in[11];
    const float* gt    = (const float*)d_in[12];
    const float* gWproj= (const float*)d_in[13];
    const float* gbproj= (const float*)d_in[14];
    const float* Wout  = (const float*)d_in[15];
    const float* bout  = (const float*)d_in[16];
    float* out = (float*)d_out;

    const int* src = ei;
    const int* dst = ei + E_EDGES;

    // workspace layout
    char* p = (char*)d_ws;
    float* bufMsg = (float*)p; p += (size_t)N_NODES * FDIM * sizeof(float);
    float* bufH   = (float*)p; p += (size_t)N_NODES * FDIM * sizeof(float);
    float* emb    = (float*)p; p += (size_t)G_GRAPHS * FDIM * sizeof(float);
    int* offsets  = (int*)p;   p += (size_t)(N_NODES + 1) * sizeof(int);
    int* gstart   = (int*)p;   p += (size_t)G_GRAPHS * sizeof(int);
    int* bucketCount  = (int*)p; p += (size_t)KBUK * 16 * sizeof(int);
    int* bucketStart  = (int*)p; p += (size_t)(KBUK + 1) * sizeof(int);
    int* bucketCursor = (int*)p; p += (size_t)KBUK * 16 * sizeof(int);
    int* srcSorted= (int*)p;   p += (size_t)E_EDGES * sizeof(int);
    int* ebuf = (int*)bufMsg;  // dead until lin layer 0 runs (after bsort)

    hipMemsetAsync(bucketCount, 0, (size_t)KBUK * 16 * sizeof(int), stream);

    const int NB = (N_NODES + 255) / 256;
    bhist_kernel<<<SEBLK, 256, 0, stream>>>(dst, bucketCount);
    bscan_kernel<<<1, 256, 0, stream>>>(bucketCount, bucketStart, bucketCursor, offsets);
    bscatter_kernel<<<SEBLK, 256, 0, stream>>>(src, dst, bucketCursor, ebuf);
    bsort_kernel<<<KBUK, 256, 0, stream>>>(ebuf, bucketStart, offsets, srcSorted);
    bound_kernel<<<NB, 256, 0, stream>>>(batch, gstart);

    const int LB = (N_NODES + 63) / 64;
    const int AB = (N_NODES + 3) / 4;

    // layer 0: h = x
    lin_kernel<true><<<LB, 256, 0, stream>>>(x, Wlin, blin, Wc, bc, bufMsg, bufH);
    agg_kernel<<<AB, 256, 0, stream>>>(bufMsg, offsets, srcSorted, t, Wproj, bproj, bufH);
    // layer 1: h = bufH (combine written in place)
    lin_kernel<true><<<LB, 256, 0, stream>>>(bufH, Wlin + 4096, blin + 64, Wc + 4096,
                                             bc + 64, bufMsg, bufH);
    agg_kernel<<<AB, 256, 0, stream>>>(bufMsg, offsets, srcSorted, t + 64, Wproj + 5,
                                       bproj + 1, bufH);
    // global conv message
    lin_kernel<false><<<LB, 256, 0, stream>>>(bufH, gWlin, gblin, nullptr, nullptr,
                                              bufMsg, nullptr);
    gagg_kernel<<<G_GRAPHS, 256, 0, stream>>>(bufMsg, gstart, gt, gWproj, gbproj, emb);
    out_kernel<<<(G_GRAPHS * OUTD + 255) / 256, 256, 0, stream>>>(emb, Wout, bout, out);
}

// Round 7
// 546.548 us; speedup vs baseline: 2.6128x; 1.1314x over previous
//
#include <hip/hip_runtime.h>
#include <hip/hip_bf16.h>

#define N_NODES 100000
#define E_EDGES 1600000
#define FDIM 64
#define G_GRAPHS 128
#define OUTD 32
#define CAP 16        // edges cached in LDS per node in agg (multiple of 8)
#define NPB 512       // nodes per bucket (power of 2)
#define NPB_SH 9
#define KBUK ((N_NODES + NPB - 1) / NPB)   // 196 (<= 256)
#define SEB 4096      // edges per block in bucket hist/scatter
#define SEBLK ((E_EDGES + SEB - 1) / SEB)  // 391

__device__ __forceinline__ float4 f4min(float4 a, float4 b) {
    return make_float4(fminf(a.x,b.x), fminf(a.y,b.y), fminf(a.z,b.z), fminf(a.w,b.w));
}
__device__ __forceinline__ float4 f4max(float4 a, float4 b) {
    return make_float4(fmaxf(a.x,b.x), fmaxf(a.y,b.y), fmaxf(a.z,b.z), fmaxf(a.w,b.w));
}
__device__ __forceinline__ float4 f4add(float4 a, float4 b) {
    return make_float4(a.x+b.x, a.y+b.y, a.z+b.z, a.w+b.w);
}

// ---------------- CSR build (bucketed) ----------------

// S1: bucket histogram. LDS hist per block, one padded global atomic per bucket.
__global__ __launch_bounds__(256) void bhist_kernel(const int* __restrict__ dst,
                                                    int* __restrict__ bucketCount) {
    __shared__ int h[KBUK];
    for (int i = threadIdx.x; i < KBUK; i += 256) h[i] = 0;
    __syncthreads();
    const int base = blockIdx.x * SEB;
#pragma unroll
    for (int i = 0; i < 16; ++i) {
        int e = base + i * 256 + threadIdx.x;
        if (e < E_EDGES) atomicAdd(&h[dst[e] >> NPB_SH], 1);
    }
    __syncthreads();
    for (int i = threadIdx.x; i < KBUK; i += 256)
        if (h[i]) atomicAdd(&bucketCount[i * 16], h[i]);  // line-padded
}

// S2: scan 196 bucket sums -> bucketStart, init bucketCursor; offsets[N]=E.
__global__ __launch_bounds__(256) void bscan_kernel(const int* __restrict__ bucketCount,
                                                    int* __restrict__ bucketStart,
                                                    int* __restrict__ bucketCursor,
                                                    int* __restrict__ offsets) {
    __shared__ int s[256];
    const int tid = threadIdx.x;
    int v = (tid < KBUK) ? bucketCount[tid * 16] : 0;
    s[tid] = v;
    __syncthreads();
    for (int off = 1; off < 256; off <<= 1) {
        int t = 0;
        if (tid >= off) t = s[tid - off];
        __syncthreads();
        if (tid >= off) s[tid] += t;
        __syncthreads();
    }
    int excl = s[tid] - v;
    if (tid < KBUK) { bucketStart[tid] = excl; bucketCursor[tid * 16] = excl; }
    if (tid == 0) { bucketStart[KBUK] = E_EDGES; offsets[N_NODES] = E_EDGES; }
}

// S3: coarse scatter into bucket regions. Block reserves per-bucket ranges with
// one global atomic each, then appends via LDS cursors. Packed (src<<9)|dstLow.
__global__ __launch_bounds__(256) void bscatter_kernel(const int* __restrict__ src,
                                                       const int* __restrict__ dst,
                                                       int* __restrict__ bucketCursor,
                                                       int* __restrict__ ebuf) {
    __shared__ int h[KBUK], resbase[KBUK], lcur[KBUK];
    for (int i = threadIdx.x; i < KBUK; i += 256) { h[i] = 0; lcur[i] = 0; }
    __syncthreads();
    const int base = blockIdx.x * SEB;
#pragma unroll
    for (int i = 0; i < 16; ++i) {
        int e = base + i * 256 + threadIdx.x;
        if (e < E_EDGES) atomicAdd(&h[dst[e] >> NPB_SH], 1);
    }
    __syncthreads();
    for (int i = threadIdx.x; i < KBUK; i += 256)
        resbase[i] = h[i] ? atomicAdd(&bucketCursor[i * 16], h[i]) : 0;
    __syncthreads();
#pragma unroll
    for (int i = 0; i < 16; ++i) {
        int e = base + i * 256 + threadIdx.x;
        if (e < E_EDGES) {
            int d = dst[e];
            int b = d >> NPB_SH;
            int pos = resbase[b] + atomicAdd(&lcur[b], 1);
            ebuf[pos] = (src[e] << NPB_SH) | (d & (NPB - 1));
        }
    }
}

// S4: per-bucket counting sort -> offsets[] + srcSorted[]. One block per bucket;
// output region owned by one block -> writes fully L2-absorbed.
__global__ __launch_bounds__(256) void bsort_kernel(const int* __restrict__ ebuf,
                                                    const int* __restrict__ bucketStart,
                                                    int* __restrict__ offsets,
                                                    int* __restrict__ srcSorted) {
    __shared__ int cnt[NPB];
    __shared__ int cur[NPB];
    __shared__ int wsum[4];
    const int b = blockIdx.x;
    const int tid = threadIdx.x;
    const int ebase = bucketStart[b], eend = bucketStart[b + 1];
    const int nbase = b * NPB;
    cnt[tid] = 0; cnt[tid + 256] = 0;
    __syncthreads();
    for (int e = ebase + tid; e < eend; e += 256)
        atomicAdd(&cnt[ebuf[e] & (NPB - 1)], 1);
    __syncthreads();
    int v0 = cnt[2 * tid], v1 = cnt[2 * tid + 1];
    int s = v0 + v1;
    const int lane = tid & 63, wv = tid >> 6;
    int incl = s;
#pragma unroll
    for (int off = 1; off < 64; off <<= 1) {
        int o = __shfl_up(incl, off);
        if (lane >= off) incl += o;
    }
    if (lane == 63) wsum[wv] = incl;
    __syncthreads();
    int wpre = 0;
#pragma unroll
    for (int w = 0; w < 4; ++w) wpre += (w < wv) ? wsum[w] : 0;
    int excl = wpre + incl - s;
    cur[2 * tid] = excl; cur[2 * tid + 1] = excl + v0;
    int n0 = nbase + 2 * tid;
    if (n0 < N_NODES) offsets[n0] = ebase + excl;
    if (n0 + 1 < N_NODES) offsets[n0 + 1] = ebase + excl + v0;
    __syncthreads();
    for (int e = ebase + tid; e < eend; e += 256) {
        int u = ebuf[e];
        int pos = ebase + atomicAdd(&cur[u & (NPB - 1)], 1);
        srcSorted[pos] = u >> NPB_SH;
    }
}

// batch is sorted -> graph g starts where batch changes value. No atomics.
__global__ __launch_bounds__(256) void bound_kernel(const int* __restrict__ batch,
                                                    int* __restrict__ gstart) {
    int i = blockIdx.x * 256 + threadIdx.x;
    if (i >= N_NODES) return;
    if (i == 0) {
        gstart[batch[0]] = 0;
    } else {
        int b = batch[i], pb = batch[i - 1];
        if (b != pb) gstart[b] = i;
    }
}

// ---------------- dual linear: outM = in@Wm.T + bm ; outC = in@Wc.T + bc ----------------
// Wave-split dual: waves 0-1 compute outM (W=Wm), waves 2-3 compute outC (W=Wc).
// Each thread holds ONE W row (64 VGPR), not two -> ~96 VGPR, 5 waves/SIMD.
// h tile staged once in LDS (single barrier); h-row reads are wave-broadcast.
// In-place safe (global reads complete before barrier; writes after).

template <bool DUAL>
__global__ __launch_bounds__(256) void lin_kernel(const float* __restrict__ in,
                                                  const float* __restrict__ Wm,
                                                  const float* __restrict__ bm,
                                                  const float* __restrict__ Wc,
                                                  const float* __restrict__ bc,
                                                  float* __restrict__ outM,
                                                  float* __restrict__ outC) {
    __shared__ __align__(16) float rows[64][64];  // 16 KB
    const int tid = threadIdx.x;
    const int f = tid & 63, r = tid >> 6;
    const bool doC = DUAL && (r >= 2);
    const float* W = doC ? Wc : Wm;
    float4 w[16];
    const float4* W4 = (const float4*)(W + f * 64);
#pragma unroll
    for (int i = 0; i < 16; ++i) w[i] = W4[i];
    const float bv = doC ? bc[f] : bm[f];
    float* outP = doC ? outC : outM;
    const int nodeOff = DUAL ? ((r & 1) * 32) : (r * 16);
    const int nodeCnt = DUAL ? 32 : 16;
    const int base = blockIdx.x * 64;
#pragma unroll
    for (int i = 0; i < 4; ++i) {
        int j = tid + i * 256;  // float4 index within the 64x64 tile
        if (base + (j >> 4) < N_NODES)
            ((float4*)rows)[j] = ((const float4*)in)[(size_t)base * 16 + j];
    }
    __syncthreads();
    for (int c = nodeOff; c < nodeOff + nodeCnt; ++c) {
        int node = base + c;
        if (node >= N_NODES) break;
        const float4* rp = (const float4*)rows[c];
        float a = bv;
#pragma unroll
        for (int k = 0; k < 16; ++k) {
            float4 hv = rp[k];
            a = fmaf(hv.x, w[k].x, a); a = fmaf(hv.y, w[k].y, a);
            a = fmaf(hv.z, w[k].z, a); a = fmaf(hv.w, w[k].w, a);
        }
        outP[(size_t)node * 64 + f] = a;
    }
}

// ---------------- per-node adaptive-relu aggregation ----------------
// wave per node; lane = (edge group g = lane>>4, feature quad fq = lane&15).
// 8 edges x float4 in flight per iter; first CAP edges cached in LDS for pass 2.

__global__ __launch_bounds__(256) void agg_kernel(const float* __restrict__ msg,
                                                  const int* __restrict__ offsets,
                                                  const int* __restrict__ srcSorted,
                                                  const float* __restrict__ tptr,
                                                  const float* __restrict__ Wp,
                                                  const float* __restrict__ bp,
                                                  float* __restrict__ hbuf) {
    __shared__ float4 cache[4][CAP][16];  // 16 KB
    const int w = threadIdx.x >> 6;
    const int lane = threadIdx.x & 63;
    const int g = lane >> 4;
    const int fq = lane & 15;
    const int node = blockIdx.x * 4 + w;
    if (node >= N_NODES) return;
    const int start = offsets[node], end = offsets[node + 1];
    const float INF = __builtin_inff();
    float4 mn = make_float4(INF, INF, INF, INF);
    float4 mx = make_float4(-INF, -INF, -INF, -INF);
    float4 sm = make_float4(0.f, 0.f, 0.f, 0.f);
    for (int e = start; e < end; e += 8) {
        int i0 = e + g, i1 = e + 4 + g;
        bool ok0 = i0 < end, ok1 = i1 < end;
        int s0 = 0, s1 = 0;
        if (ok0) s0 = srcSorted[i0];
        if (ok1) s1 = srcSorted[i1];
        float4 v0, v1;
        if (ok0) v0 = *(const float4*)(msg + (size_t)s0 * 64 + 4 * fq);
        if (ok1) v1 = *(const float4*)(msg + (size_t)s1 * 64 + 4 * fq);
        if (ok0) {
            int slot = i0 - start;
            if (slot < CAP) cache[w][slot][fq] = v0;
            mn = f4min(mn, v0); mx = f4max(mx, v0); sm = f4add(sm, v0);
        }
        if (ok1) {
            int slot = i1 - start;
            if (slot < CAP) cache[w][slot][fq] = v1;
            mn = f4min(mn, v1); mx = f4max(mx, v1); sm = f4add(sm, v1);
        }
    }
#pragma unroll
    for (int off = 16; off <= 32; off <<= 1) {
        mn.x = fminf(mn.x, __shfl_xor(mn.x, off)); mn.y = fminf(mn.y, __shfl_xor(mn.y, off));
        mn.z = fminf(mn.z, __shfl_xor(mn.z, off)); mn.w = fminf(mn.w, __shfl_xor(mn.w, off));
        mx.x = fmaxf(mx.x, __shfl_xor(mx.x, off)); mx.y = fmaxf(mx.y, __shfl_xor(mx.y, off));
        mx.z = fmaxf(mx.z, __shfl_xor(mx.z, off)); mx.w = fmaxf(mx.w, __shfl_xor(mx.w, off));
        sm.x += __shfl_xor(sm.x, off); sm.y += __shfl_xor(sm.y, off);
        sm.z += __shfl_xor(sm.z, off); sm.w += __shfl_xor(sm.w, off);
    }
    float4 tv = *(const float4*)(tptr + 4 * fq);
    tv.x = fminf(fmaxf(tv.x, 0.f), 1.f); tv.y = fminf(fmaxf(tv.y, 0.f), 1.f);
    tv.z = fminf(fmaxf(tv.z, 0.f), 1.f); tv.w = fminf(fmaxf(tv.w, 0.f), 1.f);
    float4 bias;
    bias.x = tv.x * mx.x + (1.f - tv.x) * mn.x;
    bias.y = tv.y * mx.y + (1.f - tv.y) * mn.y;
    bias.z = tv.z * mx.z + (1.f - tv.z) * mn.z;
    bias.w = tv.w * mx.w + (1.f - tv.w) * mn.w;
    float4 rs = make_float4(0.f, 0.f, 0.f, 0.f);
    const int cachedEnd = (end - start < CAP) ? end : (start + CAP);
    for (int e = start; e < cachedEnd; e += 4) {
        int idx = e + g;
        if (idx < cachedEnd) {
            float4 v = cache[w][idx - start][fq];
            rs.x += fmaxf(v.x - bias.x, 0.f); rs.y += fmaxf(v.y - bias.y, 0.f);
            rs.z += fmaxf(v.z - bias.z, 0.f); rs.w += fmaxf(v.w - bias.w, 0.f);
        }
    }
    for (int e = start + CAP; e < end; e += 8) {
        int i0 = e + g, i1 = e + 4 + g;
        bool ok0 = i0 < end, ok1 = i1 < end;
        float4 v0, v1;
        if (ok0) v0 = *(const float4*)(msg + (size_t)srcSorted[i0] * 64 + 4 * fq);
        if (ok1) v1 = *(const float4*)(msg + (size_t)srcSorted[i1] * 64 + 4 * fq);
        if (ok0) {
            rs.x += fmaxf(v0.x - bias.x, 0.f); rs.y += fmaxf(v0.y - bias.y, 0.f);
            rs.z += fmaxf(v0.z - bias.z, 0.f); rs.w += fmaxf(v0.w - bias.w, 0.f);
        }
        if (ok1) {
            rs.x += fmaxf(v1.x - bias.x, 0.f); rs.y += fmaxf(v1.y - bias.y, 0.f);
            rs.z += fmaxf(v1.z - bias.z, 0.f); rs.w += fmaxf(v1.w - bias.w, 0.f);
        }
    }
#pragma unroll
    for (int off = 16; off <= 32; off <<= 1) {
        rs.x += __shfl_xor(rs.x, off); rs.y += __shfl_xor(rs.y, off);
        rs.z += __shfl_xor(rs.z, off); rs.w += __shfl_xor(rs.w, off);
    }
    if (g == 0) {
        float cnt = (float)(end - start);
        float w0 = Wp[0], w1 = Wp[1], w2 = Wp[2], w3 = Wp[3], w4 = Wp[4], b0 = bp[0];
        float4* hp = (float4*)(hbuf + (size_t)node * 64 + 4 * fq);
        float4 h = *hp;
        h.x += w0 * cnt + w1 * mn.x + w2 * mx.x + w3 * rs.x + w4 * sm.x + b0;
        h.y += w0 * cnt + w1 * mn.y + w2 * mx.y + w3 * rs.y + w4 * sm.y + b0;
        h.z += w0 * cnt + w1 * mn.z + w2 * mx.z + w3 * rs.z + w4 * sm.z + b0;
        h.w += w0 * cnt + w1 * mn.w + w2 * mx.w + w3 * rs.w + w4 * sm.w + b0;
        *hp = h;
    }
}

// ---------------- global pooling: block per graph ----------------

__global__ __launch_bounds__(256) void gagg_kernel(const float* __restrict__ msg,
                                                   const int* __restrict__ gstart,
                                                   const float* __restrict__ gt,
                                                   const float* __restrict__ gWp,
                                                   const float* __restrict__ gbp,
                                                   float* __restrict__ emb) {
    const int g = blockIdx.x;
    const int f = threadIdx.x & 63, r = threadIdx.x >> 6;
    const int start = gstart[g];
    const int end = (g == G_GRAPHS - 1) ? N_NODES : gstart[g + 1];
    float mn = __builtin_inff(), mx = -__builtin_inff(), sm = 0.f;
    for (int i = start + r; i < end; i += 4) {
        float v = msg[(size_t)i * 64 + f];
        mn = fminf(mn, v);
        mx = fmaxf(mx, v);
        sm += v;
    }
    __shared__ float smn[4][64], smx[4][64], ssm[4][64];
    smn[r][f] = mn; smx[r][f] = mx; ssm[r][f] = sm;
    __syncthreads();
    float Mn = fminf(fminf(smn[0][f], smn[1][f]), fminf(smn[2][f], smn[3][f]));
    float Mx = fmaxf(fmaxf(smx[0][f], smx[1][f]), fmaxf(smx[2][f], smx[3][f]));
    float Sm = ssm[0][f] + ssm[1][f] + ssm[2][f] + ssm[3][f];
    float tv = fminf(fmaxf(gt[f], 0.f), 1.f);
    float bias = tv * Mx + (1.f - tv) * Mn;
    float rs = 0.f;
    for (int i = start + r; i < end; i += 4) {
        float v = msg[(size_t)i * 64 + f];
        rs += fmaxf(v - bias, 0.f);
    }
    __syncthreads();
    smn[r][f] = rs;
    __syncthreads();
    if (r == 0) {
        float Rs = smn[0][f] + smn[1][f] + smn[2][f] + smn[3][f];
        float cnt = (float)(end - start);
        emb[g * 64 + f] = gWp[0] * cnt + gWp[1] * Mn + gWp[2] * Mx + gWp[3] * Rs +
                          gWp[4] * Sm + gbp[0];
    }
}

// ---------------- output GEMV ----------------

__global__ __launch_bounds__(256) void out_kernel(const float* __restrict__ emb,
                                                  const float* __restrict__ Wout,
                                                  const float* __restrict__ bout,
                                                  float* __restrict__ out) {
    int i = blockIdx.x * 256 + threadIdx.x;
    if (i >= G_GRAPHS * OUTD) return;
    int g = i >> 5, o = i & 31;
    float a = bout[o];
#pragma unroll
    for (int k = 0; k < 64; ++k) a = fmaf(emb[g * 64 + k], Wout[o * 64 + k], a);
    out[i] = a;
}

// ---------------- launch ----------------

extern "C" void kernel_launch(void* const* d_in, const int* in_sizes, int n_in,
                              void* d_out, int out_size, void* d_ws, size_t ws_size,
                              hipStream_t stream) {
    const float* x     = (const float*)d_in[0];
    const int*   ei    = (const int*)d_in[1];
    const int*   batch = (const int*)d_in[2];
    const float* Wlin  = (const float*)d_in[3];
    const float* blin  = (const float*)d_in[4];
    const float* t     = (const float*)d_in[5];
    const float* Wproj = (const float*)d_in[6];
    const float* bproj = (const float*)d_in[7];
    const float* Wc    = (const float*)d_in[8];
    const float* bc    = (const float*)d_in[9];
    const float* gWlin = (const float*)d_in[10];
    const float* gblin = (const float*)d_in[11];
    const float* gt    = (const float*)d_in[12];
    const float* gWproj= (const float*)d_in[13];
    const float* gbproj= (const float*)d_in[14];
    const float* Wout  = (const float*)d_in[15];
    const float* bout  = (const float*)d_in[16];
    float* out = (float*)d_out;

    const int* src = ei;
    const int* dst = ei + E_EDGES;

    // workspace layout
    char* p = (char*)d_ws;
    float* bufMsg = (float*)p; p += (size_t)N_NODES * FDIM * sizeof(float);
    float* bufH   = (float*)p; p += (size_t)N_NODES * FDIM * sizeof(float);
    float* emb    = (float*)p; p += (size_t)G_GRAPHS * FDIM * sizeof(float);
    int* offsets  = (int*)p;   p += (size_t)(N_NODES + 1) * sizeof(int);
    int* gstart   = (int*)p;   p += (size_t)G_GRAPHS * sizeof(int);
    int* bucketCount  = (int*)p; p += (size_t)KBUK * 16 * sizeof(int);
    int* bucketStart  = (int*)p; p += (size_t)(KBUK + 1) * sizeof(int);
    int* bucketCursor = (int*)p; p += (size_t)KBUK * 16 * sizeof(int);
    int* srcSorted= (int*)p;   p += (size_t)E_EDGES * sizeof(int);
    int* ebuf = (int*)bufMsg;  // dead until lin layer 0 runs (after bsort)

    hipMemsetAsync(bucketCount, 0, (size_t)KBUK * 16 * sizeof(int), stream);

    const int NB = (N_NODES + 255) / 256;
    bhist_kernel<<<SEBLK, 256, 0, stream>>>(dst, bucketCount);
    bscan_kernel<<<1, 256, 0, stream>>>(bucketCount, bucketStart, bucketCursor, offsets);
    bscatter_kernel<<<SEBLK, 256, 0, stream>>>(src, dst, bucketCursor, ebuf);
    bsort_kernel<<<KBUK, 256, 0, stream>>>(ebuf, bucketStart, offsets, srcSorted);
    bound_kernel<<<NB, 256, 0, stream>>>(batch, gstart);

    const int LB = (N_NODES + 63) / 64;
    const int AB = (N_NODES + 3) / 4;

    // layer 0: h = x
    lin_kernel<true><<<LB, 256, 0, stream>>>(x, Wlin, blin, Wc, bc, bufMsg, bufH);
    agg_kernel<<<AB, 256, 0, stream>>>(bufMsg, offsets, srcSorted, t, Wproj, bproj, bufH);
    // layer 1: h = bufH (combine written in place)
    lin_kernel<true><<<LB, 256, 0, stream>>>(bufH, Wlin + 4096, blin + 64, Wc + 4096,
                                             bc + 64, bufMsg, bufH);
    agg_kernel<<<AB, 256, 0, stream>>>(bufMsg, offsets, srcSorted, t + 64, Wproj + 5,
                                       bproj + 1, bufH);
    // global conv message
    lin_kernel<false><<<LB, 256, 0, stream>>>(bufH, gWlin, gblin, nullptr, nullptr,
                                              bufMsg, nullptr);
    gagg_kernel<<<G_GRAPHS, 256, 0, stream>>>(bufMsg, gstart, gt, gWproj, gbproj, emb);
    out_kernel<<<(G_GRAPHS * OUTD + 255) / 256, 256, 0, stream>>>(emb, Wout, bout, out);
}

// Round 8
// 454.719 us; speedup vs baseline: 3.1405x; 1.2019x over previous
//
#include <hip/hip_runtime.h>
#include <hip/hip_bf16.h>

#define N_NODES 100000
#define E_EDGES 1600000
#define FDIM 64
#define G_GRAPHS 128
#define OUTD 32
#define CAP 16        // edges cached in LDS per node in agg (multiple of 8)
#define NPB 512       // nodes per bucket (power of 2)
#define NPB_SH 9
#define KBUK ((N_NODES + NPB - 1) / NPB)   // 196 (<= 256)
#define SEB 4096      // edges per block in bucket hist/scatter
#define SEBLK ((E_EDGES + SEB - 1) / SEB)  // 391
#define GCH 16        // chunks per graph in global pooling

__device__ __forceinline__ float4 f4min(float4 a, float4 b) {
    return make_float4(fminf(a.x,b.x), fminf(a.y,b.y), fminf(a.z,b.z), fminf(a.w,b.w));
}
__device__ __forceinline__ float4 f4max(float4 a, float4 b) {
    return make_float4(fmaxf(a.x,b.x), fmaxf(a.y,b.y), fmaxf(a.z,b.z), fmaxf(a.w,b.w));
}
__device__ __forceinline__ float4 f4add(float4 a, float4 b) {
    return make_float4(a.x+b.x, a.y+b.y, a.z+b.z, a.w+b.w);
}

// ---------------- CSR build (bucketed) ----------------

__global__ __launch_bounds__(256) void bhist_kernel(const int* __restrict__ dst,
                                                    int* __restrict__ bucketCount) {
    __shared__ int h[KBUK];
    for (int i = threadIdx.x; i < KBUK; i += 256) h[i] = 0;
    __syncthreads();
    const int base = blockIdx.x * SEB;
#pragma unroll
    for (int i = 0; i < 16; ++i) {
        int e = base + i * 256 + threadIdx.x;
        if (e < E_EDGES) atomicAdd(&h[dst[e] >> NPB_SH], 1);
    }
    __syncthreads();
    for (int i = threadIdx.x; i < KBUK; i += 256)
        if (h[i]) atomicAdd(&bucketCount[i * 16], h[i]);  // line-padded
}

__global__ __launch_bounds__(256) void bscan_kernel(const int* __restrict__ bucketCount,
                                                    int* __restrict__ bucketStart,
                                                    int* __restrict__ bucketCursor,
                                                    int* __restrict__ offsets) {
    __shared__ int s[256];
    const int tid = threadIdx.x;
    int v = (tid < KBUK) ? bucketCount[tid * 16] : 0;
    s[tid] = v;
    __syncthreads();
    for (int off = 1; off < 256; off <<= 1) {
        int t = 0;
        if (tid >= off) t = s[tid - off];
        __syncthreads();
        if (tid >= off) s[tid] += t;
        __syncthreads();
    }
    int excl = s[tid] - v;
    if (tid < KBUK) { bucketStart[tid] = excl; bucketCursor[tid * 16] = excl; }
    if (tid == 0) { bucketStart[KBUK] = E_EDGES; offsets[N_NODES] = E_EDGES; }
}

__global__ __launch_bounds__(256) void bscatter_kernel(const int* __restrict__ src,
                                                       const int* __restrict__ dst,
                                                       int* __restrict__ bucketCursor,
                                                       int* __restrict__ ebuf) {
    __shared__ int h[KBUK], resbase[KBUK], lcur[KBUK];
    for (int i = threadIdx.x; i < KBUK; i += 256) { h[i] = 0; lcur[i] = 0; }
    __syncthreads();
    const int base = blockIdx.x * SEB;
#pragma unroll
    for (int i = 0; i < 16; ++i) {
        int e = base + i * 256 + threadIdx.x;
        if (e < E_EDGES) atomicAdd(&h[dst[e] >> NPB_SH], 1);
    }
    __syncthreads();
    for (int i = threadIdx.x; i < KBUK; i += 256)
        resbase[i] = h[i] ? atomicAdd(&bucketCursor[i * 16], h[i]) : 0;
    __syncthreads();
#pragma unroll
    for (int i = 0; i < 16; ++i) {
        int e = base + i * 256 + threadIdx.x;
        if (e < E_EDGES) {
            int d = dst[e];
            int b = d >> NPB_SH;
            int pos = resbase[b] + atomicAdd(&lcur[b], 1);
            ebuf[pos] = (src[e] << NPB_SH) | (d & (NPB - 1));
        }
    }
}

__global__ __launch_bounds__(256) void bsort_kernel(const int* __restrict__ ebuf,
                                                    const int* __restrict__ bucketStart,
                                                    int* __restrict__ offsets,
                                                    int* __restrict__ srcSorted) {
    __shared__ int cnt[NPB];
    __shared__ int cur[NPB];
    __shared__ int wsum[4];
    const int b = blockIdx.x;
    const int tid = threadIdx.x;
    const int ebase = bucketStart[b], eend = bucketStart[b + 1];
    const int nbase = b * NPB;
    cnt[tid] = 0; cnt[tid + 256] = 0;
    __syncthreads();
    for (int e = ebase + tid; e < eend; e += 256)
        atomicAdd(&cnt[ebuf[e] & (NPB - 1)], 1);
    __syncthreads();
    int v0 = cnt[2 * tid], v1 = cnt[2 * tid + 1];
    int s = v0 + v1;
    const int lane = tid & 63, wv = tid >> 6;
    int incl = s;
#pragma unroll
    for (int off = 1; off < 64; off <<= 1) {
        int o = __shfl_up(incl, off);
        if (lane >= off) incl += o;
    }
    if (lane == 63) wsum[wv] = incl;
    __syncthreads();
    int wpre = 0;
#pragma unroll
    for (int w = 0; w < 4; ++w) wpre += (w < wv) ? wsum[w] : 0;
    int excl = wpre + incl - s;
    cur[2 * tid] = excl; cur[2 * tid + 1] = excl + v0;
    int n0 = nbase + 2 * tid;
    if (n0 < N_NODES) offsets[n0] = ebase + excl;
    if (n0 + 1 < N_NODES) offsets[n0 + 1] = ebase + excl + v0;
    __syncthreads();
    for (int e = ebase + tid; e < eend; e += 256) {
        int u = ebuf[e];
        int pos = ebase + atomicAdd(&cur[u & (NPB - 1)], 1);
        srcSorted[pos] = u >> NPB_SH;
    }
}

// batch is sorted -> graph g starts where batch changes value. No atomics.
__global__ __launch_bounds__(256) void bound_kernel(const int* __restrict__ batch,
                                                    int* __restrict__ gstart) {
    int i = blockIdx.x * 256 + threadIdx.x;
    if (i >= N_NODES) return;
    if (i == 0) {
        gstart[batch[0]] = 0;
    } else {
        int b = batch[i], pb = batch[i - 1];
        if (b != pb) gstart[b] = i;
    }
}

// ---------------- dual linear (wave-split) ----------------

template <bool DUAL>
__global__ __launch_bounds__(256) void lin_kernel(const float* __restrict__ in,
                                                  const float* __restrict__ Wm,
                                                  const float* __restrict__ bm,
                                                  const float* __restrict__ Wc,
                                                  const float* __restrict__ bc,
                                                  float* __restrict__ outM,
                                                  float* __restrict__ outC) {
    __shared__ __align__(16) float rows[64][64];  // 16 KB
    const int tid = threadIdx.x;
    const int f = tid & 63, r = tid >> 6;
    const bool doC = DUAL && (r >= 2);
    const float* W = doC ? Wc : Wm;
    float4 w[16];
    const float4* W4 = (const float4*)(W + f * 64);
#pragma unroll
    for (int i = 0; i < 16; ++i) w[i] = W4[i];
    const float bv = doC ? bc[f] : bm[f];
    float* outP = doC ? outC : outM;
    const int nodeOff = DUAL ? ((r & 1) * 32) : (r * 16);
    const int nodeCnt = DUAL ? 32 : 16;
    const int base = blockIdx.x * 64;
#pragma unroll
    for (int i = 0; i < 4; ++i) {
        int j = tid + i * 256;
        if (base + (j >> 4) < N_NODES)
            ((float4*)rows)[j] = ((const float4*)in)[(size_t)base * 16 + j];
    }
    __syncthreads();
    for (int c = nodeOff; c < nodeOff + nodeCnt; ++c) {
        int node = base + c;
        if (node >= N_NODES) break;
        const float4* rp = (const float4*)rows[c];
        float a = bv;
#pragma unroll
        for (int k = 0; k < 16; ++k) {
            float4 hv = rp[k];
            a = fmaf(hv.x, w[k].x, a); a = fmaf(hv.y, w[k].y, a);
            a = fmaf(hv.z, w[k].z, a); a = fmaf(hv.w, w[k].w, a);
        }
        outP[(size_t)node * 64 + f] = a;
    }
}

// ---------------- per-node adaptive-relu aggregation ----------------

__global__ __launch_bounds__(256) void agg_kernel(const float* __restrict__ msg,
                                                  const int* __restrict__ offsets,
                                                  const int* __restrict__ srcSorted,
                                                  const float* __restrict__ tptr,
                                                  const float* __restrict__ Wp,
                                                  const float* __restrict__ bp,
                                                  float* __restrict__ hbuf) {
    __shared__ float4 cache[4][CAP][16];  // 16 KB
    const int w = threadIdx.x >> 6;
    const int lane = threadIdx.x & 63;
    const int g = lane >> 4;
    const int fq = lane & 15;
    const int node = blockIdx.x * 4 + w;
    if (node >= N_NODES) return;
    const int start = offsets[node], end = offsets[node + 1];
    const float INF = __builtin_inff();
    float4 mn = make_float4(INF, INF, INF, INF);
    float4 mx = make_float4(-INF, -INF, -INF, -INF);
    float4 sm = make_float4(0.f, 0.f, 0.f, 0.f);
    for (int e = start; e < end; e += 8) {
        int i0 = e + g, i1 = e + 4 + g;
        bool ok0 = i0 < end, ok1 = i1 < end;
        int s0 = 0, s1 = 0;
        if (ok0) s0 = srcSorted[i0];
        if (ok1) s1 = srcSorted[i1];
        float4 v0, v1;
        if (ok0) v0 = *(const float4*)(msg + (size_t)s0 * 64 + 4 * fq);
        if (ok1) v1 = *(const float4*)(msg + (size_t)s1 * 64 + 4 * fq);
        if (ok0) {
            int slot = i0 - start;
            if (slot < CAP) cache[w][slot][fq] = v0;
            mn = f4min(mn, v0); mx = f4max(mx, v0); sm = f4add(sm, v0);
        }
        if (ok1) {
            int slot = i1 - start;
            if (slot < CAP) cache[w][slot][fq] = v1;
            mn = f4min(mn, v1); mx = f4max(mx, v1); sm = f4add(sm, v1);
        }
    }
#pragma unroll
    for (int off = 16; off <= 32; off <<= 1) {
        mn.x = fminf(mn.x, __shfl_xor(mn.x, off)); mn.y = fminf(mn.y, __shfl_xor(mn.y, off));
        mn.z = fminf(mn.z, __shfl_xor(mn.z, off)); mn.w = fminf(mn.w, __shfl_xor(mn.w, off));
        mx.x = fmaxf(mx.x, __shfl_xor(mx.x, off)); mx.y = fmaxf(mx.y, __shfl_xor(mx.y, off));
        mx.z = fmaxf(mx.z, __shfl_xor(mx.z, off)); mx.w = fmaxf(mx.w, __shfl_xor(mx.w, off));
        sm.x += __shfl_xor(sm.x, off); sm.y += __shfl_xor(sm.y, off);
        sm.z += __shfl_xor(sm.z, off); sm.w += __shfl_xor(sm.w, off);
    }
    float4 tv = *(const float4*)(tptr + 4 * fq);
    tv.x = fminf(fmaxf(tv.x, 0.f), 1.f); tv.y = fminf(fmaxf(tv.y, 0.f), 1.f);
    tv.z = fminf(fmaxf(tv.z, 0.f), 1.f); tv.w = fminf(fmaxf(tv.w, 0.f), 1.f);
    float4 bias;
    bias.x = tv.x * mx.x + (1.f - tv.x) * mn.x;
    bias.y = tv.y * mx.y + (1.f - tv.y) * mn.y;
    bias.z = tv.z * mx.z + (1.f - tv.z) * mn.z;
    bias.w = tv.w * mx.w + (1.f - tv.w) * mn.w;
    float4 rs = make_float4(0.f, 0.f, 0.f, 0.f);
    const int cachedEnd = (end - start < CAP) ? end : (start + CAP);
    for (int e = start; e < cachedEnd; e += 4) {
        int idx = e + g;
        if (idx < cachedEnd) {
            float4 v = cache[w][idx - start][fq];
            rs.x += fmaxf(v.x - bias.x, 0.f); rs.y += fmaxf(v.y - bias.y, 0.f);
            rs.z += fmaxf(v.z - bias.z, 0.f); rs.w += fmaxf(v.w - bias.w, 0.f);
        }
    }
    for (int e = start + CAP; e < end; e += 8) {
        int i0 = e + g, i1 = e + 4 + g;
        bool ok0 = i0 < end, ok1 = i1 < end;
        float4 v0, v1;
        if (ok0) v0 = *(const float4*)(msg + (size_t)srcSorted[i0] * 64 + 4 * fq);
        if (ok1) v1 = *(const float4*)(msg + (size_t)srcSorted[i1] * 64 + 4 * fq);
        if (ok0) {
            rs.x += fmaxf(v0.x - bias.x, 0.f); rs.y += fmaxf(v0.y - bias.y, 0.f);
            rs.z += fmaxf(v0.z - bias.z, 0.f); rs.w += fmaxf(v0.w - bias.w, 0.f);
        }
        if (ok1) {
            rs.x += fmaxf(v1.x - bias.x, 0.f); rs.y += fmaxf(v1.y - bias.y, 0.f);
            rs.z += fmaxf(v1.z - bias.z, 0.f); rs.w += fmaxf(v1.w - bias.w, 0.f);
        }
    }
#pragma unroll
    for (int off = 16; off <= 32; off <<= 1) {
        rs.x += __shfl_xor(rs.x, off); rs.y += __shfl_xor(rs.y, off);
        rs.z += __shfl_xor(rs.z, off); rs.w += __shfl_xor(rs.w, off);
    }
    if (g == 0) {
        float cnt = (float)(end - start);
        float w0 = Wp[0], w1 = Wp[1], w2 = Wp[2], w3 = Wp[3], w4 = Wp[4], b0 = bp[0];
        float4* hp = (float4*)(hbuf + (size_t)node * 64 + 4 * fq);
        float4 h = *hp;
        h.x += w0 * cnt + w1 * mn.x + w2 * mx.x + w3 * rs.x + w4 * sm.x + b0;
        h.y += w0 * cnt + w1 * mn.y + w2 * mx.y + w3 * rs.y + w4 * sm.y + b0;
        h.z += w0 * cnt + w1 * mn.z + w2 * mx.z + w3 * rs.z + w4 * sm.z + b0;
        h.w += w0 * cnt + w1 * mn.w + w2 * mx.w + w3 * rs.w + w4 * sm.w + b0;
        *hp = h;
    }
}

// ---------------- global pooling (4-phase, parallel) ----------------

// A: partial min/max/sum per (graph, chunk)
__global__ __launch_bounds__(256) void gaggA_kernel(const float* __restrict__ msg,
                                                    const int* __restrict__ gstart,
                                                    float* __restrict__ pmn,
                                                    float* __restrict__ pmx,
                                                    float* __restrict__ psm) {
    const int bid = blockIdx.x;
    const int g = bid >> 4, c = bid & (GCH - 1);
    const int s = gstart[g];
    const int e = (g == G_GRAPHS - 1) ? N_NODES : gstart[g + 1];
    const int clen = (e - s + GCH - 1) / GCH;
    const int cs = s + c * clen;
    const int ce = (cs + clen < e) ? (cs + clen) : e;
    const int f = threadIdx.x & 63, r = threadIdx.x >> 6;
    float mn = __builtin_inff(), mx = -__builtin_inff(), sm = 0.f;
    for (int i = cs + r; i < ce; i += 4) {
        float v = msg[(size_t)i * 64 + f];
        mn = fminf(mn, v); mx = fmaxf(mx, v); sm += v;
    }
    __shared__ float smn[4][64], smx[4][64], ssm[4][64];
    smn[r][f] = mn; smx[r][f] = mx; ssm[r][f] = sm;
    __syncthreads();
    if (r == 0) {
        pmn[bid * 64 + f] = fminf(fminf(smn[0][f], smn[1][f]), fminf(smn[2][f], smn[3][f]));
        pmx[bid * 64 + f] = fmaxf(fmaxf(smx[0][f], smx[1][f]), fmaxf(smx[2][f], smx[3][f]));
        psm[bid * 64 + f] = ssm[0][f] + ssm[1][f] + ssm[2][f] + ssm[3][f];
    }
}

// B: fold partials -> per-graph Mn/Mx/Sm + bias
__global__ __launch_bounds__(64) void gaggB_kernel(const float* __restrict__ pmn,
                                                   const float* __restrict__ pmx,
                                                   const float* __restrict__ psm,
                                                   const float* __restrict__ gt,
                                                   float* __restrict__ gMn,
                                                   float* __restrict__ gMx,
                                                   float* __restrict__ gSm,
                                                   float* __restrict__ gBias) {
    const int g = blockIdx.x, f = threadIdx.x;
    float mn = __builtin_inff(), mx = -__builtin_inff(), sm = 0.f;
#pragma unroll
    for (int c = 0; c < GCH; ++c) {
        int i = (g * GCH + c) * 64 + f;
        mn = fminf(mn, pmn[i]); mx = fmaxf(mx, pmx[i]); sm += psm[i];
    }
    float tv = fminf(fmaxf(gt[f], 0.f), 1.f);
    gMn[g * 64 + f] = mn; gMx[g * 64 + f] = mx; gSm[g * 64 + f] = sm;
    gBias[g * 64 + f] = tv * mx + (1.f - tv) * mn;
}

// C: partial relu_sum per (graph, chunk)
__global__ __launch_bounds__(256) void gaggC_kernel(const float* __restrict__ msg,
                                                    const int* __restrict__ gstart,
                                                    const float* __restrict__ gBias,
                                                    float* __restrict__ prs) {
    const int bid = blockIdx.x;
    const int g = bid >> 4, c = bid & (GCH - 1);
    const int s = gstart[g];
    const int e = (g == G_GRAPHS - 1) ? N_NODES : gstart[g + 1];
    const int clen = (e - s + GCH - 1) / GCH;
    const int cs = s + c * clen;
    const int ce = (cs + clen < e) ? (cs + clen) : e;
    const int f = threadIdx.x & 63, r = threadIdx.x >> 6;
    const float bias = gBias[g * 64 + f];
    float rs = 0.f;
    for (int i = cs + r; i < ce; i += 4) {
        float v = msg[(size_t)i * 64 + f];
        rs += fmaxf(v - bias, 0.f);
    }
    __shared__ float srs[4][64];
    srs[r][f] = rs;
    __syncthreads();
    if (r == 0)
        prs[bid * 64 + f] = srs[0][f] + srs[1][f] + srs[2][f] + srs[3][f];
}

// D: fold relu partials, project -> emb (LDS), fused out-GEMV
__global__ __launch_bounds__(64) void gaggD_kernel(const float* __restrict__ prs,
                                                   const int* __restrict__ gstart,
                                                   const float* __restrict__ gMn,
                                                   const float* __restrict__ gMx,
                                                   const float* __restrict__ gSm,
                                                   const float* __restrict__ gWp,
                                                   const float* __restrict__ gbp,
                                                   const float* __restrict__ Wout,
                                                   const float* __restrict__ bout,
                                                   float* __restrict__ out) {
    const int g = blockIdx.x, f = threadIdx.x;
    float rs = 0.f;
#pragma unroll
    for (int c = 0; c < GCH; ++c) rs += prs[(g * GCH + c) * 64 + f];
    const int s = gstart[g];
    const int e = (g == G_GRAPHS - 1) ? N_NODES : gstart[g + 1];
    float cnt = (float)(e - s);
    __shared__ float emb[64];
    emb[f] = gWp[0] * cnt + gWp[1] * gMn[g * 64 + f] + gWp[2] * gMx[g * 64 + f] +
             gWp[3] * rs + gWp[4] * gSm[g * 64 + f] + gbp[0];
    __syncthreads();
    if (f < OUTD) {
        float a = bout[f];
        const float* wr = Wout + f * 64;
#pragma unroll
        for (int k = 0; k < 64; ++k) a = fmaf(emb[k], wr[k], a);
        out[g * OUTD + f] = a;
    }
}

// ---------------- launch ----------------

extern "C" void kernel_launch(void* const* d_in, const int* in_sizes, int n_in,
                              void* d_out, int out_size, void* d_ws, size_t ws_size,
                              hipStream_t stream) {
    const float* x     = (const float*)d_in[0];
    const int*   ei    = (const int*)d_in[1];
    const int*   batch = (const int*)d_in[2];
    const float* Wlin  = (const float*)d_in[3];
    const float* blin  = (const float*)d_in[4];
    const float* t     = (const float*)d_in[5];
    const float* Wproj = (const float*)d_in[6];
    const float* bproj = (const float*)d_in[7];
    const float* Wc    = (const float*)d_in[8];
    const float* bc    = (const float*)d_in[9];
    const float* gWlin = (const float*)d_in[10];
    const float* gblin = (const float*)d_in[11];
    const float* gt    = (const float*)d_in[12];
    const float* gWproj= (const float*)d_in[13];
    const float* gbproj= (const float*)d_in[14];
    const float* Wout  = (const float*)d_in[15];
    const float* bout  = (const float*)d_in[16];
    float* out = (float*)d_out;

    const int* src = ei;
    const int* dst = ei + E_EDGES;

    // workspace layout
    char* p = (char*)d_ws;
    float* bufMsg = (float*)p; p += (size_t)N_NODES * FDIM * sizeof(float);
    float* bufH   = (float*)p; p += (size_t)N_NODES * FDIM * sizeof(float);
    int* offsets  = (int*)p;   p += (size_t)(N_NODES + 1) * sizeof(int);
    int* gstart   = (int*)p;   p += (size_t)G_GRAPHS * sizeof(int);
    int* bucketCount  = (int*)p; p += (size_t)KBUK * 16 * sizeof(int);
    int* bucketStart  = (int*)p; p += (size_t)(KBUK + 1) * sizeof(int);
    int* bucketCursor = (int*)p; p += (size_t)KBUK * 16 * sizeof(int);
    int* srcSorted= (int*)p;   p += (size_t)E_EDGES * sizeof(int);
    float* pmn = (float*)p;    p += (size_t)G_GRAPHS * GCH * 64 * sizeof(float);
    float* pmx = (float*)p;    p += (size_t)G_GRAPHS * GCH * 64 * sizeof(float);
    float* psm = (float*)p;    p += (size_t)G_GRAPHS * GCH * 64 * sizeof(float);
    float* prs = (float*)p;    p += (size_t)G_GRAPHS * GCH * 64 * sizeof(float);
    float* gMn = (float*)p;    p += (size_t)G_GRAPHS * 64 * sizeof(float);
    float* gMx = (float*)p;    p += (size_t)G_GRAPHS * 64 * sizeof(float);
    float* gSm = (float*)p;    p += (size_t)G_GRAPHS * 64 * sizeof(float);
    float* gBias = (float*)p;  p += (size_t)G_GRAPHS * 64 * sizeof(float);
    int* ebuf = (int*)bufMsg;  // dead until lin layer 0 runs (after bsort)

    hipMemsetAsync(bucketCount, 0, (size_t)KBUK * 16 * sizeof(int), stream);

    const int NB = (N_NODES + 255) / 256;
    bhist_kernel<<<SEBLK, 256, 0, stream>>>(dst, bucketCount);
    bscan_kernel<<<1, 256, 0, stream>>>(bucketCount, bucketStart, bucketCursor, offsets);
    bscatter_kernel<<<SEBLK, 256, 0, stream>>>(src, dst, bucketCursor, ebuf);
    bsort_kernel<<<KBUK, 256, 0, stream>>>(ebuf, bucketStart, offsets, srcSorted);
    bound_kernel<<<NB, 256, 0, stream>>>(batch, gstart);

    const int LB = (N_NODES + 63) / 64;
    const int AB = (N_NODES + 3) / 4;

    // layer 0: h = x
    lin_kernel<true><<<LB, 256, 0, stream>>>(x, Wlin, blin, Wc, bc, bufMsg, bufH);
    agg_kernel<<<AB, 256, 0, stream>>>(bufMsg, offsets, srcSorted, t, Wproj, bproj, bufH);
    // layer 1: h = bufH (combine written in place)
    lin_kernel<true><<<LB, 256, 0, stream>>>(bufH, Wlin + 4096, blin + 64, Wc + 4096,
                                             bc + 64, bufMsg, bufH);
    agg_kernel<<<AB, 256, 0, stream>>>(bufMsg, offsets, srcSorted, t + 64, Wproj + 5,
                                       bproj + 1, bufH);
    // global conv message
    lin_kernel<false><<<LB, 256, 0, stream>>>(bufH, gWlin, gblin, nullptr, nullptr,
                                              bufMsg, nullptr);
    gaggA_kernel<<<G_GRAPHS * GCH, 256, 0, stream>>>(bufMsg, gstart, pmn, pmx, psm);
    gaggB_kernel<<<G_GRAPHS, 64, 0, stream>>>(pmn, pmx, psm, gt, gMn, gMx, gSm, gBias);
    gaggC_kernel<<<G_GRAPHS * GCH, 256, 0, stream>>>(bufMsg, gstart, gBias, prs);
    gaggD_kernel<<<G_GRAPHS, 64, 0, stream>>>(prs, gstart, gMn, gMx, gSm, gWproj,
                                              gbproj, Wout, bout, out);
}

// Round 9
// 449.837 us; speedup vs baseline: 3.1745x; 1.0109x over previous
//
#include <hip/hip_runtime.h>
#include <hip/hip_bf16.h>

#define N_NODES 100000
#define E_EDGES 1600000
#define FDIM 64
#define G_GRAPHS 128
#define OUTD 32
#define CAP 16        // edges cached in LDS per node in agg (multiple of 8)
#define NPB 512       // nodes per bucket (power of 2)
#define NPB_SH 9
#define KBUK ((N_NODES + NPB - 1) / NPB)   // 196 (<= 256)
#define SEB 4096      // edges per block in bucket hist/scatter
#define SEBLK ((E_EDGES + SEB - 1) / SEB)  // 391
#define GCH 16        // chunks per graph in global pooling

__device__ __forceinline__ float4 f4min(float4 a, float4 b) {
    return make_float4(fminf(a.x,b.x), fminf(a.y,b.y), fminf(a.z,b.z), fminf(a.w,b.w));
}
__device__ __forceinline__ float4 f4max(float4 a, float4 b) {
    return make_float4(fmaxf(a.x,b.x), fmaxf(a.y,b.y), fmaxf(a.z,b.z), fmaxf(a.w,b.w));
}
__device__ __forceinline__ float4 f4add(float4 a, float4 b) {
    return make_float4(a.x+b.x, a.y+b.y, a.z+b.z, a.w+b.w);
}

// ---------------- CSR build (bucketed) ----------------

__global__ __launch_bounds__(256) void bhist_kernel(const int* __restrict__ dst,
                                                    int* __restrict__ bucketCount) {
    __shared__ int h[KBUK];
    for (int i = threadIdx.x; i < KBUK; i += 256) h[i] = 0;
    __syncthreads();
    const int base = blockIdx.x * SEB;
#pragma unroll
    for (int i = 0; i < 16; ++i) {
        int e = base + i * 256 + threadIdx.x;
        if (e < E_EDGES) atomicAdd(&h[dst[e] >> NPB_SH], 1);
    }
    __syncthreads();
    for (int i = threadIdx.x; i < KBUK; i += 256)
        if (h[i]) atomicAdd(&bucketCount[i * 16], h[i]);  // line-padded
}

__global__ __launch_bounds__(256) void bscan_kernel(const int* __restrict__ bucketCount,
                                                    int* __restrict__ bucketStart,
                                                    int* __restrict__ bucketCursor,
                                                    int* __restrict__ offsets) {
    __shared__ int s[256];
    const int tid = threadIdx.x;
    int v = (tid < KBUK) ? bucketCount[tid * 16] : 0;
    s[tid] = v;
    __syncthreads();
    for (int off = 1; off < 256; off <<= 1) {
        int t = 0;
        if (tid >= off) t = s[tid - off];
        __syncthreads();
        if (tid >= off) s[tid] += t;
        __syncthreads();
    }
    int excl = s[tid] - v;
    if (tid < KBUK) { bucketStart[tid] = excl; bucketCursor[tid * 16] = excl; }
    if (tid == 0) { bucketStart[KBUK] = E_EDGES; offsets[N_NODES] = E_EDGES; }
}

__global__ __launch_bounds__(256) void bscatter_kernel(const int* __restrict__ src,
                                                       const int* __restrict__ dst,
                                                       int* __restrict__ bucketCursor,
                                                       int* __restrict__ ebuf) {
    __shared__ int h[KBUK], resbase[KBUK], lcur[KBUK];
    for (int i = threadIdx.x; i < KBUK; i += 256) { h[i] = 0; lcur[i] = 0; }
    __syncthreads();
    const int base = blockIdx.x * SEB;
#pragma unroll
    for (int i = 0; i < 16; ++i) {
        int e = base + i * 256 + threadIdx.x;
        if (e < E_EDGES) atomicAdd(&h[dst[e] >> NPB_SH], 1);
    }
    __syncthreads();
    for (int i = threadIdx.x; i < KBUK; i += 256)
        resbase[i] = h[i] ? atomicAdd(&bucketCursor[i * 16], h[i]) : 0;
    __syncthreads();
#pragma unroll
    for (int i = 0; i < 16; ++i) {
        int e = base + i * 256 + threadIdx.x;
        if (e < E_EDGES) {
            int d = dst[e];
            int b = d >> NPB_SH;
            int pos = resbase[b] + atomicAdd(&lcur[b], 1);
            ebuf[pos] = (src[e] << NPB_SH) | (d & (NPB - 1));
        }
    }
}

__global__ __launch_bounds__(256) void bsort_kernel(const int* __restrict__ ebuf,
                                                    const int* __restrict__ bucketStart,
                                                    int* __restrict__ offsets,
                                                    int* __restrict__ srcSorted) {
    __shared__ int cnt[NPB];
    __shared__ int cur[NPB];
    __shared__ int wsum[4];
    const int b = blockIdx.x;
    const int tid = threadIdx.x;
    const int ebase = bucketStart[b], eend = bucketStart[b + 1];
    const int nbase = b * NPB;
    cnt[tid] = 0; cnt[tid + 256] = 0;
    __syncthreads();
    for (int e = ebase + tid; e < eend; e += 256)
        atomicAdd(&cnt[ebuf[e] & (NPB - 1)], 1);
    __syncthreads();
    int v0 = cnt[2 * tid], v1 = cnt[2 * tid + 1];
    int s = v0 + v1;
    const int lane = tid & 63, wv = tid >> 6;
    int incl = s;
#pragma unroll
    for (int off = 1; off < 64; off <<= 1) {
        int o = __shfl_up(incl, off);
        if (lane >= off) incl += o;
    }
    if (lane == 63) wsum[wv] = incl;
    __syncthreads();
    int wpre = 0;
#pragma unroll
    for (int w = 0; w < 4; ++w) wpre += (w < wv) ? wsum[w] : 0;
    int excl = wpre + incl - s;
    cur[2 * tid] = excl; cur[2 * tid + 1] = excl + v0;
    int n0 = nbase + 2 * tid;
    if (n0 < N_NODES) offsets[n0] = ebase + excl;
    if (n0 + 1 < N_NODES) offsets[n0 + 1] = ebase + excl + v0;
    __syncthreads();
    for (int e = ebase + tid; e < eend; e += 256) {
        int u = ebuf[e];
        int pos = ebase + atomicAdd(&cur[u & (NPB - 1)], 1);
        srcSorted[pos] = u >> NPB_SH;
    }
}

// batch is sorted -> graph g starts where batch changes value. No atomics.
__global__ __launch_bounds__(256) void bound_kernel(const int* __restrict__ batch,
                                                    int* __restrict__ gstart) {
    int i = blockIdx.x * 256 + threadIdx.x;
    if (i >= N_NODES) return;
    if (i == 0) {
        gstart[batch[0]] = 0;
    } else {
        int b = batch[i], pb = batch[i - 1];
        if (b != pb) gstart[b] = i;
    }
}

// ---------------- dual linear (wave-split) ----------------

template <bool DUAL>
__global__ __launch_bounds__(256) void lin_kernel(const float* __restrict__ in,
                                                  const float* __restrict__ Wm,
                                                  const float* __restrict__ bm,
                                                  const float* __restrict__ Wc,
                                                  const float* __restrict__ bc,
                                                  float* __restrict__ outM,
                                                  float* __restrict__ outC) {
    __shared__ __align__(16) float rows[64][64];  // 16 KB
    const int tid = threadIdx.x;
    const int f = tid & 63, r = tid >> 6;
    const bool doC = DUAL && (r >= 2);
    const float* W = doC ? Wc : Wm;
    float4 w[16];
    const float4* W4 = (const float4*)(W + f * 64);
#pragma unroll
    for (int i = 0; i < 16; ++i) w[i] = W4[i];
    const float bv = doC ? bc[f] : bm[f];
    float* outP = doC ? outC : outM;
    const int nodeOff = DUAL ? ((r & 1) * 32) : (r * 16);
    const int nodeCnt = DUAL ? 32 : 16;
    const int base = blockIdx.x * 64;
#pragma unroll
    for (int i = 0; i < 4; ++i) {
        int j = tid + i * 256;
        if (base + (j >> 4) < N_NODES)
            ((float4*)rows)[j] = ((const float4*)in)[(size_t)base * 16 + j];
    }
    __syncthreads();
    for (int c = nodeOff; c < nodeOff + nodeCnt; ++c) {
        int node = base + c;
        if (node >= N_NODES) break;
        const float4* rp = (const float4*)rows[c];
        float a = bv;
#pragma unroll
        for (int k = 0; k < 16; ++k) {
            float4 hv = rp[k];
            a = fmaf(hv.x, w[k].x, a); a = fmaf(hv.y, w[k].y, a);
            a = fmaf(hv.z, w[k].z, a); a = fmaf(hv.w, w[k].w, a);
        }
        outP[(size_t)node * 64 + f] = a;
    }
}

// ---------------- per-node adaptive-relu aggregation ----------------
// wave per node; lane = (edge group g = lane>>4, feature quad fq = lane&15).
// 16 edges (4 float4 gathers/lane-group) in flight per iteration; first CAP
// edges cached in LDS for pass 2.

__global__ __launch_bounds__(256) void agg_kernel(const float* __restrict__ msg,
                                                  const int* __restrict__ offsets,
                                                  const int* __restrict__ srcSorted,
                                                  const float* __restrict__ tptr,
                                                  const float* __restrict__ Wp,
                                                  const float* __restrict__ bp,
                                                  float* __restrict__ hbuf) {
    __shared__ float4 cache[4][CAP][16];  // 16 KB
    const int w = threadIdx.x >> 6;
    const int lane = threadIdx.x & 63;
    const int g = lane >> 4;
    const int fq = lane & 15;
    const int node = blockIdx.x * 4 + w;
    if (node >= N_NODES) return;
    const int start = offsets[node], end = offsets[node + 1];
    const float INF = __builtin_inff();
    float4 mn = make_float4(INF, INF, INF, INF);
    float4 mx = make_float4(-INF, -INF, -INF, -INF);
    float4 sm = make_float4(0.f, 0.f, 0.f, 0.f);
    for (int e = start; e < end; e += 16) {
        int i0 = e + g, i1 = i0 + 4, i2 = i0 + 8, i3 = i0 + 12;
        bool ok0 = i0 < end, ok1 = i1 < end, ok2 = i2 < end, ok3 = i3 < end;
        int s0 = 0, s1 = 0, s2 = 0, s3 = 0;
        if (ok0) s0 = srcSorted[i0];
        if (ok1) s1 = srcSorted[i1];
        if (ok2) s2 = srcSorted[i2];
        if (ok3) s3 = srcSorted[i3];
        float4 v0, v1, v2, v3;
        if (ok0) v0 = *(const float4*)(msg + (size_t)s0 * 64 + 4 * fq);
        if (ok1) v1 = *(const float4*)(msg + (size_t)s1 * 64 + 4 * fq);
        if (ok2) v2 = *(const float4*)(msg + (size_t)s2 * 64 + 4 * fq);
        if (ok3) v3 = *(const float4*)(msg + (size_t)s3 * 64 + 4 * fq);
        if (ok0) {
            int slot = i0 - start;
            if (slot < CAP) cache[w][slot][fq] = v0;
            mn = f4min(mn, v0); mx = f4max(mx, v0); sm = f4add(sm, v0);
        }
        if (ok1) {
            int slot = i1 - start;
            if (slot < CAP) cache[w][slot][fq] = v1;
            mn = f4min(mn, v1); mx = f4max(mx, v1); sm = f4add(sm, v1);
        }
        if (ok2) {
            int slot = i2 - start;
            if (slot < CAP) cache[w][slot][fq] = v2;
            mn = f4min(mn, v2); mx = f4max(mx, v2); sm = f4add(sm, v2);
        }
        if (ok3) {
            int slot = i3 - start;
            if (slot < CAP) cache[w][slot][fq] = v3;
            mn = f4min(mn, v3); mx = f4max(mx, v3); sm = f4add(sm, v3);
        }
    }
#pragma unroll
    for (int off = 16; off <= 32; off <<= 1) {
        mn.x = fminf(mn.x, __shfl_xor(mn.x, off)); mn.y = fminf(mn.y, __shfl_xor(mn.y, off));
        mn.z = fminf(mn.z, __shfl_xor(mn.z, off)); mn.w = fminf(mn.w, __shfl_xor(mn.w, off));
        mx.x = fmaxf(mx.x, __shfl_xor(mx.x, off)); mx.y = fmaxf(mx.y, __shfl_xor(mx.y, off));
        mx.z = fmaxf(mx.z, __shfl_xor(mx.z, off)); mx.w = fmaxf(mx.w, __shfl_xor(mx.w, off));
        sm.x += __shfl_xor(sm.x, off); sm.y += __shfl_xor(sm.y, off);
        sm.z += __shfl_xor(sm.z, off); sm.w += __shfl_xor(sm.w, off);
    }
    float4 tv = *(const float4*)(tptr + 4 * fq);
    tv.x = fminf(fmaxf(tv.x, 0.f), 1.f); tv.y = fminf(fmaxf(tv.y, 0.f), 1.f);
    tv.z = fminf(fmaxf(tv.z, 0.f), 1.f); tv.w = fminf(fmaxf(tv.w, 0.f), 1.f);
    float4 bias;
    bias.x = tv.x * mx.x + (1.f - tv.x) * mn.x;
    bias.y = tv.y * mx.y + (1.f - tv.y) * mn.y;
    bias.z = tv.z * mx.z + (1.f - tv.z) * mn.z;
    bias.w = tv.w * mx.w + (1.f - tv.w) * mn.w;
    float4 rs = make_float4(0.f, 0.f, 0.f, 0.f);
    const int deg = end - start;
    if (deg >= CAP) {
        // all CAP slots valid: branch-free full unroll
#pragma unroll
        for (int i = 0; i < CAP / 4; ++i) {
            float4 v = cache[w][i * 4 + g][fq];
            rs.x += fmaxf(v.x - bias.x, 0.f); rs.y += fmaxf(v.y - bias.y, 0.f);
            rs.z += fmaxf(v.z - bias.z, 0.f); rs.w += fmaxf(v.w - bias.w, 0.f);
        }
    } else {
        for (int idx = start + g; idx < end; idx += 4) {
            float4 v = cache[w][idx - start][fq];
            rs.x += fmaxf(v.x - bias.x, 0.f); rs.y += fmaxf(v.y - bias.y, 0.f);
            rs.z += fmaxf(v.z - bias.z, 0.f); rs.w += fmaxf(v.w - bias.w, 0.f);
        }
    }
    // overflow slots (global re-gather), 16-edge unrolled
    for (int e = start + CAP; e < end; e += 16) {
        int i0 = e + g, i1 = i0 + 4, i2 = i0 + 8, i3 = i0 + 12;
        bool ok0 = i0 < end, ok1 = i1 < end, ok2 = i2 < end, ok3 = i3 < end;
        int s0 = 0, s1 = 0, s2 = 0, s3 = 0;
        if (ok0) s0 = srcSorted[i0];
        if (ok1) s1 = srcSorted[i1];
        if (ok2) s2 = srcSorted[i2];
        if (ok3) s3 = srcSorted[i3];
        float4 v0, v1, v2, v3;
        if (ok0) v0 = *(const float4*)(msg + (size_t)s0 * 64 + 4 * fq);
        if (ok1) v1 = *(const float4*)(msg + (size_t)s1 * 64 + 4 * fq);
        if (ok2) v2 = *(const float4*)(msg + (size_t)s2 * 64 + 4 * fq);
        if (ok3) v3 = *(const float4*)(msg + (size_t)s3 * 64 + 4 * fq);
        if (ok0) {
            rs.x += fmaxf(v0.x - bias.x, 0.f); rs.y += fmaxf(v0.y - bias.y, 0.f);
            rs.z += fmaxf(v0.z - bias.z, 0.f); rs.w += fmaxf(v0.w - bias.w, 0.f);
        }
        if (ok1) {
            rs.x += fmaxf(v1.x - bias.x, 0.f); rs.y += fmaxf(v1.y - bias.y, 0.f);
            rs.z += fmaxf(v1.z - bias.z, 0.f); rs.w += fmaxf(v1.w - bias.w, 0.f);
        }
        if (ok2) {
            rs.x += fmaxf(v2.x - bias.x, 0.f); rs.y += fmaxf(v2.y - bias.y, 0.f);
            rs.z += fmaxf(v2.z - bias.z, 0.f); rs.w += fmaxf(v2.w - bias.w, 0.f);
        }
        if (ok3) {
            rs.x += fmaxf(v3.x - bias.x, 0.f); rs.y += fmaxf(v3.y - bias.y, 0.f);
            rs.z += fmaxf(v3.z - bias.z, 0.f); rs.w += fmaxf(v3.w - bias.w, 0.f);
        }
    }
#pragma unroll
    for (int off = 16; off <= 32; off <<= 1) {
        rs.x += __shfl_xor(rs.x, off); rs.y += __shfl_xor(rs.y, off);
        rs.z += __shfl_xor(rs.z, off); rs.w += __shfl_xor(rs.w, off);
    }
    if (g == 0) {
        float cnt = (float)deg;
        float w0 = Wp[0], w1 = Wp[1], w2 = Wp[2], w3 = Wp[3], w4 = Wp[4], b0 = bp[0];
        float4* hp = (float4*)(hbuf + (size_t)node * 64 + 4 * fq);
        float4 h = *hp;
        h.x += w0 * cnt + w1 * mn.x + w2 * mx.x + w3 * rs.x + w4 * sm.x + b0;
        h.y += w0 * cnt + w1 * mn.y + w2 * mx.y + w3 * rs.y + w4 * sm.y + b0;
        h.z += w0 * cnt + w1 * mn.z + w2 * mx.z + w3 * rs.z + w4 * sm.z + b0;
        h.w += w0 * cnt + w1 * mn.w + w2 * mx.w + w3 * rs.w + w4 * sm.w + b0;
        *hp = h;
    }
}

// ---------------- global pooling (4-phase, parallel) ----------------

__global__ __launch_bounds__(256) void gaggA_kernel(const float* __restrict__ msg,
                                                    const int* __restrict__ gstart,
                                                    float* __restrict__ pmn,
                                                    float* __restrict__ pmx,
                                                    float* __restrict__ psm) {
    const int bid = blockIdx.x;
    const int g = bid >> 4, c = bid & (GCH - 1);
    const int s = gstart[g];
    const int e = (g == G_GRAPHS - 1) ? N_NODES : gstart[g + 1];
    const int clen = (e - s + GCH - 1) / GCH;
    const int cs = s + c * clen;
    const int ce = (cs + clen < e) ? (cs + clen) : e;
    const int f = threadIdx.x & 63, r = threadIdx.x >> 6;
    float mn = __builtin_inff(), mx = -__builtin_inff(), sm = 0.f;
    for (int i = cs + r; i < ce; i += 4) {
        float v = msg[(size_t)i * 64 + f];
        mn = fminf(mn, v); mx = fmaxf(mx, v); sm += v;
    }
    __shared__ float smn[4][64], smx[4][64], ssm[4][64];
    smn[r][f] = mn; smx[r][f] = mx; ssm[r][f] = sm;
    __syncthreads();
    if (r == 0) {
        pmn[bid * 64 + f] = fminf(fminf(smn[0][f], smn[1][f]), fminf(smn[2][f], smn[3][f]));
        pmx[bid * 64 + f] = fmaxf(fmaxf(smx[0][f], smx[1][f]), fmaxf(smx[2][f], smx[3][f]));
        psm[bid * 64 + f] = ssm[0][f] + ssm[1][f] + ssm[2][f] + ssm[3][f];
    }
}

__global__ __launch_bounds__(64) void gaggB_kernel(const float* __restrict__ pmn,
                                                   const float* __restrict__ pmx,
                                                   const float* __restrict__ psm,
                                                   const float* __restrict__ gt,
                                                   float* __restrict__ gMn,
                                                   float* __restrict__ gMx,
                                                   float* __restrict__ gSm,
                                                   float* __restrict__ gBias) {
    const int g = blockIdx.x, f = threadIdx.x;
    float mn = __builtin_inff(), mx = -__builtin_inff(), sm = 0.f;
#pragma unroll
    for (int c = 0; c < GCH; ++c) {
        int i = (g * GCH + c) * 64 + f;
        mn = fminf(mn, pmn[i]); mx = fmaxf(mx, pmx[i]); sm += psm[i];
    }
    float tv = fminf(fmaxf(gt[f], 0.f), 1.f);
    gMn[g * 64 + f] = mn; gMx[g * 64 + f] = mx; gSm[g * 64 + f] = sm;
    gBias[g * 64 + f] = tv * mx + (1.f - tv) * mn;
}

__global__ __launch_bounds__(256) void gaggC_kernel(const float* __restrict__ msg,
                                                    const int* __restrict__ gstart,
                                                    const float* __restrict__ gBias,
                                                    float* __restrict__ prs) {
    const int bid = blockIdx.x;
    const int g = bid >> 4, c = bid & (GCH - 1);
    const int s = gstart[g];
    const int e = (g == G_GRAPHS - 1) ? N_NODES : gstart[g + 1];
    const int clen = (e - s + GCH - 1) / GCH;
    const int cs = s + c * clen;
    const int ce = (cs + clen < e) ? (cs + clen) : e;
    const int f = threadIdx.x & 63, r = threadIdx.x >> 6;
    const float bias = gBias[g * 64 + f];
    float rs = 0.f;
    for (int i = cs + r; i < ce; i += 4) {
        float v = msg[(size_t)i * 64 + f];
        rs += fmaxf(v - bias, 0.f);
    }
    __shared__ float srs[4][64];
    srs[r][f] = rs;
    __syncthreads();
    if (r == 0)
        prs[bid * 64 + f] = srs[0][f] + srs[1][f] + srs[2][f] + srs[3][f];
}

__global__ __launch_bounds__(64) void gaggD_kernel(const float* __restrict__ prs,
                                                   const int* __restrict__ gstart,
                                                   const float* __restrict__ gMn,
                                                   const float* __restrict__ gMx,
                                                   const float* __restrict__ gSm,
                                                   const float* __restrict__ gWp,
                                                   const float* __restrict__ gbp,
                                                   const float* __restrict__ Wout,
                                                   const float* __restrict__ bout,
                                                   float* __restrict__ out) {
    const int g = blockIdx.x, f = threadIdx.x;
    float rs = 0.f;
#pragma unroll
    for (int c = 0; c < GCH; ++c) rs += prs[(g * GCH + c) * 64 + f];
    const int s = gstart[g];
    const int e = (g == G_GRAPHS - 1) ? N_NODES : gstart[g + 1];
    float cnt = (float)(e - s);
    __shared__ float emb[64];
    emb[f] = gWp[0] * cnt + gWp[1] * gMn[g * 64 + f] + gWp[2] * gMx[g * 64 + f] +
             gWp[3] * rs + gWp[4] * gSm[g * 64 + f] + gbp[0];
    __syncthreads();
    if (f < OUTD) {
        float a = bout[f];
        const float* wr = Wout + f * 64;
#pragma unroll
        for (int k = 0; k < 64; ++k) a = fmaf(emb[k], wr[k], a);
        out[g * OUTD + f] = a;
    }
}

// ---------------- launch ----------------

extern "C" void kernel_launch(void* const* d_in, const int* in_sizes, int n_in,
                              void* d_out, int out_size, void* d_ws, size_t ws_size,
                              hipStream_t stream) {
    const float* x     = (const float*)d_in[0];
    const int*   ei    = (const int*)d_in[1];
    const int*   batch = (const int*)d_in[2];
    const float* Wlin  = (const float*)d_in[3];
    const float* blin  = (const float*)d_in[4];
    const float* t     = (const float*)d_in[5];
    const float* Wproj = (const float*)d_in[6];
    const float* bproj = (const float*)d_in[7];
    const float* Wc    = (const float*)d_in[8];
    const float* bc    = (const float*)d_in[9];
    const float* gWlin = (const float*)d_in[10];
    const float* gblin = (const float*)d_in[11];
    const float* gt    = (const float*)d_in[12];
    const float* gWproj= (const float*)d_in[13];
    const float* gbproj= (const float*)d_in[14];
    const float* Wout  = (const float*)d_in[15];
    const float* bout  = (const float*)d_in[16];
    float* out = (float*)d_out;

    const int* src = ei;
    const int* dst = ei + E_EDGES;

    // workspace layout
    char* p = (char*)d_ws;
    float* bufMsg = (float*)p; p += (size_t)N_NODES * FDIM * sizeof(float);
    float* bufH   = (float*)p; p += (size_t)N_NODES * FDIM * sizeof(float);
    int* offsets  = (int*)p;   p += (size_t)(N_NODES + 1) * sizeof(int);
    int* gstart   = (int*)p;   p += (size_t)G_GRAPHS * sizeof(int);
    int* bucketCount  = (int*)p; p += (size_t)KBUK * 16 * sizeof(int);
    int* bucketStart  = (int*)p; p += (size_t)(KBUK + 1) * sizeof(int);
    int* bucketCursor = (int*)p; p += (size_t)KBUK * 16 * sizeof(int);
    int* srcSorted= (int*)p;   p += (size_t)E_EDGES * sizeof(int);
    float* pmn = (float*)p;    p += (size_t)G_GRAPHS * GCH * 64 * sizeof(float);
    float* pmx = (float*)p;    p += (size_t)G_GRAPHS * GCH * 64 * sizeof(float);
    float* psm = (float*)p;    p += (size_t)G_GRAPHS * GCH * 64 * sizeof(float);
    float* prs = (float*)p;    p += (size_t)G_GRAPHS * GCH * 64 * sizeof(float);
    float* gMn = (float*)p;    p += (size_t)G_GRAPHS * 64 * sizeof(float);
    float* gMx = (float*)p;    p += (size_t)G_GRAPHS * 64 * sizeof(float);
    float* gSm = (float*)p;    p += (size_t)G_GRAPHS * 64 * sizeof(float);
    float* gBias = (float*)p;  p += (size_t)G_GRAPHS * 64 * sizeof(float);
    int* ebuf = (int*)bufMsg;  // dead until lin layer 0 runs (after bsort)

    hipMemsetAsync(bucketCount, 0, (size_t)KBUK * 16 * sizeof(int), stream);

    const int NB = (N_NODES + 255) / 256;
    bhist_kernel<<<SEBLK, 256, 0, stream>>>(dst, bucketCount);
    bscan_kernel<<<1, 256, 0, stream>>>(bucketCount, bucketStart, bucketCursor, offsets);
    bscatter_kernel<<<SEBLK, 256, 0, stream>>>(src, dst, bucketCursor, ebuf);
    bsort_kernel<<<KBUK, 256, 0, stream>>>(ebuf, bucketStart, offsets, srcSorted);
    bound_kernel<<<NB, 256, 0, stream>>>(batch, gstart);

    const int LB = (N_NODES + 63) / 64;
    const int AB = (N_NODES + 3) / 4;

    // layer 0: h = x
    lin_kernel<true><<<LB, 256, 0, stream>>>(x, Wlin, blin, Wc, bc, bufMsg, bufH);
    agg_kernel<<<AB, 256, 0, stream>>>(bufMsg, offsets, srcSorted, t, Wproj, bproj, bufH);
    // layer 1: h = bufH (combine written in place)
    lin_kernel<true><<<LB, 256, 0, stream>>>(bufH, Wlin + 4096, blin + 64, Wc + 4096,
                                             bc + 64, bufMsg, bufH);
    agg_kernel<<<AB, 256, 0, stream>>>(bufMsg, offsets, srcSorted, t + 64, Wproj + 5,
                                       bproj + 1, bufH);
    // global conv message
    lin_kernel<false><<<LB, 256, 0, stream>>>(bufH, gWlin, gblin, nullptr, nullptr,
                                              bufMsg, nullptr);
    gaggA_kernel<<<G_GRAPHS * GCH, 256, 0, stream>>>(bufMsg, gstart, pmn, pmx, psm);
    gaggB_kernel<<<G_GRAPHS, 64, 0, stream>>>(pmn, pmx, psm, gt, gMn, gMx, gSm, gBias);
    gaggC_kernel<<<G_GRAPHS * GCH, 256, 0, stream>>>(bufMsg, gstart, gBias, prs);
    gaggD_kernel<<<G_GRAPHS, 64, 0, stream>>>(prs, gstart, gMn, gMx, gSm, gWproj,
                                              gbproj, Wout, bout, out);
}

// Round 10
// 405.985 us; speedup vs baseline: 3.5174x; 1.1080x over previous
//
#include <hip/hip_runtime.h>
#include <hip/hip_bf16.h>

#define N_NODES 100000
#define E_EDGES 1600000
#define FDIM 64
#define G_GRAPHS 128
#define OUTD 32
#define CAP 16        // edges cached in LDS per node in agg (== one full iteration)
#define NPB 512       // nodes per bucket (power of 2)
#define NPB_SH 9
#define KBUK ((N_NODES + NPB - 1) / NPB)   // 196 (<= 256)
#define SEB 4096      // edges per block in bucket hist/scatter
#define SEBLK ((E_EDGES + SEB - 1) / SEB)  // 391
#define GCH 16        // chunks per graph in global pooling

__device__ __forceinline__ float4 f4min(float4 a, float4 b) {
    return make_float4(fminf(a.x,b.x), fminf(a.y,b.y), fminf(a.z,b.z), fminf(a.w,b.w));
}
__device__ __forceinline__ float4 f4max(float4 a, float4 b) {
    return make_float4(fmaxf(a.x,b.x), fmaxf(a.y,b.y), fmaxf(a.z,b.z), fmaxf(a.w,b.w));
}
__device__ __forceinline__ float4 f4add(float4 a, float4 b) {
    return make_float4(a.x+b.x, a.y+b.y, a.z+b.z, a.w+b.w);
}

// ---------------- CSR build (bucketed) ----------------

__global__ __launch_bounds__(256) void bhist_kernel(const int* __restrict__ dst,
                                                    int* __restrict__ bucketCount) {
    __shared__ int h[KBUK];
    for (int i = threadIdx.x; i < KBUK; i += 256) h[i] = 0;
    __syncthreads();
    const int base = blockIdx.x * SEB;
#pragma unroll
    for (int i = 0; i < 16; ++i) {
        int e = base + i * 256 + threadIdx.x;
        if (e < E_EDGES) atomicAdd(&h[dst[e] >> NPB_SH], 1);
    }
    __syncthreads();
    for (int i = threadIdx.x; i < KBUK; i += 256)
        if (h[i]) atomicAdd(&bucketCount[i * 16], h[i]);  // line-padded
}

__global__ __launch_bounds__(256) void bscan_kernel(const int* __restrict__ bucketCount,
                                                    int* __restrict__ bucketStart,
                                                    int* __restrict__ bucketCursor,
                                                    int* __restrict__ offsets) {
    __shared__ int s[256];
    const int tid = threadIdx.x;
    int v = (tid < KBUK) ? bucketCount[tid * 16] : 0;
    s[tid] = v;
    __syncthreads();
    for (int off = 1; off < 256; off <<= 1) {
        int t = 0;
        if (tid >= off) t = s[tid - off];
        __syncthreads();
        if (tid >= off) s[tid] += t;
        __syncthreads();
    }
    int excl = s[tid] - v;
    if (tid < KBUK) { bucketStart[tid] = excl; bucketCursor[tid * 16] = excl; }
    if (tid == 0) { bucketStart[KBUK] = E_EDGES; offsets[N_NODES] = E_EDGES; }
}

__global__ __launch_bounds__(256) void bscatter_kernel(const int* __restrict__ src,
                                                       const int* __restrict__ dst,
                                                       int* __restrict__ bucketCursor,
                                                       int* __restrict__ ebuf) {
    __shared__ int h[KBUK], resbase[KBUK], lcur[KBUK];
    for (int i = threadIdx.x; i < KBUK; i += 256) { h[i] = 0; lcur[i] = 0; }
    __syncthreads();
    const int base = blockIdx.x * SEB;
#pragma unroll
    for (int i = 0; i < 16; ++i) {
        int e = base + i * 256 + threadIdx.x;
        if (e < E_EDGES) atomicAdd(&h[dst[e] >> NPB_SH], 1);
    }
    __syncthreads();
    for (int i = threadIdx.x; i < KBUK; i += 256)
        resbase[i] = h[i] ? atomicAdd(&bucketCursor[i * 16], h[i]) : 0;
    __syncthreads();
#pragma unroll
    for (int i = 0; i < 16; ++i) {
        int e = base + i * 256 + threadIdx.x;
        if (e < E_EDGES) {
            int d = dst[e];
            int b = d >> NPB_SH;
            int pos = resbase[b] + atomicAdd(&lcur[b], 1);
            ebuf[pos] = (src[e] << NPB_SH) | (d & (NPB - 1));
        }
    }
}

__global__ __launch_bounds__(256) void bsort_kernel(const int* __restrict__ ebuf,
                                                    const int* __restrict__ bucketStart,
                                                    int* __restrict__ offsets,
                                                    int* __restrict__ srcSorted) {
    __shared__ int cnt[NPB];
    __shared__ int cur[NPB];
    __shared__ int wsum[4];
    const int b = blockIdx.x;
    const int tid = threadIdx.x;
    const int ebase = bucketStart[b], eend = bucketStart[b + 1];
    const int nbase = b * NPB;
    cnt[tid] = 0; cnt[tid + 256] = 0;
    __syncthreads();
    for (int e = ebase + tid; e < eend; e += 256)
        atomicAdd(&cnt[ebuf[e] & (NPB - 1)], 1);
    __syncthreads();
    int v0 = cnt[2 * tid], v1 = cnt[2 * tid + 1];
    int s = v0 + v1;
    const int lane = tid & 63, wv = tid >> 6;
    int incl = s;
#pragma unroll
    for (int off = 1; off < 64; off <<= 1) {
        int o = __shfl_up(incl, off);
        if (lane >= off) incl += o;
    }
    if (lane == 63) wsum[wv] = incl;
    __syncthreads();
    int wpre = 0;
#pragma unroll
    for (int w = 0; w < 4; ++w) wpre += (w < wv) ? wsum[w] : 0;
    int excl = wpre + incl - s;
    cur[2 * tid] = excl; cur[2 * tid + 1] = excl + v0;
    int n0 = nbase + 2 * tid;
    if (n0 < N_NODES) offsets[n0] = ebase + excl;
    if (n0 + 1 < N_NODES) offsets[n0 + 1] = ebase + excl + v0;
    __syncthreads();
    for (int e = ebase + tid; e < eend; e += 256) {
        int u = ebuf[e];
        int pos = ebase + atomicAdd(&cur[u & (NPB - 1)], 1);
        srcSorted[pos] = u >> NPB_SH;
    }
}

// batch is sorted -> graph g starts where batch changes value. No atomics.
__global__ __launch_bounds__(256) void bound_kernel(const int* __restrict__ batch,
                                                    int* __restrict__ gstart) {
    int i = blockIdx.x * 256 + threadIdx.x;
    if (i >= N_NODES) return;
    if (i == 0) {
        gstart[batch[0]] = 0;
    } else {
        int b = batch[i], pb = batch[i - 1];
        if (b != pb) gstart[b] = i;
    }
}

// ---------------- dual linear (wave-split) ----------------

template <bool DUAL>
__global__ __launch_bounds__(256) void lin_kernel(const float* __restrict__ in,
                                                  const float* __restrict__ Wm,
                                                  const float* __restrict__ bm,
                                                  const float* __restrict__ Wc,
                                                  const float* __restrict__ bc,
                                                  float* __restrict__ outM,
                                                  float* __restrict__ outC) {
    __shared__ __align__(16) float rows[64][64];  // 16 KB
    const int tid = threadIdx.x;
    const int f = tid & 63, r = tid >> 6;
    const bool doC = DUAL && (r >= 2);
    const float* W = doC ? Wc : Wm;
    float4 w[16];
    const float4* W4 = (const float4*)(W + f * 64);
#pragma unroll
    for (int i = 0; i < 16; ++i) w[i] = W4[i];
    const float bv = doC ? bc[f] : bm[f];
    float* outP = doC ? outC : outM;
    const int nodeOff = DUAL ? ((r & 1) * 32) : (r * 16);
    const int nodeCnt = DUAL ? 32 : 16;
    const int base = blockIdx.x * 64;
#pragma unroll
    for (int i = 0; i < 4; ++i) {
        int j = tid + i * 256;
        if (base + (j >> 4) < N_NODES)
            ((float4*)rows)[j] = ((const float4*)in)[(size_t)base * 16 + j];
    }
    __syncthreads();
    for (int c = nodeOff; c < nodeOff + nodeCnt; ++c) {
        int node = base + c;
        if (node >= N_NODES) break;
        const float4* rp = (const float4*)rows[c];
        float a = bv;
#pragma unroll
        for (int k = 0; k < 16; ++k) {
            float4 hv = rp[k];
            a = fmaf(hv.x, w[k].x, a); a = fmaf(hv.y, w[k].y, a);
            a = fmaf(hv.z, w[k].z, a); a = fmaf(hv.w, w[k].w, a);
        }
        outP[(size_t)node * 64 + f] = a;
    }
}

// ---------------- per-node adaptive-relu aggregation ----------------
// wave per node; lane = (edge group g = lane>>4, feature quad fq = lane&15).
// deg>=16: iter0 branchless (all slots cached), then branchless full-16 iters
// (no cache logic: slots >= CAP never cached), then one masked tail.

__global__ __launch_bounds__(256) void agg_kernel(const float* __restrict__ msg,
                                                  const int* __restrict__ offsets,
                                                  const int* __restrict__ srcSorted,
                                                  const float* __restrict__ tptr,
                                                  const float* __restrict__ Wp,
                                                  const float* __restrict__ bp,
                                                  float* __restrict__ hbuf) {
    __shared__ float4 cache[4][CAP][16];  // 16 KB
    const int w = threadIdx.x >> 6;
    const int lane = threadIdx.x & 63;
    const int g = lane >> 4;
    const int fq = lane & 15;
    const int node = blockIdx.x * 4 + w;
    if (node >= N_NODES) return;
    const int start = offsets[node], end = offsets[node + 1];
    const int deg = end - start;
    const float4* mq = (const float4*)msg + fq;  // row stride = 16 float4
    const float INF = __builtin_inff();
    float4 mn = make_float4(INF, INF, INF, INF);
    float4 mx = make_float4(-INF, -INF, -INF, -INF);
    float4 sm = make_float4(0.f, 0.f, 0.f, 0.f);

#define ACC1(v) { mn = f4min(mn, v); mx = f4max(mx, v); sm = f4add(sm, v); }

    if (deg >= 16) {
        // iteration 0: branchless, cache all 16 slots
        {
            int i0 = start + g;
            int s0 = srcSorted[i0], s1 = srcSorted[i0 + 4];
            int s2 = srcSorted[i0 + 8], s3 = srcSorted[i0 + 12];
            float4 v0 = mq[(size_t)s0 * 16], v1 = mq[(size_t)s1 * 16];
            float4 v2 = mq[(size_t)s2 * 16], v3 = mq[(size_t)s3 * 16];
            cache[w][g][fq] = v0; cache[w][g + 4][fq] = v1;
            cache[w][g + 8][fq] = v2; cache[w][g + 12][fq] = v3;
            ACC1(v0) ACC1(v1) ACC1(v2) ACC1(v3)
        }
        int e = start + 16;
        for (; e + 16 <= end; e += 16) {  // branchless full iterations
            int i0 = e + g;
            int s0 = srcSorted[i0], s1 = srcSorted[i0 + 4];
            int s2 = srcSorted[i0 + 8], s3 = srcSorted[i0 + 12];
            float4 v0 = mq[(size_t)s0 * 16], v1 = mq[(size_t)s1 * 16];
            float4 v2 = mq[(size_t)s2 * 16], v3 = mq[(size_t)s3 * 16];
            ACC1(v0) ACC1(v1) ACC1(v2) ACC1(v3)
        }
        if (e < end) {  // masked tail, never cached
            int i0 = e + g, i1 = i0 + 4, i2 = i0 + 8, i3 = i0 + 12;
            bool ok0 = i0 < end, ok1 = i1 < end, ok2 = i2 < end, ok3 = i3 < end;
            int s0 = 0, s1 = 0, s2 = 0, s3 = 0;
            if (ok0) s0 = srcSorted[i0];
            if (ok1) s1 = srcSorted[i1];
            if (ok2) s2 = srcSorted[i2];
            if (ok3) s3 = srcSorted[i3];
            float4 v0, v1, v2, v3;
            if (ok0) v0 = mq[(size_t)s0 * 16];
            if (ok1) v1 = mq[(size_t)s1 * 16];
            if (ok2) v2 = mq[(size_t)s2 * 16];
            if (ok3) v3 = mq[(size_t)s3 * 16];
            if (ok0) ACC1(v0)
            if (ok1) ACC1(v1)
            if (ok2) ACC1(v2)
            if (ok3) ACC1(v3)
        }
    } else {
        // deg < 16: one masked iteration, cache valid slots
        int i0 = start + g, i1 = i0 + 4, i2 = i0 + 8, i3 = i0 + 12;
        bool ok0 = i0 < end, ok1 = i1 < end, ok2 = i2 < end, ok3 = i3 < end;
        int s0 = 0, s1 = 0, s2 = 0, s3 = 0;
        if (ok0) s0 = srcSorted[i0];
        if (ok1) s1 = srcSorted[i1];
        if (ok2) s2 = srcSorted[i2];
        if (ok3) s3 = srcSorted[i3];
        float4 v0, v1, v2, v3;
        if (ok0) v0 = mq[(size_t)s0 * 16];
        if (ok1) v1 = mq[(size_t)s1 * 16];
        if (ok2) v2 = mq[(size_t)s2 * 16];
        if (ok3) v3 = mq[(size_t)s3 * 16];
        if (ok0) { cache[w][g][fq] = v0;      ACC1(v0) }
        if (ok1) { cache[w][g + 4][fq] = v1;  ACC1(v1) }
        if (ok2) { cache[w][g + 8][fq] = v2;  ACC1(v2) }
        if (ok3) { cache[w][g + 12][fq] = v3; ACC1(v3) }
    }
#pragma unroll
    for (int off = 16; off <= 32; off <<= 1) {
        mn.x = fminf(mn.x, __shfl_xor(mn.x, off)); mn.y = fminf(mn.y, __shfl_xor(mn.y, off));
        mn.z = fminf(mn.z, __shfl_xor(mn.z, off)); mn.w = fminf(mn.w, __shfl_xor(mn.w, off));
        mx.x = fmaxf(mx.x, __shfl_xor(mx.x, off)); mx.y = fmaxf(mx.y, __shfl_xor(mx.y, off));
        mx.z = fmaxf(mx.z, __shfl_xor(mx.z, off)); mx.w = fmaxf(mx.w, __shfl_xor(mx.w, off));
        sm.x += __shfl_xor(sm.x, off); sm.y += __shfl_xor(sm.y, off);
        sm.z += __shfl_xor(sm.z, off); sm.w += __shfl_xor(sm.w, off);
    }
    float4 tv = *(const float4*)(tptr + 4 * fq);
    tv.x = fminf(fmaxf(tv.x, 0.f), 1.f); tv.y = fminf(fmaxf(tv.y, 0.f), 1.f);
    tv.z = fminf(fmaxf(tv.z, 0.f), 1.f); tv.w = fminf(fmaxf(tv.w, 0.f), 1.f);
    float4 bias;
    bias.x = tv.x * mx.x + (1.f - tv.x) * mn.x;
    bias.y = tv.y * mx.y + (1.f - tv.y) * mn.y;
    bias.z = tv.z * mx.z + (1.f - tv.z) * mn.z;
    bias.w = tv.w * mx.w + (1.f - tv.w) * mn.w;
    float4 rs = make_float4(0.f, 0.f, 0.f, 0.f);

#define RACC(v) { rs.x += fmaxf(v.x - bias.x, 0.f); rs.y += fmaxf(v.y - bias.y, 0.f); \
                  rs.z += fmaxf(v.z - bias.z, 0.f); rs.w += fmaxf(v.w - bias.w, 0.f); }

    if (deg >= 16) {
        // cached slots: branch-free full unroll
#pragma unroll
        for (int i = 0; i < 4; ++i) {
            float4 v = cache[w][i * 4 + g][fq];
            RACC(v)
        }
        // overflow: branchless full iterations + masked tail
        int e = start + 16;
        for (; e + 16 <= end; e += 16) {
            int i0 = e + g;
            int s0 = srcSorted[i0], s1 = srcSorted[i0 + 4];
            int s2 = srcSorted[i0 + 8], s3 = srcSorted[i0 + 12];
            float4 v0 = mq[(size_t)s0 * 16], v1 = mq[(size_t)s1 * 16];
            float4 v2 = mq[(size_t)s2 * 16], v3 = mq[(size_t)s3 * 16];
            RACC(v0) RACC(v1) RACC(v2) RACC(v3)
        }
        if (e < end) {
            int i0 = e + g, i1 = i0 + 4, i2 = i0 + 8, i3 = i0 + 12;
            bool ok0 = i0 < end, ok1 = i1 < end, ok2 = i2 < end, ok3 = i3 < end;
            int s0 = 0, s1 = 0, s2 = 0, s3 = 0;
            if (ok0) s0 = srcSorted[i0];
            if (ok1) s1 = srcSorted[i1];
            if (ok2) s2 = srcSorted[i2];
            if (ok3) s3 = srcSorted[i3];
            float4 v0, v1, v2, v3;
            if (ok0) v0 = mq[(size_t)s0 * 16];
            if (ok1) v1 = mq[(size_t)s1 * 16];
            if (ok2) v2 = mq[(size_t)s2 * 16];
            if (ok3) v3 = mq[(size_t)s3 * 16];
            if (ok0) RACC(v0)
            if (ok1) RACC(v1)
            if (ok2) RACC(v2)
            if (ok3) RACC(v3)
        }
    } else {
        for (int idx = start + g; idx < end; idx += 4) {
            float4 v = cache[w][idx - start][fq];
            RACC(v)
        }
    }
#pragma unroll
    for (int off = 16; off <= 32; off <<= 1) {
        rs.x += __shfl_xor(rs.x, off); rs.y += __shfl_xor(rs.y, off);
        rs.z += __shfl_xor(rs.z, off); rs.w += __shfl_xor(rs.w, off);
    }
    if (g == 0) {
        float cnt = (float)deg;
        float w0 = Wp[0], w1 = Wp[1], w2 = Wp[2], w3 = Wp[3], w4 = Wp[4], b0 = bp[0];
        float4* hp = (float4*)(hbuf + (size_t)node * 64 + 4 * fq);
        float4 h = *hp;
        h.x += w0 * cnt + w1 * mn.x + w2 * mx.x + w3 * rs.x + w4 * sm.x + b0;
        h.y += w0 * cnt + w1 * mn.y + w2 * mx.y + w3 * rs.y + w4 * sm.y + b0;
        h.z += w0 * cnt + w1 * mn.z + w2 * mx.z + w3 * rs.z + w4 * sm.z + b0;
        h.w += w0 * cnt + w1 * mn.w + w2 * mx.w + w3 * rs.w + w4 * sm.w + b0;
        *hp = h;
    }
#undef ACC1
#undef RACC
}

// ---------------- global pooling (4-phase, parallel) ----------------

__global__ __launch_bounds__(256) void gaggA_kernel(const float* __restrict__ msg,
                                                    const int* __restrict__ gstart,
                                                    float* __restrict__ pmn,
                                                    float* __restrict__ pmx,
                                                    float* __restrict__ psm) {
    const int bid = blockIdx.x;
    const int g = bid >> 4, c = bid & (GCH - 1);
    const int s = gstart[g];
    const int e = (g == G_GRAPHS - 1) ? N_NODES : gstart[g + 1];
    const int clen = (e - s + GCH - 1) / GCH;
    const int cs = s + c * clen;
    const int ce = (cs + clen < e) ? (cs + clen) : e;
    const int f = threadIdx.x & 63, r = threadIdx.x >> 6;
    float mn = __builtin_inff(), mx = -__builtin_inff(), sm = 0.f;
    for (int i = cs + r; i < ce; i += 4) {
        float v = msg[(size_t)i * 64 + f];
        mn = fminf(mn, v); mx = fmaxf(mx, v); sm += v;
    }
    __shared__ float smn[4][64], smx[4][64], ssm[4][64];
    smn[r][f] = mn; smx[r][f] = mx; ssm[r][f] = sm;
    __syncthreads();
    if (r == 0) {
        pmn[bid * 64 + f] = fminf(fminf(smn[0][f], smn[1][f]), fminf(smn[2][f], smn[3][f]));
        pmx[bid * 64 + f] = fmaxf(fmaxf(smx[0][f], smx[1][f]), fmaxf(smx[2][f], smx[3][f]));
        psm[bid * 64 + f] = ssm[0][f] + ssm[1][f] + ssm[2][f] + ssm[3][f];
    }
}

__global__ __launch_bounds__(64) void gaggB_kernel(const float* __restrict__ pmn,
                                                   const float* __restrict__ pmx,
                                                   const float* __restrict__ psm,
                                                   const float* __restrict__ gt,
                                                   float* __restrict__ gMn,
                                                   float* __restrict__ gMx,
                                                   float* __restrict__ gSm,
                                                   float* __restrict__ gBias) {
    const int g = blockIdx.x, f = threadIdx.x;
    float mn = __builtin_inff(), mx = -__builtin_inff(), sm = 0.f;
#pragma unroll
    for (int c = 0; c < GCH; ++c) {
        int i = (g * GCH + c) * 64 + f;
        mn = fminf(mn, pmn[i]); mx = fmaxf(mx, pmx[i]); sm += psm[i];
    }
    float tv = fminf(fmaxf(gt[f], 0.f), 1.f);
    gMn[g * 64 + f] = mn; gMx[g * 64 + f] = mx; gSm[g * 64 + f] = sm;
    gBias[g * 64 + f] = tv * mx + (1.f - tv) * mn;
}

__global__ __launch_bounds__(256) void gaggC_kernel(const float* __restrict__ msg,
                                                    const int* __restrict__ gstart,
                                                    const float* __restrict__ gBias,
                                                    float* __restrict__ prs) {
    const int bid = blockIdx.x;
    const int g = bid >> 4, c = bid & (GCH - 1);
    const int s = gstart[g];
    const int e = (g == G_GRAPHS - 1) ? N_NODES : gstart[g + 1];
    const int clen = (e - s + GCH - 1) / GCH;
    const int cs = s + c * clen;
    const int ce = (cs + clen < e) ? (cs + clen) : e;
    const int f = threadIdx.x & 63, r = threadIdx.x >> 6;
    const float bias = gBias[g * 64 + f];
    float rs = 0.f;
    for (int i = cs + r; i < ce; i += 4) {
        float v = msg[(size_t)i * 64 + f];
        rs += fmaxf(v - bias, 0.f);
    }
    __shared__ float srs[4][64];
    srs[r][f] = rs;
    __syncthreads();
    if (r == 0)
        prs[bid * 64 + f] = srs[0][f] + srs[1][f] + srs[2][f] + srs[3][f];
}

__global__ __launch_bounds__(64) void gaggD_kernel(const float* __restrict__ prs,
                                                   const int* __restrict__ gstart,
                                                   const float* __restrict__ gMn,
                                                   const float* __restrict__ gMx,
                                                   const float* __restrict__ gSm,
                                                   const float* __restrict__ gWp,
                                                   const float* __restrict__ gbp,
                                                   const float* __restrict__ Wout,
                                                   const float* __restrict__ bout,
                                                   float* __restrict__ out) {
    const int g = blockIdx.x, f = threadIdx.x;
    float rs = 0.f;
#pragma unroll
    for (int c = 0; c < GCH; ++c) rs += prs[(g * GCH + c) * 64 + f];
    const int s = gstart[g];
    const int e = (g == G_GRAPHS - 1) ? N_NODES : gstart[g + 1];
    float cnt = (float)(e - s);
    __shared__ float emb[64];
    emb[f] = gWp[0] * cnt + gWp[1] * gMn[g * 64 + f] + gWp[2] * gMx[g * 64 + f] +
             gWp[3] * rs + gWp[4] * gSm[g * 64 + f] + gbp[0];
    __syncthreads();
    if (f < OUTD) {
        float a = bout[f];
        const float* wr = Wout + f * 64;
#pragma unroll
        for (int k = 0; k < 64; ++k) a = fmaf(emb[k], wr[k], a);
        out[g * OUTD + f] = a;
    }
}

// ---------------- launch ----------------

extern "C" void kernel_launch(void* const* d_in, const int* in_sizes, int n_in,
                              void* d_out, int out_size, void* d_ws, size_t ws_size,
                              hipStream_t stream) {
    const float* x     = (const float*)d_in[0];
    const int*   ei    = (const int*)d_in[1];
    const int*   batch = (const int*)d_in[2];
    const float* Wlin  = (const float*)d_in[3];
    const float* blin  = (const float*)d_in[4];
    const float* t     = (const float*)d_in[5];
    const float* Wproj = (const float*)d_in[6];
    const float* bproj = (const float*)d_in[7];
    const float* Wc    = (const float*)d_in[8];
    const float* bc    = (const float*)d_in[9];
    const float* gWlin = (const float*)d_in[10];
    const float* gblin = (const float*)d_in[11];
    const float* gt    = (const float*)d_in[12];
    const float* gWproj= (const float*)d_in[13];
    const float* gbproj= (const float*)d_in[14];
    const float* Wout  = (const float*)d_in[15];
    const float* bout  = (const float*)d_in[16];
    float* out = (float*)d_out;

    const int* src = ei;
    const int* dst = ei + E_EDGES;

    // workspace layout
    char* p = (char*)d_ws;
    float* bufMsg = (float*)p; p += (size_t)N_NODES * FDIM * sizeof(float);
    float* bufH   = (float*)p; p += (size_t)N_NODES * FDIM * sizeof(float);
    int* offsets  = (int*)p;   p += (size_t)(N_NODES + 1) * sizeof(int);
    int* gstart   = (int*)p;   p += (size_t)G_GRAPHS * sizeof(int);
    int* bucketCount  = (int*)p; p += (size_t)KBUK * 16 * sizeof(int);
    int* bucketStart  = (int*)p; p += (size_t)(KBUK + 1) * sizeof(int);
    int* bucketCursor = (int*)p; p += (size_t)KBUK * 16 * sizeof(int);
    int* srcSorted= (int*)p;   p += (size_t)E_EDGES * sizeof(int);
    float* pmn = (float*)p;    p += (size_t)G_GRAPHS * GCH * 64 * sizeof(float);
    float* pmx = (float*)p;    p += (size_t)G_GRAPHS * GCH * 64 * sizeof(float);
    float* psm = (float*)p;    p += (size_t)G_GRAPHS * GCH * 64 * sizeof(float);
    float* prs = (float*)p;    p += (size_t)G_GRAPHS * GCH * 64 * sizeof(float);
    float* gMn = (float*)p;    p += (size_t)G_GRAPHS * 64 * sizeof(float);
    float* gMx = (float*)p;    p += (size_t)G_GRAPHS * 64 * sizeof(float);
    float* gSm = (float*)p;    p += (size_t)G_GRAPHS * 64 * sizeof(float);
    float* gBias = (float*)p;  p += (size_t)G_GRAPHS * 64 * sizeof(float);
    int* ebuf = (int*)bufMsg;  // dead until lin layer 0 runs (after bsort)

    hipMemsetAsync(bucketCount, 0, (size_t)KBUK * 16 * sizeof(int), stream);

    const int NB = (N_NODES + 255) / 256;
    bhist_kernel<<<SEBLK, 256, 0, stream>>>(dst, bucketCount);
    bscan_kernel<<<1, 256, 0, stream>>>(bucketCount, bucketStart, bucketCursor, offsets);
    bscatter_kernel<<<SEBLK, 256, 0, stream>>>(src, dst, bucketCursor, ebuf);
    bsort_kernel<<<KBUK, 256, 0, stream>>>(ebuf, bucketStart, offsets, srcSorted);
    bound_kernel<<<NB, 256, 0, stream>>>(batch, gstart);

    const int LB = (N_NODES + 63) / 64;
    const int AB = (N_NODES + 3) / 4;

    // layer 0: h = x
    lin_kernel<true><<<LB, 256, 0, stream>>>(x, Wlin, blin, Wc, bc, bufMsg, bufH);
    agg_kernel<<<AB, 256, 0, stream>>>(bufMsg, offsets, srcSorted, t, Wproj, bproj, bufH);
    // layer 1: h = bufH (combine written in place)
    lin_kernel<true><<<LB, 256, 0, stream>>>(bufH, Wlin + 4096, blin + 64, Wc + 4096,
                                             bc + 64, bufMsg, bufH);
    agg_kernel<<<AB, 256, 0, stream>>>(bufMsg, offsets, srcSorted, t + 64, Wproj + 5,
                                       bproj + 1, bufH);
    // global conv message
    lin_kernel<false><<<LB, 256, 0, stream>>>(bufH, gWlin, gblin, nullptr, nullptr,
                                              bufMsg, nullptr);
    gaggA_kernel<<<G_GRAPHS * GCH, 256, 0, stream>>>(bufMsg, gstart, pmn, pmx, psm);
    gaggB_kernel<<<G_GRAPHS, 64, 0, stream>>>(pmn, pmx, psm, gt, gMn, gMx, gSm, gBias);
    gaggC_kernel<<<G_GRAPHS * GCH, 256, 0, stream>>>(bufMsg, gstart, gBias, prs);
    gaggD_kernel<<<G_GRAPHS, 64, 0, stream>>>(prs, gstart, gMn, gMx, gSm, gWproj,
                                              gbproj, Wout, bout, out);
}